// Round 4
// baseline (4385.296 us; speedup 1.0000x reference)
//
#include <hip/hip_runtime.h>
#include <hip/hip_bf16.h>

// Problem constants (from reference)
#define B_TOT 16384
#define DD    384
#define HH    1024
#define DRR   512
#define DMM   1152
#define SS    6     // 1 + KP + KN
#define KPP   3
#define KNN   2

typedef unsigned short ushort_t;
typedef __bf16 bf16x8 __attribute__((ext_vector_type(8)));
typedef float  f32x4  __attribute__((ext_vector_type(4)));

#define ROWE 72    // staging LDS row stride (bf16): 144 B, 16B-aligned
#define CST  136   // bgemm 128-wide epilogue LDS stride (bf16): 272 B, 16B-aligned

// ---------------------------------------------------------------- helpers
__device__ __forceinline__ float gelu_f(float x) {
    float x3 = x * x * x;
    return 0.5f * x * (1.0f + tanhf(0.7978845608028654f * (x + 0.044715f * x3)));
}
__device__ __forceinline__ float sigmoid_f(float x) {
    return 1.0f / (1.0f + expf(-x));
}
__device__ __forceinline__ float wave_red_sum(float v) {
    #pragma unroll
    for (int off = 32; off; off >>= 1) v += __shfl_xor(v, off);
    return v;
}
__device__ __forceinline__ ushort_t f2bf(float v) {
    __hip_bfloat16 h = __float2bfloat16(v);
    return *reinterpret_cast<ushort_t*>(&h);
}
__device__ __forceinline__ float bf2f(ushort_t u) {
    unsigned int x = ((unsigned int)u) << 16;
    return __uint_as_float(x);
}
// XCD-aware bijective block swizzle
__device__ __forceinline__ void swz_xy(int& bx, int& by) {
    const int nx = gridDim.x;
    const int nwg = nx * gridDim.y;
    const int h = by * nx + bx;
    const int q = nwg >> 3, r = nwg & 7;
    const int xcd = h & 7, lo = h >> 3;
    const int lin = (xcd < r) ? (xcd * (q + 1) + lo)
                              : (r * (q + 1) + (xcd - r) * q + lo);
    bx = lin % nx;
    by = lin / nx;
}

// ---------------------------------------------------------------- MFMA GEMM
// C[M,N] = epi( A[M,K](bf16) @ WT[N,K](bf16)^T + bias )
// EPI: 0 none, 1 relu, 4 v - X2(bf16), 7 split-xy (c<512 -> Ch, else gelu -> Ch2)
// ACCUM: v += C_old. C fp32 direct stores; Ch/Ch2 bf16 via LDS-transpose epilogue.
template<int EPI, bool ACCUM>
__global__ __launch_bounds__(256, 3)
void bgemm(const ushort_t* __restrict__ A, const ushort_t* __restrict__ WT,
           const float* __restrict__ bias, const ushort_t* __restrict__ X2,
           float* __restrict__ C, ushort_t* __restrict__ Ch, ushort_t* __restrict__ Ch2,
           int M, int N, int K)
{
    __shared__ ushort_t sm[2 * 128 * ROWE];    // 36 KiB pool
    ushort_t* smA = sm;
    ushort_t* smB = sm + 128 * ROWE;

    int bx = blockIdx.x, by = blockIdx.y;
    swz_xy(bx, by);
    const int tid = threadIdx.x;
    const int l = tid & 63, w = tid >> 6;
    const int wr = w >> 1, wc = w & 1;
    const int lr = l & 15, hi = l >> 4;
    const int row0 = by * 128, col0 = bx * 128;

    const int sr = tid & 127, sseg = tid >> 7;
    const int swb = sr * ROWE + sseg * 32;
    const ushort_t* Ag = A  + (size_t)(row0 + sr) * K + sseg * 32;
    const ushort_t* Bg = WT + (size_t)(col0 + sr) * K + sseg * 32;

    f32x4 acc[4][4] = {};
    uint4 ra[4], rb[4];
    const int NT = K >> 6;

    {
        const uint4* sa = (const uint4*)Ag;
        const uint4* sb = (const uint4*)Bg;
        ra[0]=sa[0]; ra[1]=sa[1]; ra[2]=sa[2]; ra[3]=sa[3];
        rb[0]=sb[0]; rb[1]=sb[1]; rb[2]=sb[2]; rb[3]=sb[3];
        uint4* dA = (uint4*)&smA[swb];
        uint4* dB = (uint4*)&smB[swb];
        dA[0]=ra[0]; dA[1]=ra[1]; dA[2]=ra[2]; dA[3]=ra[3];
        dB[0]=rb[0]; dB[1]=rb[1]; dB[2]=rb[2]; dB[3]=rb[3];
    }
    __syncthreads();

    for (int t = 0; t < NT; ++t) {
        if (t + 1 < NT) {
            const uint4* sa = (const uint4*)(Ag + (size_t)(t + 1) * 64);
            const uint4* sb = (const uint4*)(Bg + (size_t)(t + 1) * 64);
            ra[0]=sa[0]; ra[1]=sa[1]; ra[2]=sa[2]; ra[3]=sa[3];
            rb[0]=sb[0]; rb[1]=sb[1]; rb[2]=sb[2]; rb[3]=sb[3];
        }
        #pragma unroll
        for (int ks = 0; ks < 2; ++ks) {
            bf16x8 af[4], bfr[4];
            #pragma unroll
            for (int m = 0; m < 4; ++m)
                af[m] = *(const bf16x8*)&smA[(wr*64 + m*16 + lr) * ROWE + ks*32 + hi*8];
            #pragma unroll
            for (int n = 0; n < 4; ++n)
                bfr[n] = *(const bf16x8*)&smB[(wc*64 + n*16 + lr) * ROWE + ks*32 + hi*8];
            #pragma unroll
            for (int m = 0; m < 4; ++m)
                #pragma unroll
                for (int n = 0; n < 4; ++n)
                    acc[m][n] = __builtin_amdgcn_mfma_f32_16x16x32_bf16(
                        af[m], bfr[n], acc[m][n], 0, 0, 0);
        }
        __syncthreads();
        if (t + 1 < NT) {
            uint4* dA = (uint4*)&smA[swb];
            uint4* dB = (uint4*)&smB[swb];
            dA[0]=ra[0]; dA[1]=ra[1]; dA[2]=ra[2]; dA[3]=ra[3];
            dB[0]=rb[0]; dB[1]=rb[1]; dB[2]=rb[2]; dB[3]=rb[3];
            __syncthreads();
        }
    }

    // epilogue: C/D frag mapping col = l&15, row = (l>>4)*4 + j
    const bool BF = (EPI == 7) || (Ch != nullptr);
    #pragma unroll
    for (int m = 0; m < 4; ++m) {
        #pragma unroll
        for (int n = 0; n < 4; ++n) {
            const int r0 = row0 + wr*64 + m*16 + hi*4;
            const int c  = col0 + wc*64 + n*16 + lr;
            const float bv = bias ? bias[c] : 0.f;
            #pragma unroll
            for (int j = 0; j < 4; ++j) {
                const int r = r0 + j;
                float v = acc[m][n][j] + bv;
                if (EPI == 1) v = fmaxf(v, 0.f);
                if (EPI == 4) v = v - bf2f(X2[(size_t)r * N + c]);
                if (ACCUM)    v += C[(size_t)r * N + c];
                if (C) C[(size_t)r * N + c] = v;   // fp32: 64B/16-lane sectors, dense
                if (BF) {
                    float ov = (EPI == 7 && c >= 512) ? gelu_f(v) : v;
                    sm[(wr*64 + m*16 + hi*4 + j) * CST + wc*64 + n*16 + lr] = f2bf(ov);
                }
            }
        }
    }
    if (BF) {   // coalesced bf16 stores: 128B contiguous per thread
        __syncthreads();
        const int er = tid >> 1, ec = (tid & 1) * 64;
        ushort_t* dst; int nn, dc0;
        if (EPI == 7) {
            nn = 512;
            if (col0 < 512) { dst = Ch;  dc0 = col0; }
            else            { dst = Ch2; dc0 = col0 - 512; }
        } else { dst = Ch; nn = N; dc0 = col0; }
        const uint4* sp = (const uint4*)&sm[er * CST + ec];
        uint4* gp = (uint4*)(dst + (size_t)(row0 + er) * nn + dc0 + ec);
        #pragma unroll
        for (int q = 0; q < 8; ++q) gp[q] = sp[q];
    }
}

// ---------------------------------------------------------------- dual-B GEMM
// LOGITS=false: Ch[M,N] = gelu(A@W1T^T) * (A@W2T^T)  (bf16, LDS-transposed stores)
// LOGITS=true : LP[r*6+bx] = sum_c gelu(G)*V*wproj[c] over this block's 64 cols
template<bool LOGITS>
__global__ __launch_bounds__(256, 2)
void dual_k(const ushort_t* __restrict__ A, const ushort_t* __restrict__ W1T,
            const ushort_t* __restrict__ W2T, ushort_t* __restrict__ Ch,
            float* __restrict__ LP, const float* __restrict__ wproj,
            int M, int N, int K)
{
    __shared__ ushort_t sm[128*ROWE + 2*64*ROWE];   // 36 KiB
    ushort_t* smA = sm;
    ushort_t* smG = sm + 128*ROWE;
    ushort_t* smV = smG + 64*ROWE;

    int bx = blockIdx.x, by = blockIdx.y;
    swz_xy(bx, by);
    const int tid = threadIdx.x;
    const int l = tid & 63, w = tid >> 6;
    const int wr = w >> 1, wc = w & 1;
    const int lr = l & 15, hi = l >> 4;
    const int row0 = by * 128, col0 = bx * 64;

    const int sr = tid & 127, sseg = tid >> 7;
    const int swbA = sr * ROWE + sseg * 32;
    const int sr2 = tid & 63, kof2 = (tid >> 6) * 16;
    const int swbB = sr2 * ROWE + kof2;

    const ushort_t* Ag = A   + (size_t)(row0 + sr)  * K + sseg * 32;
    const ushort_t* Gg = W1T + (size_t)(col0 + sr2) * K + kof2;
    const ushort_t* Vg = W2T + (size_t)(col0 + sr2) * K + kof2;

    f32x4 ag[4][2] = {}, av[4][2] = {};
    uint4 ra[4], rg[2], rv[2];
    const int NT = K >> 6;

    {
        const uint4* sa = (const uint4*)Ag;
        const uint4* sg = (const uint4*)Gg;
        const uint4* sv = (const uint4*)Vg;
        ra[0]=sa[0]; ra[1]=sa[1]; ra[2]=sa[2]; ra[3]=sa[3];
        rg[0]=sg[0]; rg[1]=sg[1];
        rv[0]=sv[0]; rv[1]=sv[1];
        uint4* dA=(uint4*)&smA[swbA]; dA[0]=ra[0]; dA[1]=ra[1]; dA[2]=ra[2]; dA[3]=ra[3];
        uint4* dG=(uint4*)&smG[swbB]; dG[0]=rg[0]; dG[1]=rg[1];
        uint4* dV=(uint4*)&smV[swbB]; dV[0]=rv[0]; dV[1]=rv[1];
    }
    __syncthreads();

    for (int t = 0; t < NT; ++t) {
        if (t + 1 < NT) {
            const uint4* sa = (const uint4*)(Ag + (size_t)(t + 1) * 64);
            const uint4* sg = (const uint4*)(Gg + (size_t)(t + 1) * 64);
            const uint4* sv = (const uint4*)(Vg + (size_t)(t + 1) * 64);
            ra[0]=sa[0]; ra[1]=sa[1]; ra[2]=sa[2]; ra[3]=sa[3];
            rg[0]=sg[0]; rg[1]=sg[1];
            rv[0]=sv[0]; rv[1]=sv[1];
        }
        #pragma unroll
        for (int ks = 0; ks < 2; ++ks) {
            bf16x8 af[4], bg[2], bv[2];
            #pragma unroll
            for (int m = 0; m < 4; ++m)
                af[m] = *(const bf16x8*)&smA[(wr*64 + m*16 + lr) * ROWE + ks*32 + hi*8];
            #pragma unroll
            for (int n = 0; n < 2; ++n) {
                bg[n] = *(const bf16x8*)&smG[(wc*32 + n*16 + lr) * ROWE + ks*32 + hi*8];
                bv[n] = *(const bf16x8*)&smV[(wc*32 + n*16 + lr) * ROWE + ks*32 + hi*8];
            }
            #pragma unroll
            for (int m = 0; m < 4; ++m)
                #pragma unroll
                for (int n = 0; n < 2; ++n) {
                    ag[m][n] = __builtin_amdgcn_mfma_f32_16x16x32_bf16(af[m], bg[n], ag[m][n], 0, 0, 0);
                    av[m][n] = __builtin_amdgcn_mfma_f32_16x16x32_bf16(af[m], bv[n], av[m][n], 0, 0, 0);
                }
        }
        __syncthreads();
        if (t + 1 < NT) {
            uint4* dA=(uint4*)&smA[swbA]; dA[0]=ra[0]; dA[1]=ra[1]; dA[2]=ra[2]; dA[3]=ra[3];
            uint4* dG=(uint4*)&smG[swbB]; dG[0]=rg[0]; dG[1]=rg[1];
            uint4* dV=(uint4*)&smV[swbB]; dV[0]=rv[0]; dV[1]=rv[1];
            __syncthreads();
        }
    }

    if (!LOGITS) {
        // LDS-transpose epilogue: dense 64B stores
        #pragma unroll
        for (int m = 0; m < 4; ++m)
            #pragma unroll
            for (int n = 0; n < 2; ++n)
                #pragma unroll
                for (int j = 0; j < 4; ++j)
                    sm[(wr*64 + m*16 + hi*4 + j) * ROWE + wc*32 + n*16 + lr] =
                        f2bf(gelu_f(ag[m][n][j]) * av[m][n][j]);
        __syncthreads();
        const int er = tid >> 1, ec = (tid & 1) * 32;
        const uint4* sp = (const uint4*)&sm[er * ROWE + ec];
        uint4* gp = (uint4*)(Ch + (size_t)(row0 + er) * N + col0 + ec);
        #pragma unroll
        for (int q = 0; q < 4; ++q) gp[q] = sp[q];
    } else {
        // fused logit partial: dot with wproj over this block's 64 cols
        float wp[2];
        #pragma unroll
        for (int n = 0; n < 2; ++n) wp[n] = wproj[col0 + wc*32 + n*16 + lr];
        float* red = (float*)sm;   // [128 rows][2 wc] f32
        #pragma unroll
        for (int m = 0; m < 4; ++m) {
            #pragma unroll
            for (int j = 0; j < 4; ++j) {
                float s = 0.f;
                #pragma unroll
                for (int n = 0; n < 2; ++n)
                    s += gelu_f(ag[m][n][j]) * av[m][n][j] * wp[n];
                s += __shfl_xor(s, 1);
                s += __shfl_xor(s, 2);
                s += __shfl_xor(s, 4);
                s += __shfl_xor(s, 8);
                if (lr == 0) red[(wr*64 + m*16 + hi*4 + j) * 2 + wc] = s;
            }
        }
        __syncthreads();
        if (tid < 128)
            LP[(size_t)(row0 + tid) * 6 + bx] = red[tid*2] + red[tid*2 + 1];
    }
}

// ---------------------------------------------------------------- fused rgri+rec
// Per (b-block 128, dcol-block 64): loop t=0..5, GEMM r/i logits over K=512,
// sigmoid in-register, recurrence in regs, prod = h*gate -> bf16 (LDS epilogue).
__global__ __launch_bounds__(256, 2)
void rgri_rec_k(const ushort_t* __restrict__ u, const ushort_t* __restrict__ gate,
                const ushort_t* __restrict__ wrT, const ushort_t* __restrict__ wiT,
                const float* __restrict__ br, const float* __restrict__ bi,
                const float* __restrict__ a2, ushort_t* __restrict__ prod, int Bc)
{
    __shared__ ushort_t sm[128*ROWE + 2*64*ROWE];
    ushort_t* smA = sm;
    ushort_t* smR = sm + 128*ROWE;
    ushort_t* smI = smR + 64*ROWE;

    int bx = blockIdx.x, by = blockIdx.y;
    swz_xy(bx, by);
    const int tid = threadIdx.x;
    const int l = tid & 63, w = tid >> 6;
    const int wr = w >> 1, wc = w & 1;
    const int lr = l & 15, hi = l >> 4;
    const int c0 = bx * 64, b0r = by * 128;

    const int sr = tid & 127, sseg = tid >> 7;
    const int swbA = sr * ROWE + sseg * 32;
    const int sr2 = tid & 63, kof2 = (tid >> 6) * 16;
    const int swbB = sr2 * ROWE + kof2;

    const ushort_t* Rg = wrT + (size_t)(c0 + sr2) * DRR + kof2;
    const ushort_t* Ig = wiT + (size_t)(c0 + sr2) * DRR + kof2;

    float a2v[2], brv[2], biv[2];
    #pragma unroll
    for (int n = 0; n < 2; ++n) {
        const int c = c0 + wc*32 + n*16 + lr;
        a2v[n] = a2[c]; brv[n] = br[c]; biv[n] = bi[c];
    }
    f32x4 h[4][2] = {};

    for (int t = 0; t < SS; ++t) {
        const ushort_t* Ag = u + (size_t)(t * Bc + b0r + sr) * DRR + sseg * 32;
        f32x4 ar[4][2] = {}, ai[4][2] = {};
        uint4 ra[4], rr_[2], ri_[2];
        {
            const uint4* sa = (const uint4*)Ag;
            const uint4* sg = (const uint4*)Rg;
            const uint4* sv = (const uint4*)Ig;
            ra[0]=sa[0]; ra[1]=sa[1]; ra[2]=sa[2]; ra[3]=sa[3];
            rr_[0]=sg[0]; rr_[1]=sg[1];
            ri_[0]=sv[0]; ri_[1]=sv[1];
            uint4* dA=(uint4*)&smA[swbA]; dA[0]=ra[0]; dA[1]=ra[1]; dA[2]=ra[2]; dA[3]=ra[3];
            uint4* dR=(uint4*)&smR[swbB]; dR[0]=rr_[0]; dR[1]=rr_[1];
            uint4* dI=(uint4*)&smI[swbB]; dI[0]=ri_[0]; dI[1]=ri_[1];
        }
        __syncthreads();
        const int NT = DRR >> 6;  // 8
        for (int kt = 0; kt < NT; ++kt) {
            if (kt + 1 < NT) {
                const uint4* sa = (const uint4*)(Ag + (kt + 1) * 64);
                const uint4* sg = (const uint4*)(Rg + (kt + 1) * 64);
                const uint4* sv = (const uint4*)(Ig + (kt + 1) * 64);
                ra[0]=sa[0]; ra[1]=sa[1]; ra[2]=sa[2]; ra[3]=sa[3];
                rr_[0]=sg[0]; rr_[1]=sg[1];
                ri_[0]=sv[0]; ri_[1]=sv[1];
            }
            #pragma unroll
            for (int ks = 0; ks < 2; ++ks) {
                bf16x8 af[4], bfr[2], bfi[2];
                #pragma unroll
                for (int m = 0; m < 4; ++m)
                    af[m] = *(const bf16x8*)&smA[(wr*64 + m*16 + lr) * ROWE + ks*32 + hi*8];
                #pragma unroll
                for (int n = 0; n < 2; ++n) {
                    bfr[n] = *(const bf16x8*)&smR[(wc*32 + n*16 + lr) * ROWE + ks*32 + hi*8];
                    bfi[n] = *(const bf16x8*)&smI[(wc*32 + n*16 + lr) * ROWE + ks*32 + hi*8];
                }
                #pragma unroll
                for (int m = 0; m < 4; ++m)
                    #pragma unroll
                    for (int n = 0; n < 2; ++n) {
                        ar[m][n] = __builtin_amdgcn_mfma_f32_16x16x32_bf16(af[m], bfr[n], ar[m][n], 0, 0, 0);
                        ai[m][n] = __builtin_amdgcn_mfma_f32_16x16x32_bf16(af[m], bfi[n], ai[m][n], 0, 0, 0);
                    }
            }
            __syncthreads();
            if (kt + 1 < NT) {
                uint4* dA=(uint4*)&smA[swbA]; dA[0]=ra[0]; dA[1]=ra[1]; dA[2]=ra[2]; dA[3]=ra[3];
                uint4* dR=(uint4*)&smR[swbB]; dR[0]=rr_[0]; dR[1]=rr_[1];
                uint4* dI=(uint4*)&smI[swbB]; dI[0]=ri_[0]; dI[1]=ri_[1];
                __syncthreads();
            }
        }
        // recurrence step (r,i fp32 in-register); stage prod tile into LDS
        #pragma unroll
        for (int m = 0; m < 4; ++m) {
            #pragma unroll
            for (int n = 0; n < 2; ++n) {
                const int c = c0 + wc*32 + n*16 + lr;
                #pragma unroll
                for (int j = 0; j < 4; ++j) {
                    const int b = b0r + wr*64 + m*16 + hi*4 + j;
                    const size_t idx = (size_t)(t * Bc + b) * DRR + c;
                    const float rv = sigmoid_f(ar[m][n][j] + brv[n]);
                    const float iv = sigmoid_f(ai[m][n][j] + biv[n]);
                    const float e  = exp2f(a2v[n] * rv);
                    const float uu = bf2f(u[idx]);
                    const float hv = e * h[m][n][j]
                                   + sqrtf(fmaxf(0.f, 1.f - e * e)) * (iv * uu);
                    h[m][n][j] = hv;
                    sm[(wr*64 + m*16 + hi*4 + j) * ROWE + wc*32 + n*16 + lr] =
                        f2bf(hv * bf2f(gate[idx]));
                }
            }
        }
        __syncthreads();
        {
            const int er = tid >> 1, ec = (tid & 1) * 32;
            const uint4* sp = (const uint4*)&sm[er * ROWE + ec];
            uint4* gp = (uint4*)(prod + (size_t)(t * Bc + b0r + er) * DRR + c0 + ec);
            #pragma unroll
            for (int q = 0; q < 4; ++q) gp[q] = sp[q];
        }
        __syncthreads();   // protect LDS before next t's staging
    }
}

// ---------------------------------------------------------------- small kernels

__global__ void tr_k(const float* __restrict__ W, ushort_t* __restrict__ WT,
                     int K, int N)
{
    int idx = blockIdx.x * 256 + threadIdx.x;
    if (idx >= K * N) return;
    int n = idx / K, k = idx % K;
    WT[idx] = f2bf(W[(size_t)k * N + n]);
}

__global__ void prep_k(const float* __restrict__ rg_bx, const float* __restrict__ rg_by,
                       const float* __restrict__ rg_lam,
                       float* __restrict__ bias_xy, float* __restrict__ a2)
{
    int i = blockIdx.x * 256 + threadIdx.x;
    if (i < 512) {
        bias_xy[i] = rg_bx[i];
        float lam = rg_lam[i];
        float sp = (lam > 20.f) ? lam : log1pf(expf(lam));
        a2[i] = -8.0f * sp * 1.4426950408889634f;
    } else if (i < 1024) {
        bias_xy[i] = rg_by[i - 512];
    }
}

__global__ void negm_k(const float* __restrict__ head, const float* __restrict__ pred,
                       ushort_t* __restrict__ negm_h, int b0, int Bc)
{
    int idx = blockIdx.x * 256 + threadIdx.x;        // < Bc*2*384
    int d = idx % DD, rr = idx / DD;
    int j = (rr >= Bc) ? 1 : 0;
    int b = rr - j * Bc;
    size_t off = ((size_t)(KPP + j) * B_TOT + (b0 + b)) * DD + d;
    negm_h[idx] = f2bf(head[off] + pred[off]);
}

// grouped softmax attn + assemble x rows (t-major) + rmsnorm(g1) -> hb bf16
__global__ void asmrms_k(const float* __restrict__ init_f,
                         const float* __restrict__ head, const float* __restrict__ pred,
                         const float* __restrict__ w_ap, const float* __restrict__ b_ap,
                         const float* __restrict__ w_an, const float* __restrict__ b_an,
                         const ushort_t* __restrict__ nf, const float* __restrict__ g1,
                         float* __restrict__ x, ushort_t* __restrict__ hb,
                         int b0, int Bc)
{
    const int lb = blockIdx.x, gb = b0 + lb, lane = threadIdx.x;
    float hp[3][6], nv[2][6], iv[6], wap[6], wan[6];
    #pragma unroll
    for (int q = 0; q < 6; ++q) {
        int d = lane + 64 * q;
        wap[q] = w_ap[d]; wan[q] = w_an[d];
        iv[q] = init_f[(size_t)gb * DD + d];
    }
    float lp[3], ln2[2];
    #pragma unroll
    for (int j = 0; j < 3; ++j) {
        float p = 0.f;
        #pragma unroll
        for (int q = 0; q < 6; ++q) {
            int d = lane + 64 * q;
            size_t off = ((size_t)j * B_TOT + gb) * DD + d;
            float v = head[off] + pred[off];
            hp[j][q] = v;
            p += v * wap[q];
        }
        lp[j] = wave_red_sum(p) + b_ap[0];
    }
    #pragma unroll
    for (int j = 0; j < 2; ++j) {
        float p = 0.f;
        #pragma unroll
        for (int q = 0; q < 6; ++q) {
            int d = lane + 64 * q;
            float v = bf2f(nf[((size_t)j * Bc + lb) * DD + d]);
            nv[j][q] = v;
            p += v * wan[q];
        }
        ln2[j] = wave_red_sum(p) + b_an[0];
    }
    float mp = fmaxf(lp[0], fmaxf(lp[1], lp[2]));
    float e0 = expf(lp[0]-mp), e1 = expf(lp[1]-mp), e2 = expf(lp[2]-mp);
    float sp = e0 + e1 + e2;
    float awp[3] = {e0/sp, e1/sp, e2/sp};
    float mn = fmaxf(ln2[0], ln2[1]);
    float f0 = expf(ln2[0]-mn), f1 = expf(ln2[1]-mn);
    float sn = f0 + f1;
    float awn[2] = {f0/sn, f1/sn};

    #pragma unroll
    for (int t = 0; t < SS; ++t) {
        float rowv[6], ss = 0.f;
        #pragma unroll
        for (int q = 0; q < 6; ++q) {
            float v;
            if (t == 0)      v = iv[q];
            else if (t <= 3) v = hp[t-1][q] * awp[t-1];
            else             v = nv[t-4][q] * awn[t-4];
            rowv[q] = v;
            ss += v * v;
        }
        ss = wave_red_sum(ss);
        float sc = rsqrtf(ss / (float)DD + 1e-6f);
        float* xr = x + (size_t)(t * Bc + lb) * DD;
        ushort_t* hr = hb + (size_t)(t * Bc + lb) * DD;
        #pragma unroll
        for (int q = 0; q < 6; ++q) {
            int d = lane + 64 * q;
            xr[d] = rowv[q];
            hr[d] = f2bf(rowv[q] * g1[d] * sc);
        }
    }
}

__global__ void rms_k(const float* __restrict__ x, const float* __restrict__ g,
                      ushort_t* __restrict__ h)
{
    int row  = blockIdx.x * 4 + (threadIdx.x >> 6);
    int lane = threadIdx.x & 63;
    const float* xr = x + (size_t)row * DD;
    float ss = 0.f;
    for (int d = lane; d < DD; d += 64) { float v = xr[d]; ss += v * v; }
    ss = wave_red_sum(ss);
    float sc = rsqrtf(ss / (float)DD + 1e-6f);
    ushort_t* hr = h + (size_t)row * DD;
    for (int d = lane; d < DD; d += 64) hr[d] = f2bf(xr[d] * g[d] * sc);
}

__global__ void wproj_k(const float* __restrict__ fa_wo, const float* __restrict__ fa_wl,
                        float* __restrict__ wproj)
{
    int d = threadIdx.x;  // 384 threads
    float s = 0.f;
    for (int k = 0; k < DD; ++k) s += fa_wo[(size_t)d * DD + k] * fa_wl[k];
    wproj[d] = s;
}

// logits from 6 partials; softmax over S; out = (1/6) sum_t x_t * w_t
__global__ void final_k(const float* __restrict__ x, const float* __restrict__ lp,
                        const float* __restrict__ fa_bl,
                        float* __restrict__ out, int b0, int Bc)
{
    const int lb = blockIdx.x, gb = b0 + lb, lane = threadIdx.x;
    float lg[SS];
    #pragma unroll
    for (int t = 0; t < SS; ++t) {
        const float* pp = lp + (size_t)(t * Bc + lb) * 6;
        lg[t] = pp[0] + pp[1] + pp[2] + pp[3] + pp[4] + pp[5] + fa_bl[0];
    }
    float m = lg[0];
    #pragma unroll
    for (int t = 1; t < SS; ++t) m = fmaxf(m, lg[t]);
    float e[SS], s = 0.f;
    #pragma unroll
    for (int t = 0; t < SS; ++t) { e[t] = expf(lg[t] - m); s += e[t]; }
    float inv = 1.0f / s;
    #pragma unroll
    for (int q = 0; q < 6; ++q) {
        int d = lane + 64 * q;
        float acc = 0.f;
        #pragma unroll
        for (int t = 0; t < SS; ++t)
            acc += x[(size_t)(t * Bc + lb) * DD + d] * (e[t] * inv);
        out[(size_t)gb * DD + d] = acc * (1.0f / 6.0f);
    }
}

// ---------------------------------------------------------------- launch
extern "C" void kernel_launch(void* const* d_in, const int* in_sizes, int n_in,
                              void* d_out, int out_size, void* d_ws, size_t ws_size,
                              hipStream_t stream)
{
    (void)in_sizes; (void)n_in; (void)out_size;
    const float* init_f  = (const float*)d_in[0];
    const float* head    = (const float*)d_in[1];
    const float* pred    = (const float*)d_in[2];
    const float* w_ap    = (const float*)d_in[3];
    const float* b_ap    = (const float*)d_in[4];
    const float* w_an    = (const float*)d_in[5];
    const float* b_an    = (const float*)d_in[6];
    const float* nt_w1   = (const float*)d_in[7];
    const float* nt_b1   = (const float*)d_in[8];
    const float* nt_w2   = (const float*)d_in[9];
    const float* nt_b2   = (const float*)d_in[10];
    const float* g1      = (const float*)d_in[11];
    const float* rg_wx   = (const float*)d_in[12];
    const float* rg_bx   = (const float*)d_in[13];
    const float* rg_wy   = (const float*)d_in[14];
    const float* rg_by   = (const float*)d_in[15];
    const float* rg_wr   = (const float*)d_in[16];
    const float* rg_br   = (const float*)d_in[17];
    const float* rg_wi   = (const float*)d_in[18];
    const float* rg_bi   = (const float*)d_in[19];
    const float* rg_lam  = (const float*)d_in[20];
    const float* rg_wo   = (const float*)d_in[21];
    const float* rg_bo   = (const float*)d_in[22];
    const float* g2      = (const float*)d_in[23];
    const float* mlp_wg  = (const float*)d_in[24];
    const float* mlp_wv  = (const float*)d_in[25];
    const float* mlp_wo  = (const float*)d_in[26];
    const float* fa_wg   = (const float*)d_in[27];
    const float* fa_wv   = (const float*)d_in[28];
    const float* fa_wo   = (const float*)d_in[29];
    const float* fa_wl   = (const float*)d_in[30];
    const float* fa_bl   = (const float*)d_in[31];
    float* out = (float*)d_out;

    float* ws_f    = (float*)d_ws;
    float* wproj   = ws_f;                 // 512 f32 slot
    float* bias_xy = ws_f + 512;           // 1024
    float* a2      = ws_f + 1536;          // 512
    ushort_t* wt   = (ushort_t*)(ws_f + 2048);

    // bf16 transposed weights (offsets in bf16 elems)
    ushort_t* ntw1T = wt + 0;
    ushort_t* ntw2T = wt + 393216;
    ushort_t* wxyT  = wt + 786432;
    ushort_t* wrT   = wt + 1179648;
    ushort_t* wiT   = wt + 1441792;
    ushort_t* woT   = wt + 1703936;
    ushort_t* mwgT  = wt + 1900544;
    ushort_t* mwvT  = wt + 2342912;
    ushort_t* mwoT  = wt + 2785280;
    ushort_t* fwgT  = wt + 3227648;
    ushort_t* fwvT  = wt + 3375104;       // end 3522560 bf16 = 1761280 f32

    struct WSpec { const float* W; ushort_t* WT; int K, N; };
    const WSpec specs[12] = {
        {nt_w1, ntw1T, DD, HH}, {nt_w2, ntw2T, HH, DD},
        {rg_wx, wxyT, DD, DRR}, {rg_wy, wxyT + 512*384, DD, DRR},
        {rg_wr, wrT, DRR, DRR}, {rg_wi, wiT, DRR, DRR}, {rg_wo, woT, DRR, DD},
        {mlp_wg, mwgT, DD, DMM}, {mlp_wv, mwvT, DD, DMM}, {mlp_wo, mwoT, DMM, DD},
        {fa_wg, fwgT, DD, DD}, {fa_wv, fwvT, DD, DD},
    };
    for (int i = 0; i < 12; ++i) {
        int e = specs[i].K * specs[i].N;
        tr_k<<<(e + 255) / 256, 256, 0, stream>>>(specs[i].W, specs[i].WT,
                                                  specs[i].K, specs[i].N);
    }
    prep_k<<<4, 256, 0, stream>>>(rg_bx, rg_by, rg_lam, bias_xy, a2);
    wproj_k<<<1, DD, 0, stream>>>(fa_wo, fa_wl, wproj);

    const size_t fixed_f32 = 2048 + 1761280;
    const size_t per_b_f32 = 16768;
    int Bc = B_TOT;
    while (Bc > 128 && (fixed_f32 + per_b_f32 * (size_t)Bc) * 4 > ws_size) Bc >>= 1;

    float* arena = ws_f + fixed_f32;

    for (int b0 = 0; b0 < B_TOT; b0 += Bc) {
        const int M  = Bc * SS;
        const int M2 = Bc * KNN;
        float*    xbuf = arena;                                   // 2304*Bc f32
        ushort_t* xh   = (ushort_t*)(arena + (size_t)2304  * Bc); // M*384 bf16
        ushort_t* hb   = (ushort_t*)(arena + (size_t)3456  * Bc); // M*384 bf16
        ushort_t* negm = (ushort_t*)(arena + (size_t)4608  * Bc); // M2*384 bf16
        ushort_t* hid  = (ushort_t*)(arena + (size_t)4992  * Bc); // M2*1024 bf16
        ushort_t* nf   = (ushort_t*)(arena + (size_t)6016  * Bc); // M2*384 bf16
        ushort_t* uh   = (ushort_t*)(arena + (size_t)6400  * Bc); // M*512 bf16
        ushort_t* gth  = (ushort_t*)(arena + (size_t)7936  * Bc); // M*512 bf16
        ushort_t* pr   = (ushort_t*)(arena + (size_t)9472  * Bc); // M*512 bf16
        ushort_t* h2   = (ushort_t*)(arena + (size_t)11008 * Bc); // M*384 bf16
        ushort_t* Th   = (ushort_t*)(arena + (size_t)12160 * Bc); // M*1152 bf16
        float*    lpb  = arena + (size_t)15616 * Bc;              // M*6 f32

        // stage 1: neg messages + MLP residual + attention assembly (+rms g1)
        negm_k<<<Bc * 3, 256, 0, stream>>>(head, pred, negm, b0, Bc);
        bgemm<1, false><<<dim3(HH/128, M2/128), 256, 0, stream>>>(
            negm, ntw1T, nt_b1, nullptr, nullptr, hid, nullptr, M2, HH, DD);
        bgemm<4, false><<<dim3(DD/128, M2/128), 256, 0, stream>>>(
            hid, ntw2T, nt_b2, negm, nullptr, nf, nullptr, M2, DD, HH);
        asmrms_k<<<Bc, 64, 0, stream>>>(init_f, head, pred, w_ap, b_ap, w_an, b_an,
                                        nf, g1, xbuf, hb, b0, Bc);

        // Griffin recurrent branch
        bgemm<7, false><<<dim3(1024/128, M/128), 256, 0, stream>>>(
            hb, wxyT, bias_xy, nullptr, nullptr, uh, gth, M, 1024, DD);
        rgri_rec_k<<<dim3(DRR/64, Bc/128), 256, 0, stream>>>(
            uh, gth, wrT, wiT, rg_br, rg_bi, a2, pr, Bc);
        bgemm<0, true><<<dim3(DD/128, M/128), 256, 0, stream>>>(
            pr, woT, rg_bo, nullptr, xbuf, nullptr, nullptr, M, DD, DRR);

        // gated-MLP residual branch
        rms_k<<<M / 4, 256, 0, stream>>>(xbuf, g2, h2);
        dual_k<false><<<dim3(DMM/64, M/128), 256, 0, stream>>>(
            h2, mwgT, mwvT, Th, nullptr, nullptr, M, DMM, DD);
        bgemm<0, true><<<dim3(DD/128, M/128), 256, 0, stream>>>(
            Th, mwoT, nullptr, nullptr, xbuf, xh, nullptr, M, DD, DMM);

        // final attention: fused dual-GEMM -> per-row logit partials (no Afa)
        dual_k<true><<<dim3(DD/64, M/128), 256, 0, stream>>>(
            xh, fwgT, fwvT, nullptr, lpb, wproj, M, DD, DD);
        final_k<<<Bc, 64, 0, stream>>>(xbuf, lpb, fa_bl, out, b0, Bc);
    }
}

// Round 5
// 1865.924 us; speedup vs baseline: 2.3502x; 2.3502x over previous
//
#include <hip/hip_runtime.h>
#include <hip/hip_bf16.h>

// Problem constants (from reference)
#define B_TOT 16384
#define DD    384
#define HH    1024
#define DRR   512
#define DMM   1152
#define SS    6     // 1 + KP + KN
#define KPP   3
#define KNN   2

typedef unsigned short ushort_t;
typedef __bf16 bf16x8 __attribute__((ext_vector_type(8)));
typedef float  f32x4  __attribute__((ext_vector_type(4)));

#define CST 136   // bgemm epilogue LDS stride (bf16)
#define EPW 72    // dual epilogue LDS stride

// ---------------------------------------------------------------- helpers
__device__ __forceinline__ float gelu_f(float x) {
    float x3 = x * x * x;
    return 0.5f * x * (1.0f + tanhf(0.7978845608028654f * (x + 0.044715f * x3)));
}
__device__ __forceinline__ float sigmoid_f(float x) {
    return 1.0f / (1.0f + expf(-x));
}
__device__ __forceinline__ float wave_red_sum(float v) {
    #pragma unroll
    for (int off = 32; off; off >>= 1) v += __shfl_xor(v, off);
    return v;
}
__device__ __forceinline__ ushort_t f2bf(float v) {
    __hip_bfloat16 h = __float2bfloat16(v);
    return *reinterpret_cast<ushort_t*>(&h);
}
__device__ __forceinline__ float bf2f(ushort_t u) {
    unsigned int x = ((unsigned int)u) << 16;
    return __uint_as_float(x);
}
// async global->LDS, 16B per lane; LDS dest = wave-uniform base + lane*16
__device__ __forceinline__ void g2l16(const ushort_t* g, ushort_t* l) {
    __builtin_amdgcn_global_load_lds(
        (const __attribute__((address_space(1))) void*)g,
        (__attribute__((address_space(3))) void*)l, 16, 0, 0);
}
// XCD-aware bijective block swizzle
__device__ __forceinline__ void swz_xy(int& bx, int& by) {
    const int nx = gridDim.x;
    const int nwg = nx * gridDim.y;
    const int h = by * nx + bx;
    const int q = nwg >> 3, r = nwg & 7;
    const int xcd = h & 7, lo = h >> 3;
    const int lin = (xcd < r) ? (xcd * (q + 1) + lo)
                              : (r * (q + 1) + (xcd - r) * q + lo);
    bx = lin % nx;
    by = lin / nx;
}

// ---------------------------------------------------------------- MFMA GEMM
// C[M,N] = epi( A[M,K](bf16) @ WT[N,K](bf16)^T + bias )
// EPI: 0 none, 1 relu, 4 v - X2(bf16), 7 split-xy (c<512 -> Ch, else gelu -> Ch2)
// global_load_lds dbuf: A0@0 A1@8192 B0@16384 B1@24576 (ushort units; 64 KiB)
// LDS linear rows of 64 elems, XOR-swizzled chunks: phys_chunk = chunk ^ (row&7)
template<int EPI, bool ACCUM>
__global__ __launch_bounds__(256, 2)
void bgemm(const ushort_t* __restrict__ A, const ushort_t* __restrict__ WT,
           const float* __restrict__ bias, const ushort_t* __restrict__ X2,
           float* __restrict__ C, ushort_t* __restrict__ Ch, ushort_t* __restrict__ Ch2,
           int M, int N, int K)
{
    __shared__ ushort_t sm[32768];

    int bx = blockIdx.x, by = blockIdx.y;
    swz_xy(bx, by);
    const int tid = threadIdx.x;
    const int l = tid & 63, w = tid >> 6;
    const int wr = w >> 1, wc = w & 1;
    const int lr = l & 15, hi = l >> 4;
    const int row0 = by * 128, col0 = bx * 128;

    // staging: wave w, instr i -> rows (w*4+i)*8 + l/8, swizzled source chunk
    const int lrw = l >> 3;
    const int lch = (l & 7) ^ (lrw & 7);
    const ushort_t* As[4]; const ushort_t* Bs[4]; int lo_[4];
    #pragma unroll
    for (int i = 0; i < 4; ++i) {
        const int g = w * 4 + i;
        As[i] = A  + (size_t)(row0 + g*8 + lrw) * K + lch * 8;
        Bs[i] = WT + (size_t)(col0 + g*8 + lrw) * K + lch * 8;
        lo_[i] = g * 512;
    }
    const int ko[2] = {(hi*8) ^ ((lr&7)*8), (32 + hi*8) ^ ((lr&7)*8)};

    f32x4 acc[4][4] = {};
    const int NT = K >> 6;

    #pragma unroll
    for (int i = 0; i < 4; ++i) {
        g2l16(As[i], &sm[lo_[i]]);
        g2l16(Bs[i], &sm[16384 + lo_[i]]);
    }
    __syncthreads();

    int db = 0;
    for (int t = 0; t < NT; ++t) {
        if (t + 1 < NT) {
            const int nb = db ^ 1;
            #pragma unroll
            for (int i = 0; i < 4; ++i) {
                g2l16(As[i] + (size_t)(t+1)*64, &sm[nb*8192 + lo_[i]]);
                g2l16(Bs[i] + (size_t)(t+1)*64, &sm[16384 + nb*8192 + lo_[i]]);
            }
        }
        #pragma unroll
        for (int ks = 0; ks < 2; ++ks) {
            bf16x8 af[4], bfr[4];
            #pragma unroll
            for (int m = 0; m < 4; ++m)
                af[m] = *(const bf16x8*)&sm[db*8192 + (wr*64 + m*16 + lr)*64 + ko[ks]];
            #pragma unroll
            for (int n = 0; n < 4; ++n)
                bfr[n] = *(const bf16x8*)&sm[16384 + db*8192 + (wc*64 + n*16 + lr)*64 + ko[ks]];
            #pragma unroll
            for (int m = 0; m < 4; ++m)
                #pragma unroll
                for (int n = 0; n < 4; ++n)
                    acc[m][n] = __builtin_amdgcn_mfma_f32_16x16x32_bf16(
                        af[m], bfr[n], acc[m][n], 0, 0, 0);
        }
        __syncthreads();
        db ^= 1;
    }

    // epilogue: C/D frag mapping col = l&15, row = (l>>4)*4 + j
    const bool BF = (EPI == 7) || (Ch != nullptr);
    #pragma unroll
    for (int m = 0; m < 4; ++m) {
        #pragma unroll
        for (int n = 0; n < 4; ++n) {
            const int r0 = row0 + wr*64 + m*16 + hi*4;
            const int c  = col0 + wc*64 + n*16 + lr;
            const float bv = bias ? bias[c] : 0.f;
            #pragma unroll
            for (int j = 0; j < 4; ++j) {
                const int r = r0 + j;
                float v = acc[m][n][j] + bv;
                if (EPI == 1) v = fmaxf(v, 0.f);
                if (EPI == 4) v = v - bf2f(X2[(size_t)r * N + c]);
                if (ACCUM)    v += C[(size_t)r * N + c];
                if (C) C[(size_t)r * N + c] = v;
                if (BF) {
                    float ov = (EPI == 7 && c >= 512) ? gelu_f(v) : v;
                    sm[(wr*64 + m*16 + hi*4 + j) * CST + wc*64 + n*16 + lr] = f2bf(ov);
                }
            }
        }
    }
    if (BF) {
        __syncthreads();
        const int er = tid >> 1, ec = (tid & 1) * 64;
        ushort_t* dst; int nn, dc0;
        if (EPI == 7) {
            nn = 512;
            if (col0 < 512) { dst = Ch;  dc0 = col0; }
            else            { dst = Ch2; dc0 = col0 - 512; }
        } else { dst = Ch; nn = N; dc0 = col0; }
        const uint4* sp = (const uint4*)&sm[er * CST + ec];
        uint4* gp = (uint4*)(dst + (size_t)(row0 + er) * nn + dc0 + ec);
        #pragma unroll
        for (int q = 0; q < 8; ++q) gp[q] = sp[q];
    }
}

// ---------------------------------------------------------------- dual-B GEMM
// LOGITS=false: Ch[M,N] = gelu(A@W1T^T) * (A@W2T^T)
// LOGITS=true : LP[r*6+bx] = sum over this block's 64 cols of gelu(G)*V*wproj[c]
// LDS: A0@0 A1@8192 G0@16384 G1@20480 V0@24576 V1@28672 (64 KiB)
template<bool LOGITS>
__global__ __launch_bounds__(256, 2)
void dual_k(const ushort_t* __restrict__ A, const ushort_t* __restrict__ W1T,
            const ushort_t* __restrict__ W2T, ushort_t* __restrict__ Ch,
            float* __restrict__ LP, const float* __restrict__ wproj,
            int M, int N, int K)
{
    __shared__ ushort_t sm[32768];

    int bx = blockIdx.x, by = blockIdx.y;
    swz_xy(bx, by);
    const int tid = threadIdx.x;
    const int l = tid & 63, w = tid >> 6;
    const int wr = w >> 1, wc = w & 1;
    const int lr = l & 15, hi = l >> 4;
    const int row0 = by * 128, col0 = bx * 64;

    const int lrw = l >> 3;
    const int lch = (l & 7) ^ (lrw & 7);
    const ushort_t* As[4]; int loA[4];
    #pragma unroll
    for (int i = 0; i < 4; ++i) {
        const int g = w * 4 + i;
        As[i] = A + (size_t)(row0 + g*8 + lrw) * K + lch * 8;
        loA[i] = g * 512;
    }
    const ushort_t* Gs[2]; const ushort_t* Vs[2]; int loB[2];
    #pragma unroll
    for (int i = 0; i < 2; ++i) {
        const int g = w * 2 + i;
        Gs[i] = W1T + (size_t)(col0 + g*8 + lrw) * K + lch * 8;
        Vs[i] = W2T + (size_t)(col0 + g*8 + lrw) * K + lch * 8;
        loB[i] = g * 512;
    }
    const int ko[2] = {(hi*8) ^ ((lr&7)*8), (32 + hi*8) ^ ((lr&7)*8)};

    f32x4 ag[4][2] = {}, av[4][2] = {};
    const int NT = K >> 6;

    #pragma unroll
    for (int i = 0; i < 4; ++i) g2l16(As[i], &sm[loA[i]]);
    #pragma unroll
    for (int i = 0; i < 2; ++i) {
        g2l16(Gs[i], &sm[16384 + loB[i]]);
        g2l16(Vs[i], &sm[24576 + loB[i]]);
    }
    __syncthreads();

    int db = 0;
    for (int t = 0; t < NT; ++t) {
        if (t + 1 < NT) {
            const int nb = db ^ 1;
            #pragma unroll
            for (int i = 0; i < 4; ++i)
                g2l16(As[i] + (size_t)(t+1)*64, &sm[nb*8192 + loA[i]]);
            #pragma unroll
            for (int i = 0; i < 2; ++i) {
                g2l16(Gs[i] + (size_t)(t+1)*64, &sm[16384 + nb*4096 + loB[i]]);
                g2l16(Vs[i] + (size_t)(t+1)*64, &sm[24576 + nb*4096 + loB[i]]);
            }
        }
        #pragma unroll
        for (int ks = 0; ks < 2; ++ks) {
            bf16x8 af[4], bg[2], bv[2];
            #pragma unroll
            for (int m = 0; m < 4; ++m)
                af[m] = *(const bf16x8*)&sm[db*8192 + (wr*64 + m*16 + lr)*64 + ko[ks]];
            #pragma unroll
            for (int n = 0; n < 2; ++n) {
                bg[n] = *(const bf16x8*)&sm[16384 + db*4096 + (wc*32 + n*16 + lr)*64 + ko[ks]];
                bv[n] = *(const bf16x8*)&sm[24576 + db*4096 + (wc*32 + n*16 + lr)*64 + ko[ks]];
            }
            #pragma unroll
            for (int m = 0; m < 4; ++m)
                #pragma unroll
                for (int n = 0; n < 2; ++n) {
                    ag[m][n] = __builtin_amdgcn_mfma_f32_16x16x32_bf16(af[m], bg[n], ag[m][n], 0, 0, 0);
                    av[m][n] = __builtin_amdgcn_mfma_f32_16x16x32_bf16(af[m], bv[n], av[m][n], 0, 0, 0);
                }
        }
        __syncthreads();
        db ^= 1;
    }

    if (!LOGITS) {
        #pragma unroll
        for (int m = 0; m < 4; ++m)
            #pragma unroll
            for (int n = 0; n < 2; ++n)
                #pragma unroll
                for (int j = 0; j < 4; ++j)
                    sm[(wr*64 + m*16 + hi*4 + j) * EPW + wc*32 + n*16 + lr] =
                        f2bf(gelu_f(ag[m][n][j]) * av[m][n][j]);
        __syncthreads();
        const int er = tid >> 1, ec = (tid & 1) * 32;
        const uint4* sp = (const uint4*)&sm[er * EPW + ec];
        uint4* gp = (uint4*)(Ch + (size_t)(row0 + er) * N + col0 + ec);
        #pragma unroll
        for (int q = 0; q < 4; ++q) gp[q] = sp[q];
    } else {
        float wp[2];
        #pragma unroll
        for (int n = 0; n < 2; ++n) wp[n] = wproj[col0 + wc*32 + n*16 + lr];
        float* red = (float*)sm;   // [128][2]
        #pragma unroll
        for (int m = 0; m < 4; ++m) {
            #pragma unroll
            for (int j = 0; j < 4; ++j) {
                float s = 0.f;
                #pragma unroll
                for (int n = 0; n < 2; ++n)
                    s += gelu_f(ag[m][n][j]) * av[m][n][j] * wp[n];
                s += __shfl_xor(s, 1);
                s += __shfl_xor(s, 2);
                s += __shfl_xor(s, 4);
                s += __shfl_xor(s, 8);
                if (lr == 0) red[(wr*64 + m*16 + hi*4 + j) * 2 + wc] = s;
            }
        }
        __syncthreads();
        if (tid < 128)
            LP[(size_t)(row0 + tid) * 6 + bx] = red[tid*2] + red[tid*2 + 1];
    }
}

// ---------------------------------------------------------------- fused rgri+rec
// 64(b-rows) x 64(d-cols) block, 4 waves (wave w owns cols w*16..+16 of all 64 rows).
// Per t: 8 K-tiles of the r/i GEMMs (dbuf, 1 barrier/tile, cross-t prefetch),
// then in-register sigmoid + RG-LRU recurrence; prod = h*gate (bf16).
// LDS: A0@0 A1@4096 R0@8192 R1@12288 I0@16384 I1@20480 (48 KiB)
__global__ __launch_bounds__(256, 3)
void rgri_rec_k(const ushort_t* __restrict__ u, const ushort_t* __restrict__ gate,
                const ushort_t* __restrict__ wrT, const ushort_t* __restrict__ wiT,
                const float* __restrict__ br, const float* __restrict__ bi,
                const float* __restrict__ a2, ushort_t* __restrict__ prod, int Bc)
{
    __shared__ ushort_t sm[24576];

    int bx = blockIdx.x, by = blockIdx.y;
    swz_xy(bx, by);
    const int tid = threadIdx.x;
    const int l = tid & 63, w = tid >> 6;
    const int lr = l & 15, hi = l >> 4;
    const int c0 = bx * 64, b0r = by * 64;

    const int lrw = l >> 3;
    const int lch = (l & 7) ^ (lrw & 7);
    size_t Ao[2]; const ushort_t* Rs[2]; const ushort_t* Is[2]; int lo_[2];
    #pragma unroll
    for (int i = 0; i < 2; ++i) {
        const int g = w * 2 + i;
        Ao[i] = (size_t)(b0r + g*8 + lrw) * DRR + lch * 8;
        Rs[i] = wrT + (size_t)(c0 + g*8 + lrw) * DRR + lch * 8;
        Is[i] = wiT + (size_t)(c0 + g*8 + lrw) * DRR + lch * 8;
        lo_[i] = g * 512;
    }
    const int ko[2] = {(hi*8) ^ ((lr&7)*8), (32 + hi*8) ^ ((lr&7)*8)};
    const int c = c0 + w*16 + lr;
    const float a2v = a2[c], brv = br[c], biv = bi[c];
    f32x4 h4[4] = {};

    int db = 0;
    {   // prologue: t=0, kt=0
        #pragma unroll
        for (int i = 0; i < 2; ++i) {
            g2l16(u + Ao[i], &sm[lo_[i]]);
            g2l16(Rs[i], &sm[8192  + lo_[i]]);
            g2l16(Is[i], &sm[16384 + lo_[i]]);
        }
    }
    __syncthreads();

    for (int t = 0; t < SS; ++t) {
        f32x4 ar[4] = {}, ai[4] = {};
        for (int kt = 0; kt < 8; ++kt) {
            const int s = t*8 + kt;
            if (s + 1 < SS*8) {
                const int t2 = (s+1) >> 3, kt2 = (s+1) & 7;
                const int nb = db ^ 1;
                #pragma unroll
                for (int i = 0; i < 2; ++i) {
                    g2l16(u + (size_t)t2 * Bc * DRR + Ao[i] + kt2*64, &sm[nb*4096 + lo_[i]]);
                    g2l16(Rs[i] + kt2*64, &sm[8192  + nb*4096 + lo_[i]]);
                    g2l16(Is[i] + kt2*64, &sm[16384 + nb*4096 + lo_[i]]);
                }
            }
            #pragma unroll
            for (int ks = 0; ks < 2; ++ks) {
                bf16x8 af[4];
                #pragma unroll
                for (int m = 0; m < 4; ++m)
                    af[m] = *(const bf16x8*)&sm[db*4096 + (m*16 + lr)*64 + ko[ks]];
                bf16x8 brf = *(const bf16x8*)&sm[8192  + db*4096 + (w*16 + lr)*64 + ko[ks]];
                bf16x8 bif = *(const bf16x8*)&sm[16384 + db*4096 + (w*16 + lr)*64 + ko[ks]];
                #pragma unroll
                for (int m = 0; m < 4; ++m) {
                    ar[m] = __builtin_amdgcn_mfma_f32_16x16x32_bf16(af[m], brf, ar[m], 0, 0, 0);
                    ai[m] = __builtin_amdgcn_mfma_f32_16x16x32_bf16(af[m], bif, ai[m], 0, 0, 0);
                }
            }
            __syncthreads();
            db ^= 1;
        }
        // recurrence (fp32 in-register); LDS untouched so next-t prefetch survives
        #pragma unroll
        for (int m = 0; m < 4; ++m) {
            #pragma unroll
            for (int j = 0; j < 4; ++j) {
                const int b = b0r + m*16 + hi*4 + j;
                const size_t idx = (size_t)(t*Bc + b)*DRR + c;
                const float rv = sigmoid_f(ar[m][j] + brv);
                const float iv = sigmoid_f(ai[m][j] + biv);
                const float e  = exp2f(a2v * rv);
                const float uu = bf2f(u[idx]);
                const float hv = e * h4[m][j]
                               + sqrtf(fmaxf(0.f, 1.f - e * e)) * (iv * uu);
                h4[m][j] = hv;
                prod[idx] = f2bf(hv * bf2f(gate[idx]));
            }
        }
    }
}

// ---------------------------------------------------------------- small kernels

// one-shot tiled transpose+convert of all 12 weights: WT[n*K+k] = bf16(W[k*N+n])
struct TrArgs { const float* W[12]; };
__global__ void tr_all_k(TrArgs a, ushort_t* __restrict__ wt)
{
    constexpr int KT[12]  = {384,1024,384,384,512,512,512,384,384,1152,384,384};
    constexpr int NTb[12] = {1024,384,512,512,512,512,384,1152,1152,384,384,384};
    constexpr int EOFF[12]= {0,393216,786432,983040,1179648,1441792,1703936,
                             1900544,2342912,2785280,3227648,3375104};
    constexpr int TPRE[13]= {0,384,768,960,1152,1408,1664,1856,2288,2720,3152,3296,3440};
    const int tb = blockIdx.x;
    int s = 0;
    #pragma unroll
    for (int i = 0; i < 12; ++i) if (tb >= TPRE[i+1]) s = i + 1;
    const int rel = tb - TPRE[s];
    const int K = KT[s], N = NTb[s];
    const int ntn = N >> 5;
    const int k0 = (rel / ntn) * 32, n0 = (rel % ntn) * 32;

    __shared__ float ts[32][33];
    const int r = threadIdx.x >> 3, c4 = (threadIdx.x & 7) * 4;
    const float4 v = *(const float4*)&a.W[s][(size_t)(k0 + r) * N + n0 + c4];
    ts[r][c4+0] = v.x; ts[r][c4+1] = v.y; ts[r][c4+2] = v.z; ts[r][c4+3] = v.w;
    __syncthreads();
    ushort_t o4[4];
    #pragma unroll
    for (int q = 0; q < 4; ++q) o4[q] = f2bf(ts[c4 + q][r]);
    *(uint2*)&wt[EOFF[s] + (size_t)(n0 + r) * K + k0 + c4] = *(const uint2*)o4;
}

__global__ void prep_k(const float* __restrict__ rg_bx, const float* __restrict__ rg_by,
                       const float* __restrict__ rg_lam,
                       float* __restrict__ bias_xy, float* __restrict__ a2)
{
    int i = blockIdx.x * 256 + threadIdx.x;
    if (i < 512) {
        bias_xy[i] = rg_bx[i];
        float lam = rg_lam[i];
        float sp = (lam > 20.f) ? lam : log1pf(expf(lam));
        a2[i] = -8.0f * sp * 1.4426950408889634f;
    } else if (i < 1024) {
        bias_xy[i] = rg_by[i - 512];
    }
}

__global__ void negm_k(const float* __restrict__ head, const float* __restrict__ pred,
                       ushort_t* __restrict__ negm_h, int b0, int Bc)
{
    int idx = blockIdx.x * 256 + threadIdx.x;        // < Bc*2*384
    int d = idx % DD, rr = idx / DD;
    int j = (rr >= Bc) ? 1 : 0;
    int b = rr - j * Bc;
    size_t off = ((size_t)(KPP + j) * B_TOT + (b0 + b)) * DD + d;
    negm_h[idx] = f2bf(head[off] + pred[off]);
}

// grouped softmax attn + assemble x rows (t-major) + rmsnorm(g1) -> hb bf16
__global__ void asmrms_k(const float* __restrict__ init_f,
                         const float* __restrict__ head, const float* __restrict__ pred,
                         const float* __restrict__ w_ap, const float* __restrict__ b_ap,
                         const float* __restrict__ w_an, const float* __restrict__ b_an,
                         const ushort_t* __restrict__ nf, const float* __restrict__ g1,
                         float* __restrict__ x, ushort_t* __restrict__ hb,
                         int b0, int Bc)
{
    const int lb = blockIdx.x, gb = b0 + lb, lane = threadIdx.x;
    float hp[3][6], nv[2][6], iv[6], wap[6], wan[6];
    #pragma unroll
    for (int q = 0; q < 6; ++q) {
        int d = lane + 64 * q;
        wap[q] = w_ap[d]; wan[q] = w_an[d];
        iv[q] = init_f[(size_t)gb * DD + d];
    }
    float lp[3], ln2[2];
    #pragma unroll
    for (int j = 0; j < 3; ++j) {
        float p = 0.f;
        #pragma unroll
        for (int q = 0; q < 6; ++q) {
            int d = lane + 64 * q;
            size_t off = ((size_t)j * B_TOT + gb) * DD + d;
            float v = head[off] + pred[off];
            hp[j][q] = v;
            p += v * wap[q];
        }
        lp[j] = wave_red_sum(p) + b_ap[0];
    }
    #pragma unroll
    for (int j = 0; j < 2; ++j) {
        float p = 0.f;
        #pragma unroll
        for (int q = 0; q < 6; ++q) {
            int d = lane + 64 * q;
            float v = bf2f(nf[((size_t)j * Bc + lb) * DD + d]);
            nv[j][q] = v;
            p += v * wan[q];
        }
        ln2[j] = wave_red_sum(p) + b_an[0];
    }
    float mp = fmaxf(lp[0], fmaxf(lp[1], lp[2]));
    float e0 = expf(lp[0]-mp), e1 = expf(lp[1]-mp), e2 = expf(lp[2]-mp);
    float sp = e0 + e1 + e2;
    float awp[3] = {e0/sp, e1/sp, e2/sp};
    float mn = fmaxf(ln2[0], ln2[1]);
    float f0 = expf(ln2[0]-mn), f1 = expf(ln2[1]-mn);
    float sn = f0 + f1;
    float awn[2] = {f0/sn, f1/sn};

    #pragma unroll
    for (int t = 0; t < SS; ++t) {
        float rowv[6], ss = 0.f;
        #pragma unroll
        for (int q = 0; q < 6; ++q) {
            float v;
            if (t == 0)      v = iv[q];
            else if (t <= 3) v = hp[t-1][q] * awp[t-1];
            else             v = nv[t-4][q] * awn[t-4];
            rowv[q] = v;
            ss += v * v;
        }
        ss = wave_red_sum(ss);
        float sc = rsqrtf(ss / (float)DD + 1e-6f);
        float* xr = x + (size_t)(t * Bc + lb) * DD;
        ushort_t* hr = hb + (size_t)(t * Bc + lb) * DD;
        #pragma unroll
        for (int q = 0; q < 6; ++q) {
            int d = lane + 64 * q;
            xr[d] = rowv[q];
            hr[d] = f2bf(rowv[q] * g1[d] * sc);
        }
    }
}

__global__ void rms_k(const float* __restrict__ x, const float* __restrict__ g,
                      ushort_t* __restrict__ h)
{
    int row  = blockIdx.x * 4 + (threadIdx.x >> 6);
    int lane = threadIdx.x & 63;
    const float* xr = x + (size_t)row * DD;
    float ss = 0.f;
    for (int d = lane; d < DD; d += 64) { float v = xr[d]; ss += v * v; }
    ss = wave_red_sum(ss);
    float sc = rsqrtf(ss / (float)DD + 1e-6f);
    ushort_t* hr = h + (size_t)row * DD;
    for (int d = lane; d < DD; d += 64) hr[d] = f2bf(xr[d] * g[d] * sc);
}

__global__ void wproj_k(const float* __restrict__ fa_wo, const float* __restrict__ fa_wl,
                        float* __restrict__ wproj)
{
    int d = threadIdx.x;  // 384 threads
    float s = 0.f;
    for (int k = 0; k < DD; ++k) s += fa_wo[(size_t)d * DD + k] * fa_wl[k];
    wproj[d] = s;
}

// logits from 6 partials; softmax over S; out = (1/6) sum_t x_t * w_t
__global__ void final_k(const float* __restrict__ x, const float* __restrict__ lp,
                        const float* __restrict__ fa_bl,
                        float* __restrict__ out, int b0, int Bc)
{
    const int lb = blockIdx.x, gb = b0 + lb, lane = threadIdx.x;
    float lg[SS];
    #pragma unroll
    for (int t = 0; t < SS; ++t) {
        const float* pp = lp + (size_t)(t * Bc + lb) * 6;
        lg[t] = pp[0] + pp[1] + pp[2] + pp[3] + pp[4] + pp[5] + fa_bl[0];
    }
    float m = lg[0];
    #pragma unroll
    for (int t = 1; t < SS; ++t) m = fmaxf(m, lg[t]);
    float e[SS], s = 0.f;
    #pragma unroll
    for (int t = 0; t < SS; ++t) { e[t] = expf(lg[t] - m); s += e[t]; }
    float inv = 1.0f / s;
    #pragma unroll
    for (int q = 0; q < 6; ++q) {
        int d = lane + 64 * q;
        float acc = 0.f;
        #pragma unroll
        for (int t = 0; t < SS; ++t)
            acc += x[(size_t)(t * Bc + lb) * DD + d] * (e[t] * inv);
        out[(size_t)gb * DD + d] = acc * (1.0f / 6.0f);
    }
}

// ---------------------------------------------------------------- launch
extern "C" void kernel_launch(void* const* d_in, const int* in_sizes, int n_in,
                              void* d_out, int out_size, void* d_ws, size_t ws_size,
                              hipStream_t stream)
{
    (void)in_sizes; (void)n_in; (void)out_size;
    const float* init_f  = (const float*)d_in[0];
    const float* head    = (const float*)d_in[1];
    const float* pred    = (const float*)d_in[2];
    const float* w_ap    = (const float*)d_in[3];
    const float* b_ap    = (const float*)d_in[4];
    const float* w_an    = (const float*)d_in[5];
    const float* b_an    = (const float*)d_in[6];
    const float* nt_w1   = (const float*)d_in[7];
    const float* nt_b1   = (const float*)d_in[8];
    const float* nt_w2   = (const float*)d_in[9];
    const float* nt_b2   = (const float*)d_in[10];
    const float* g1      = (const float*)d_in[11];
    const float* rg_wx   = (const float*)d_in[12];
    const float* rg_bx   = (const float*)d_in[13];
    const float* rg_wy   = (const float*)d_in[14];
    const float* rg_by   = (const float*)d_in[15];
    const float* rg_wr   = (const float*)d_in[16];
    const float* rg_br   = (const float*)d_in[17];
    const float* rg_wi   = (const float*)d_in[18];
    const float* rg_bi   = (const float*)d_in[19];
    const float* rg_lam  = (const float*)d_in[20];
    const float* rg_wo   = (const float*)d_in[21];
    const float* rg_bo   = (const float*)d_in[22];
    const float* g2      = (const float*)d_in[23];
    const float* mlp_wg  = (const float*)d_in[24];
    const float* mlp_wv  = (const float*)d_in[25];
    const float* mlp_wo  = (const float*)d_in[26];
    const float* fa_wg   = (const float*)d_in[27];
    const float* fa_wv   = (const float*)d_in[28];
    const float* fa_wo   = (const float*)d_in[29];
    const float* fa_wl   = (const float*)d_in[30];
    const float* fa_bl   = (const float*)d_in[31];
    float* out = (float*)d_out;

    float* ws_f    = (float*)d_ws;
    float* wproj   = ws_f;                 // 512 f32
    float* bias_xy = ws_f + 512;           // 1024
    float* a2      = ws_f + 1536;          // 512
    ushort_t* wt   = (ushort_t*)(ws_f + 2048);

    // bf16 transposed weights (bf16-elem offsets; matches tr_all_k EOFF)
    ushort_t* ntw1T = wt + 0;
    ushort_t* ntw2T = wt + 393216;
    ushort_t* wxyT  = wt + 786432;   // wx rows [0,512), wy rows [512,1024)
    ushort_t* wrT   = wt + 1179648;
    ushort_t* wiT   = wt + 1441792;
    ushort_t* woT   = wt + 1703936;
    ushort_t* mwgT  = wt + 1900544;
    ushort_t* mwvT  = wt + 2342912;
    ushort_t* mwoT  = wt + 2785280;
    ushort_t* fwgT  = wt + 3227648;
    ushort_t* fwvT  = wt + 3375104;  // end 3522560 bf16 = 1761280 f32

    TrArgs ta;
    ta.W[0]=nt_w1; ta.W[1]=nt_w2; ta.W[2]=rg_wx; ta.W[3]=rg_wy;
    ta.W[4]=rg_wr; ta.W[5]=rg_wi; ta.W[6]=rg_wo; ta.W[7]=mlp_wg;
    ta.W[8]=mlp_wv; ta.W[9]=mlp_wo; ta.W[10]=fa_wg; ta.W[11]=fa_wv;
    tr_all_k<<<3440, 256, 0, stream>>>(ta, wt);
    prep_k<<<4, 256, 0, stream>>>(rg_bx, rg_by, rg_lam, bias_xy, a2);
    wproj_k<<<1, DD, 0, stream>>>(fa_wo, fa_wl, wproj);

    // per-b arena 8064 f32 with lifetime-overlaid slots
    const size_t fixed_f32 = 2048 + 1761280;
    const size_t per_b_f32 = 8064;
    int Bc = B_TOT;
    while (Bc > 128 && (fixed_f32 + per_b_f32 * (size_t)Bc) * 4 > ws_size) Bc >>= 1;

    float* arena = ws_f + fixed_f32;

    for (int b0 = 0; b0 < B_TOT; b0 += Bc) {
        const int M  = Bc * SS;
        const int M2 = Bc * KNN;
        float*    xbuf = arena;                                    // [0,2304)
        ushort_t* negm = (ushort_t*)(arena + (size_t)2304 * Bc);   // [2304,2688) a-c
        ushort_t* hid  = (ushort_t*)(arena + (size_t)2688 * Bc);   // [2688,3712) b-c
        ushort_t* nf   = (ushort_t*)(arena + (size_t)3712 * Bc);   // [3712,4096) c-d
        ushort_t* hb   = (ushort_t*)(arena + (size_t)2304 * Bc);   // [2304,3456) d-e
        ushort_t* uh   = (ushort_t*)(arena + (size_t)3840 * Bc);   // [3840,5376) e-f
        ushort_t* gth  = (ushort_t*)(arena + (size_t)5376 * Bc);   // [5376,6912) e-f
        ushort_t* pr   = (ushort_t*)(arena + (size_t)2304 * Bc);   // [2304,3840) f-g
        ushort_t* h2   = (ushort_t*)(arena + (size_t)6912 * Bc);   // [6912,8064) g-h
        ushort_t* Th   = (ushort_t*)(arena + (size_t)2304 * Bc);   // [2304,5760) h-i
        ushort_t* xh   = (ushort_t*)(arena + (size_t)5760 * Bc);   // [5760,6912) i-j
        float*    lpb  = arena + (size_t)2304 * Bc;                // [2304,2340) j-k

        // stage 1: neg messages + MLP residual + attention assembly (+rms g1)
        negm_k<<<Bc * 3, 256, 0, stream>>>(head, pred, negm, b0, Bc);
        bgemm<1, false><<<dim3(HH/128, M2/128), 256, 0, stream>>>(
            negm, ntw1T, nt_b1, nullptr, nullptr, hid, nullptr, M2, HH, DD);
        bgemm<4, false><<<dim3(DD/128, M2/128), 256, 0, stream>>>(
            hid, ntw2T, nt_b2, negm, nullptr, nf, nullptr, M2, DD, HH);
        asmrms_k<<<Bc, 64, 0, stream>>>(init_f, head, pred, w_ap, b_ap, w_an, b_an,
                                        nf, g1, xbuf, hb, b0, Bc);

        // Griffin recurrent branch
        bgemm<7, false><<<dim3(1024/128, M/128), 256, 0, stream>>>(
            hb, wxyT, bias_xy, nullptr, nullptr, uh, gth, M, 1024, DD);
        rgri_rec_k<<<dim3(DRR/64, Bc/64), 256, 0, stream>>>(
            uh, gth, wrT, wiT, rg_br, rg_bi, a2, pr, Bc);
        bgemm<0, true><<<dim3(DD/128, M/128), 256, 0, stream>>>(
            pr, woT, rg_bo, nullptr, xbuf, nullptr, nullptr, M, DD, DRR);

        // gated-MLP residual branch
        rms_k<<<M / 4, 256, 0, stream>>>(xbuf, g2, h2);
        dual_k<false><<<dim3(DMM/64, M/128), 256, 0, stream>>>(
            h2, mwgT, mwvT, Th, nullptr, nullptr, M, DMM, DD);
        bgemm<0, true><<<dim3(DD/128, M/128), 256, 0, stream>>>(
            Th, mwoT, nullptr, nullptr, xbuf, xh, nullptr, M, DD, DMM);

        // final attention: fused dual-GEMM -> per-row logit partials
        dual_k<true><<<dim3(DD/64, M/128), 256, 0, stream>>>(
            xh, fwgT, fwvT, nullptr, lpb, wproj, M, DD, DD);
        final_k<<<Bc, 64, 0, stream>>>(xbuf, lpb, fa_bl, out, b0, Bc);
    }
}

// Round 6
// 1822.381 us; speedup vs baseline: 2.4064x; 1.0239x over previous
//
#include <hip/hip_runtime.h>
#include <hip/hip_bf16.h>

// Problem constants (from reference)
#define B_TOT 16384
#define DD    384
#define HH    1024
#define DRR   512
#define DMM   1152
#define SS    6     // 1 + KP + KN
#define KPP   3
#define KNN   2

typedef unsigned short ushort_t;
typedef __bf16 bf16x8 __attribute__((ext_vector_type(8)));
typedef float  f32x4  __attribute__((ext_vector_type(4)));

#define CST 136   // bgemm epilogue LDS stride (bf16)
#define EPW 72    // dual epilogue LDS stride

// ---------------------------------------------------------------- helpers
__device__ __forceinline__ float gelu_f(float x) {
    float x3 = x * x * x;
    return 0.5f * x * (1.0f + tanhf(0.7978845608028654f * (x + 0.044715f * x3)));
}
__device__ __forceinline__ float sigmoid_f(float x) {
    return 1.0f / (1.0f + expf(-x));
}
__device__ __forceinline__ float wave_red_sum(float v) {
    #pragma unroll
    for (int off = 32; off; off >>= 1) v += __shfl_xor(v, off);
    return v;
}
__device__ __forceinline__ ushort_t f2bf(float v) {
    __hip_bfloat16 h = __float2bfloat16(v);
    return *reinterpret_cast<ushort_t*>(&h);
}
__device__ __forceinline__ float bf2f(ushort_t u) {
    unsigned int x = ((unsigned int)u) << 16;
    return __uint_as_float(x);
}
// async global->LDS, 16B per lane; LDS dest = wave-uniform base + lane*16
__device__ __forceinline__ void g2l16(const ushort_t* g, ushort_t* l) {
    __builtin_amdgcn_global_load_lds(
        (const __attribute__((address_space(1))) void*)g,
        (__attribute__((address_space(3))) void*)l, 16, 0, 0);
}
// XCD-aware bijective block swizzle
__device__ __forceinline__ void swz_xy(int& bx, int& by) {
    const int nx = gridDim.x;
    const int nwg = nx * gridDim.y;
    const int h = by * nx + bx;
    const int q = nwg >> 3, r = nwg & 7;
    const int xcd = h & 7, lo = h >> 3;
    const int lin = (xcd < r) ? (xcd * (q + 1) + lo)
                              : (r * (q + 1) + (xcd - r) * q + lo);
    bx = lin % nx;
    by = lin / nx;
}

// ---------------------------------------------------------------- MFMA GEMM
// C[M,N] = epi( A[M,K](bf16) @ WT[N,K](bf16)^T + bias )
// EPI: 0 none, 1 relu, 4 v - X2(bf16), 7 split-xy (c<512 -> Ch, else gelu -> Ch2)
// global_load_lds dbuf: A0@0 A1@8192 B0@16384 B1@24576 (ushort units; 64 KiB)
// LDS linear rows of 64 elems, XOR-swizzled chunks: phys_chunk = chunk ^ (row&7)
template<int EPI, bool ACCUM>
__global__ __launch_bounds__(256, 2)
void bgemm(const ushort_t* __restrict__ A, const ushort_t* __restrict__ WT,
           const float* __restrict__ bias, const ushort_t* __restrict__ X2,
           float* __restrict__ C, ushort_t* __restrict__ Ch, ushort_t* __restrict__ Ch2,
           int M, int N, int K)
{
    __shared__ ushort_t sm[32768];

    int bx = blockIdx.x, by = blockIdx.y;
    swz_xy(bx, by);
    const int tid = threadIdx.x;
    const int l = tid & 63, w = tid >> 6;
    const int wr = w >> 1, wc = w & 1;
    const int lr = l & 15, hi = l >> 4;
    const int row0 = by * 128, col0 = bx * 128;

    // staging: wave w, instr i -> rows (w*4+i)*8 + l/8, swizzled source chunk
    const int lrw = l >> 3;
    const int lch = (l & 7) ^ (lrw & 7);
    const ushort_t* As[4]; const ushort_t* Bs[4]; int lo_[4];
    #pragma unroll
    for (int i = 0; i < 4; ++i) {
        const int g = w * 4 + i;
        As[i] = A  + (size_t)(row0 + g*8 + lrw) * K + lch * 8;
        Bs[i] = WT + (size_t)(col0 + g*8 + lrw) * K + lch * 8;
        lo_[i] = g * 512;
    }
    const int ko[2] = {(hi*8) ^ ((lr&7)*8), (32 + hi*8) ^ ((lr&7)*8)};

    f32x4 acc[4][4] = {};
    const int NT = K >> 6;

    #pragma unroll
    for (int i = 0; i < 4; ++i) {
        g2l16(As[i], &sm[lo_[i]]);
        g2l16(Bs[i], &sm[16384 + lo_[i]]);
    }
    __syncthreads();

    int db = 0;
    for (int t = 0; t < NT; ++t) {
        if (t + 1 < NT) {
            const int nb = db ^ 1;
            #pragma unroll
            for (int i = 0; i < 4; ++i) {
                g2l16(As[i] + (size_t)(t+1)*64, &sm[nb*8192 + lo_[i]]);
                g2l16(Bs[i] + (size_t)(t+1)*64, &sm[16384 + nb*8192 + lo_[i]]);
            }
        }
        #pragma unroll
        for (int ks = 0; ks < 2; ++ks) {
            bf16x8 af[4], bfr[4];
            #pragma unroll
            for (int m = 0; m < 4; ++m)
                af[m] = *(const bf16x8*)&sm[db*8192 + (wr*64 + m*16 + lr)*64 + ko[ks]];
            #pragma unroll
            for (int n = 0; n < 4; ++n)
                bfr[n] = *(const bf16x8*)&sm[16384 + db*8192 + (wc*64 + n*16 + lr)*64 + ko[ks]];
            #pragma unroll
            for (int m = 0; m < 4; ++m)
                #pragma unroll
                for (int n = 0; n < 4; ++n)
                    acc[m][n] = __builtin_amdgcn_mfma_f32_16x16x32_bf16(
                        af[m], bfr[n], acc[m][n], 0, 0, 0);
        }
        __syncthreads();
        db ^= 1;
    }

    // epilogue: C/D frag mapping col = l&15, row = (l>>4)*4 + j
    const bool BF = (EPI == 7) || (Ch != nullptr);
    #pragma unroll
    for (int m = 0; m < 4; ++m) {
        #pragma unroll
        for (int n = 0; n < 4; ++n) {
            const int r0 = row0 + wr*64 + m*16 + hi*4;
            const int c  = col0 + wc*64 + n*16 + lr;
            const float bv = bias ? bias[c] : 0.f;
            #pragma unroll
            for (int j = 0; j < 4; ++j) {
                const int r = r0 + j;
                float v = acc[m][n][j] + bv;
                if (EPI == 1) v = fmaxf(v, 0.f);
                if (EPI == 4) v = v - bf2f(X2[(size_t)r * N + c]);
                if (ACCUM)    v += C[(size_t)r * N + c];
                if (C) C[(size_t)r * N + c] = v;
                if (BF) {
                    float ov = (EPI == 7 && c >= 512) ? gelu_f(v) : v;
                    sm[(wr*64 + m*16 + hi*4 + j) * CST + wc*64 + n*16 + lr] = f2bf(ov);
                }
            }
        }
    }
    if (BF) {
        __syncthreads();
        const int er = tid >> 1, ec = (tid & 1) * 64;
        ushort_t* dst; int nn, dc0;
        if (EPI == 7) {
            nn = 512;
            if (col0 < 512) { dst = Ch;  dc0 = col0; }
            else            { dst = Ch2; dc0 = col0 - 512; }
        } else { dst = Ch; nn = N; dc0 = col0; }
        const uint4* sp = (const uint4*)&sm[er * CST + ec];
        uint4* gp = (uint4*)(dst + (size_t)(row0 + er) * nn + dc0 + ec);
        #pragma unroll
        for (int q = 0; q < 8; ++q) gp[q] = sp[q];
    }
}

// ---------------------------------------------------------------- dual-B GEMM
// LOGITS=false: Ch[M,N] = gelu(A@W1T^T) * (A@W2T^T)
// LOGITS=true : LP[r*6+bx] = sum over this block's 64 cols of gelu(G)*V*wproj[c]
// LDS: A0@0 A1@8192 G0@16384 G1@20480 V0@24576 V1@28672 (64 KiB)
template<bool LOGITS>
__global__ __launch_bounds__(256, 2)
void dual_k(const ushort_t* __restrict__ A, const ushort_t* __restrict__ W1T,
            const ushort_t* __restrict__ W2T, ushort_t* __restrict__ Ch,
            float* __restrict__ LP, const float* __restrict__ wproj,
            int M, int N, int K)
{
    __shared__ ushort_t sm[32768];

    int bx = blockIdx.x, by = blockIdx.y;
    swz_xy(bx, by);
    const int tid = threadIdx.x;
    const int l = tid & 63, w = tid >> 6;
    const int wr = w >> 1, wc = w & 1;
    const int lr = l & 15, hi = l >> 4;
    const int row0 = by * 128, col0 = bx * 64;

    const int lrw = l >> 3;
    const int lch = (l & 7) ^ (lrw & 7);
    const ushort_t* As[4]; int loA[4];
    #pragma unroll
    for (int i = 0; i < 4; ++i) {
        const int g = w * 4 + i;
        As[i] = A + (size_t)(row0 + g*8 + lrw) * K + lch * 8;
        loA[i] = g * 512;
    }
    const ushort_t* Gs[2]; const ushort_t* Vs[2]; int loB[2];
    #pragma unroll
    for (int i = 0; i < 2; ++i) {
        const int g = w * 2 + i;
        Gs[i] = W1T + (size_t)(col0 + g*8 + lrw) * K + lch * 8;
        Vs[i] = W2T + (size_t)(col0 + g*8 + lrw) * K + lch * 8;
        loB[i] = g * 512;
    }
    const int ko[2] = {(hi*8) ^ ((lr&7)*8), (32 + hi*8) ^ ((lr&7)*8)};

    f32x4 ag[4][2] = {}, av[4][2] = {};
    const int NT = K >> 6;

    #pragma unroll
    for (int i = 0; i < 4; ++i) g2l16(As[i], &sm[loA[i]]);
    #pragma unroll
    for (int i = 0; i < 2; ++i) {
        g2l16(Gs[i], &sm[16384 + loB[i]]);
        g2l16(Vs[i], &sm[24576 + loB[i]]);
    }
    __syncthreads();

    int db = 0;
    for (int t = 0; t < NT; ++t) {
        if (t + 1 < NT) {
            const int nb = db ^ 1;
            #pragma unroll
            for (int i = 0; i < 4; ++i)
                g2l16(As[i] + (size_t)(t+1)*64, &sm[nb*8192 + loA[i]]);
            #pragma unroll
            for (int i = 0; i < 2; ++i) {
                g2l16(Gs[i] + (size_t)(t+1)*64, &sm[16384 + nb*4096 + loB[i]]);
                g2l16(Vs[i] + (size_t)(t+1)*64, &sm[24576 + nb*4096 + loB[i]]);
            }
        }
        #pragma unroll
        for (int ks = 0; ks < 2; ++ks) {
            bf16x8 af[4], bg[2], bv[2];
            #pragma unroll
            for (int m = 0; m < 4; ++m)
                af[m] = *(const bf16x8*)&sm[db*8192 + (wr*64 + m*16 + lr)*64 + ko[ks]];
            #pragma unroll
            for (int n = 0; n < 2; ++n) {
                bg[n] = *(const bf16x8*)&sm[16384 + db*4096 + (wc*32 + n*16 + lr)*64 + ko[ks]];
                bv[n] = *(const bf16x8*)&sm[24576 + db*4096 + (wc*32 + n*16 + lr)*64 + ko[ks]];
            }
            #pragma unroll
            for (int m = 0; m < 4; ++m)
                #pragma unroll
                for (int n = 0; n < 2; ++n) {
                    ag[m][n] = __builtin_amdgcn_mfma_f32_16x16x32_bf16(af[m], bg[n], ag[m][n], 0, 0, 0);
                    av[m][n] = __builtin_amdgcn_mfma_f32_16x16x32_bf16(af[m], bv[n], av[m][n], 0, 0, 0);
                }
        }
        __syncthreads();
        db ^= 1;
    }

    if (!LOGITS) {
        #pragma unroll
        for (int m = 0; m < 4; ++m)
            #pragma unroll
            for (int n = 0; n < 2; ++n)
                #pragma unroll
                for (int j = 0; j < 4; ++j)
                    sm[(wr*64 + m*16 + hi*4 + j) * EPW + wc*32 + n*16 + lr] =
                        f2bf(gelu_f(ag[m][n][j]) * av[m][n][j]);
        __syncthreads();
        const int er = tid >> 1, ec = (tid & 1) * 32;
        const uint4* sp = (const uint4*)&sm[er * EPW + ec];
        uint4* gp = (uint4*)(Ch + (size_t)(row0 + er) * N + col0 + ec);
        #pragma unroll
        for (int q = 0; q < 4; ++q) gp[q] = sp[q];
    } else {
        float wp[2];
        #pragma unroll
        for (int n = 0; n < 2; ++n) wp[n] = wproj[col0 + wc*32 + n*16 + lr];
        float* red = (float*)sm;   // [128][2]
        #pragma unroll
        for (int m = 0; m < 4; ++m) {
            #pragma unroll
            for (int j = 0; j < 4; ++j) {
                float s = 0.f;
                #pragma unroll
                for (int n = 0; n < 2; ++n)
                    s += gelu_f(ag[m][n][j]) * av[m][n][j] * wp[n];
                s += __shfl_xor(s, 1);
                s += __shfl_xor(s, 2);
                s += __shfl_xor(s, 4);
                s += __shfl_xor(s, 8);
                if (lr == 0) red[(wr*64 + m*16 + hi*4 + j) * 2 + wc] = s;
            }
        }
        __syncthreads();
        if (tid < 128)
            LP[(size_t)(row0 + tid) * 6 + bx] = red[tid*2] + red[tid*2 + 1];
    }
}

// ---------------------------------------------------------------- RG-LRU recurrence
// ri[M][1024] holds r logits (cols 0..511) and i logits (cols 512..1023),
// biases already folded. Thread owns 8 contiguous d's of one b; loops t.
// Writes prod = h*gate IN-PLACE over u (same element, read-before-write).
__global__ __launch_bounds__(256, 8)
void rec_k(ushort_t* __restrict__ u, const ushort_t* __restrict__ gate,
           const ushort_t* __restrict__ ri, const float* __restrict__ a2,
           int Bc)
{
    const int g = blockIdx.x * 256 + threadIdx.x;   // < Bc*64
    const int b = g >> 6, c8 = (g & 63) << 3;
    float a2v[8];
    *(float4*)&a2v[0] = *(const float4*)&a2[c8];
    *(float4*)&a2v[4] = *(const float4*)&a2[c8 + 4];
    float h[8] = {};
    for (int t = 0; t < SS; ++t) {
        const size_t row = (size_t)t * Bc + b;
        uint4 uw = *(const uint4*)&u[row * DRR + c8];
        uint4 rw = *(const uint4*)&ri[row * 1024 + c8];
        uint4 iw = *(const uint4*)&ri[row * 1024 + 512 + c8];
        uint4 gw = *(const uint4*)&gate[row * DRR + c8];
        const ushort_t* up = (const ushort_t*)&uw;
        const ushort_t* rp = (const ushort_t*)&rw;
        const ushort_t* ip = (const ushort_t*)&iw;
        const ushort_t* gp = (const ushort_t*)&gw;
        ushort_t o[8];
        #pragma unroll
        for (int q = 0; q < 8; ++q) {
            const float rv = sigmoid_f(bf2f(rp[q]));
            const float iv = sigmoid_f(bf2f(ip[q]));
            const float e  = exp2f(a2v[q] * rv);
            const float hv = e * h[q]
                           + sqrtf(fmaxf(0.f, 1.f - e * e)) * (iv * bf2f(up[q]));
            h[q] = hv;
            o[q] = f2bf(hv * bf2f(gp[q]));
        }
        *(uint4*)&u[row * DRR + c8] = *(const uint4*)o;
    }
}

// ---------------------------------------------------------------- small kernels

// one-shot tiled transpose+convert of all 12 weights: WT[n*K+k] = bf16(W[k*N+n])
struct TrArgs { const float* W[12]; };
__global__ void tr_all_k(TrArgs a, ushort_t* __restrict__ wt)
{
    constexpr int KT[12]  = {384,1024,384,384,512,512,512,384,384,1152,384,384};
    constexpr int NTb[12] = {1024,384,512,512,512,512,384,1152,1152,384,384,384};
    constexpr int EOFF[12]= {0,393216,786432,983040,1179648,1441792,1703936,
                             1900544,2342912,2785280,3227648,3375104};
    constexpr int TPRE[13]= {0,384,768,960,1152,1408,1664,1856,2288,2720,3152,3296,3440};
    const int tb = blockIdx.x;
    int s = 0;
    #pragma unroll
    for (int i = 0; i < 12; ++i) if (tb >= TPRE[i+1]) s = i + 1;
    const int rel = tb - TPRE[s];
    const int K = KT[s], N = NTb[s];
    const int ntn = N >> 5;
    const int k0 = (rel / ntn) * 32, n0 = (rel % ntn) * 32;

    __shared__ float ts[32][33];
    const int r = threadIdx.x >> 3, c4 = (threadIdx.x & 7) * 4;
    const float4 v = *(const float4*)&a.W[s][(size_t)(k0 + r) * N + n0 + c4];
    ts[r][c4+0] = v.x; ts[r][c4+1] = v.y; ts[r][c4+2] = v.z; ts[r][c4+3] = v.w;
    __syncthreads();
    ushort_t o4[4];
    #pragma unroll
    for (int q = 0; q < 4; ++q) o4[q] = f2bf(ts[c4 + q][r]);
    *(uint2*)&wt[EOFF[s] + (size_t)(n0 + r) * K + k0 + c4] = *(const uint2*)o4;
}

__global__ void prep_k(const float* __restrict__ rg_bx, const float* __restrict__ rg_by,
                       const float* __restrict__ rg_lam,
                       const float* __restrict__ rg_br, const float* __restrict__ rg_bi,
                       float* __restrict__ bias_xy, float* __restrict__ a2,
                       float* __restrict__ bias_ri)
{
    int i = blockIdx.x * 256 + threadIdx.x;
    if (i < 512) {
        bias_xy[i] = rg_bx[i];
        bias_ri[i] = rg_br[i];
        float lam = rg_lam[i];
        float sp = (lam > 20.f) ? lam : log1pf(expf(lam));
        a2[i] = -8.0f * sp * 1.4426950408889634f;
    } else if (i < 1024) {
        bias_xy[i] = rg_by[i - 512];
        bias_ri[i] = rg_bi[i - 512];
    }
}

__global__ void negm_k(const float* __restrict__ head, const float* __restrict__ pred,
                       ushort_t* __restrict__ negm_h, int b0, int Bc)
{
    int idx = blockIdx.x * 256 + threadIdx.x;        // < Bc*2*384
    int d = idx % DD, rr = idx / DD;
    int j = (rr >= Bc) ? 1 : 0;
    int b = rr - j * Bc;
    size_t off = ((size_t)(KPP + j) * B_TOT + (b0 + b)) * DD + d;
    negm_h[idx] = f2bf(head[off] + pred[off]);
}

// grouped softmax attn + assemble x rows (t-major) + rmsnorm(g1) -> hb bf16
__global__ void asmrms_k(const float* __restrict__ init_f,
                         const float* __restrict__ head, const float* __restrict__ pred,
                         const float* __restrict__ w_ap, const float* __restrict__ b_ap,
                         const float* __restrict__ w_an, const float* __restrict__ b_an,
                         const ushort_t* __restrict__ nf, const float* __restrict__ g1,
                         float* __restrict__ x, ushort_t* __restrict__ hb,
                         int b0, int Bc)
{
    const int lb = blockIdx.x, gb = b0 + lb, lane = threadIdx.x;
    float hp[3][6], nv[2][6], iv[6], wap[6], wan[6];
    #pragma unroll
    for (int q = 0; q < 6; ++q) {
        int d = lane + 64 * q;
        wap[q] = w_ap[d]; wan[q] = w_an[d];
        iv[q] = init_f[(size_t)gb * DD + d];
    }
    float lp[3], ln2[2];
    #pragma unroll
    for (int j = 0; j < 3; ++j) {
        float p = 0.f;
        #pragma unroll
        for (int q = 0; q < 6; ++q) {
            int d = lane + 64 * q;
            size_t off = ((size_t)j * B_TOT + gb) * DD + d;
            float v = head[off] + pred[off];
            hp[j][q] = v;
            p += v * wap[q];
        }
        lp[j] = wave_red_sum(p) + b_ap[0];
    }
    #pragma unroll
    for (int j = 0; j < 2; ++j) {
        float p = 0.f;
        #pragma unroll
        for (int q = 0; q < 6; ++q) {
            int d = lane + 64 * q;
            float v = bf2f(nf[((size_t)j * Bc + lb) * DD + d]);
            nv[j][q] = v;
            p += v * wan[q];
        }
        ln2[j] = wave_red_sum(p) + b_an[0];
    }
    float mp = fmaxf(lp[0], fmaxf(lp[1], lp[2]));
    float e0 = expf(lp[0]-mp), e1 = expf(lp[1]-mp), e2 = expf(lp[2]-mp);
    float sp = e0 + e1 + e2;
    float awp[3] = {e0/sp, e1/sp, e2/sp};
    float mn = fmaxf(ln2[0], ln2[1]);
    float f0 = expf(ln2[0]-mn), f1 = expf(ln2[1]-mn);
    float sn = f0 + f1;
    float awn[2] = {f0/sn, f1/sn};

    #pragma unroll
    for (int t = 0; t < SS; ++t) {
        float rowv[6], ss = 0.f;
        #pragma unroll
        for (int q = 0; q < 6; ++q) {
            float v;
            if (t == 0)      v = iv[q];
            else if (t <= 3) v = hp[t-1][q] * awp[t-1];
            else             v = nv[t-4][q] * awn[t-4];
            rowv[q] = v;
            ss += v * v;
        }
        ss = wave_red_sum(ss);
        float sc = rsqrtf(ss / (float)DD + 1e-6f);
        float* xr = x + (size_t)(t * Bc + lb) * DD;
        ushort_t* hr = hb + (size_t)(t * Bc + lb) * DD;
        #pragma unroll
        for (int q = 0; q < 6; ++q) {
            int d = lane + 64 * q;
            xr[d] = rowv[q];
            hr[d] = f2bf(rowv[q] * g1[d] * sc);
        }
    }
}

__global__ void rms_k(const float* __restrict__ x, const float* __restrict__ g,
                      ushort_t* __restrict__ h)
{
    int row  = blockIdx.x * 4 + (threadIdx.x >> 6);
    int lane = threadIdx.x & 63;
    const float* xr = x + (size_t)row * DD;
    float ss = 0.f;
    for (int d = lane; d < DD; d += 64) { float v = xr[d]; ss += v * v; }
    ss = wave_red_sum(ss);
    float sc = rsqrtf(ss / (float)DD + 1e-6f);
    ushort_t* hr = h + (size_t)row * DD;
    for (int d = lane; d < DD; d += 64) hr[d] = f2bf(xr[d] * g[d] * sc);
}

__global__ void wproj_k(const float* __restrict__ fa_wo, const float* __restrict__ fa_wl,
                        float* __restrict__ wproj)
{
    int d = threadIdx.x;  // 384 threads
    float s = 0.f;
    for (int k = 0; k < DD; ++k) s += fa_wo[(size_t)d * DD + k] * fa_wl[k];
    wproj[d] = s;
}

// logits from 6 partials; softmax over S; out = (1/6) sum_t x_t * w_t
__global__ void final_k(const float* __restrict__ x, const float* __restrict__ lp,
                        const float* __restrict__ fa_bl,
                        float* __restrict__ out, int b0, int Bc)
{
    const int lb = blockIdx.x, gb = b0 + lb, lane = threadIdx.x;
    float lg[SS];
    #pragma unroll
    for (int t = 0; t < SS; ++t) {
        const float* pp = lp + (size_t)(t * Bc + lb) * 6;
        lg[t] = pp[0] + pp[1] + pp[2] + pp[3] + pp[4] + pp[5] + fa_bl[0];
    }
    float m = lg[0];
    #pragma unroll
    for (int t = 1; t < SS; ++t) m = fmaxf(m, lg[t]);
    float e[SS], s = 0.f;
    #pragma unroll
    for (int t = 0; t < SS; ++t) { e[t] = expf(lg[t] - m); s += e[t]; }
    float inv = 1.0f / s;
    #pragma unroll
    for (int q = 0; q < 6; ++q) {
        int d = lane + 64 * q;
        float acc = 0.f;
        #pragma unroll
        for (int t = 0; t < SS; ++t)
            acc += x[(size_t)(t * Bc + lb) * DD + d] * (e[t] * inv);
        out[(size_t)gb * DD + d] = acc * (1.0f / 6.0f);
    }
}

// ---------------------------------------------------------------- launch
extern "C" void kernel_launch(void* const* d_in, const int* in_sizes, int n_in,
                              void* d_out, int out_size, void* d_ws, size_t ws_size,
                              hipStream_t stream)
{
    (void)in_sizes; (void)n_in; (void)out_size;
    const float* init_f  = (const float*)d_in[0];
    const float* head    = (const float*)d_in[1];
    const float* pred    = (const float*)d_in[2];
    const float* w_ap    = (const float*)d_in[3];
    const float* b_ap    = (const float*)d_in[4];
    const float* w_an    = (const float*)d_in[5];
    const float* b_an    = (const float*)d_in[6];
    const float* nt_w1   = (const float*)d_in[7];
    const float* nt_b1   = (const float*)d_in[8];
    const float* nt_w2   = (const float*)d_in[9];
    const float* nt_b2   = (const float*)d_in[10];
    const float* g1      = (const float*)d_in[11];
    const float* rg_wx   = (const float*)d_in[12];
    const float* rg_bx   = (const float*)d_in[13];
    const float* rg_wy   = (const float*)d_in[14];
    const float* rg_by   = (const float*)d_in[15];
    const float* rg_wr   = (const float*)d_in[16];
    const float* rg_br   = (const float*)d_in[17];
    const float* rg_wi   = (const float*)d_in[18];
    const float* rg_bi   = (const float*)d_in[19];
    const float* rg_lam  = (const float*)d_in[20];
    const float* rg_wo   = (const float*)d_in[21];
    const float* rg_bo   = (const float*)d_in[22];
    const float* g2      = (const float*)d_in[23];
    const float* mlp_wg  = (const float*)d_in[24];
    const float* mlp_wv  = (const float*)d_in[25];
    const float* mlp_wo  = (const float*)d_in[26];
    const float* fa_wg   = (const float*)d_in[27];
    const float* fa_wv   = (const float*)d_in[28];
    const float* fa_wo   = (const float*)d_in[29];
    const float* fa_wl   = (const float*)d_in[30];
    const float* fa_bl   = (const float*)d_in[31];
    float* out = (float*)d_out;

    float* ws_f    = (float*)d_ws;
    float* wproj   = ws_f;                 // 512 f32
    float* bias_xy = ws_f + 512;           // 1024
    float* a2      = ws_f + 1536;          // 512
    float* bias_ri = ws_f + 2048;          // 1024
    ushort_t* wt   = (ushort_t*)(ws_f + 3072);

    // bf16 transposed weights (bf16-elem offsets; matches tr_all_k EOFF)
    ushort_t* ntw1T = wt + 0;
    ushort_t* ntw2T = wt + 393216;
    ushort_t* wxyT  = wt + 786432;   // wx rows [0,512), wy rows [512,1024)
    ushort_t* wriT  = wt + 1179648;  // wr rows [0,512), wi rows [512,1024) (adjacent)
    ushort_t* woT   = wt + 1703936;
    ushort_t* mwgT  = wt + 1900544;
    ushort_t* mwvT  = wt + 2342912;
    ushort_t* mwoT  = wt + 2785280;
    ushort_t* fwgT  = wt + 3227648;
    ushort_t* fwvT  = wt + 3375104;  // end 3522560 bf16 = 1761280 f32

    TrArgs ta;
    ta.W[0]=nt_w1; ta.W[1]=nt_w2; ta.W[2]=rg_wx; ta.W[3]=rg_wy;
    ta.W[4]=rg_wr; ta.W[5]=rg_wi; ta.W[6]=rg_wo; ta.W[7]=mlp_wg;
    ta.W[8]=mlp_wv; ta.W[9]=mlp_wo; ta.W[10]=fa_wg; ta.W[11]=fa_wv;
    tr_all_k<<<3440, 256, 0, stream>>>(ta, wt);
    prep_k<<<4, 256, 0, stream>>>(rg_bx, rg_by, rg_lam, rg_br, rg_bi,
                                  bias_xy, a2, bias_ri);
    wproj_k<<<1, DD, 0, stream>>>(fa_wo, fa_wl, wproj);

    // per-b arena 8448 f32 with lifetime-overlaid slots
    const size_t fixed_f32 = 3072 + 1761280;
    const size_t per_b_f32 = 8448;
    int Bc = B_TOT;
    while (Bc > 128 && (fixed_f32 + per_b_f32 * (size_t)Bc) * 4 > ws_size) Bc >>= 1;

    float* arena = ws_f + fixed_f32;

    for (int b0 = 0; b0 < B_TOT; b0 += Bc) {
        const int M  = Bc * SS;
        const int M2 = Bc * KNN;
        float*    xbuf = arena;                                    // [0,2304) live always
        ushort_t* negm = (ushort_t*)(arena + (size_t)2304 * Bc);   // [2304,2688)
        ushort_t* hid  = (ushort_t*)(arena + (size_t)2688 * Bc);   // [2688,3712)
        ushort_t* nf   = (ushort_t*)(arena + (size_t)3712 * Bc);   // [3712,4096)
        ushort_t* hb   = (ushort_t*)(arena + (size_t)4096 * Bc);   // [4096,5248)
        ushort_t* uh   = (ushort_t*)(arena + (size_t)5376 * Bc);   // [5376,6912) (u, then prod in-place)
        ushort_t* gth  = (ushort_t*)(arena + (size_t)6912 * Bc);   // [6912,8448)
        ushort_t* ri   = (ushort_t*)(arena + (size_t)2304 * Bc);   // [2304,5376) (after hb dead)
        ushort_t* h2   = (ushort_t*)(arena + (size_t)2304 * Bc);   // [2304,3456)
        ushort_t* Th   = (ushort_t*)(arena + (size_t)3456 * Bc);   // [3456,6912)
        ushort_t* xh   = (ushort_t*)(arena + (size_t)6912 * Bc);   // [6912,8064)
        float*    lpb  = arena + (size_t)2304 * Bc;                // [2304,2340)

        // stage 1: neg messages + MLP residual + attention assembly (+rms g1)
        negm_k<<<Bc * 3, 256, 0, stream>>>(head, pred, negm, b0, Bc);
        bgemm<1, false><<<dim3(HH/128, M2/128), 256, 0, stream>>>(
            negm, ntw1T, nt_b1, nullptr, nullptr, hid, nullptr, M2, HH, DD);
        bgemm<4, false><<<dim3(DD/128, M2/128), 256, 0, stream>>>(
            hid, ntw2T, nt_b2, negm, nullptr, nf, nullptr, M2, DD, HH);
        asmrms_k<<<Bc, 64, 0, stream>>>(init_f, head, pred, w_ap, b_ap, w_an, b_an,
                                        nf, g1, xbuf, hb, b0, Bc);

        // Griffin recurrent branch: u|gate GEMM, r|i logits GEMM, recurrence, wo
        bgemm<7, false><<<dim3(1024/128, M/128), 256, 0, stream>>>(
            hb, wxyT, bias_xy, nullptr, nullptr, uh, gth, M, 1024, DD);
        bgemm<0, false><<<dim3(1024/128, M/128), 256, 0, stream>>>(
            uh, wriT, bias_ri, nullptr, nullptr, ri, nullptr, M, 1024, DRR);
        rec_k<<<Bc / 4, 256, 0, stream>>>(uh, gth, ri, a2, Bc);
        bgemm<0, true><<<dim3(DD/128, M/128), 256, 0, stream>>>(
            uh, woT, rg_bo, nullptr, xbuf, nullptr, nullptr, M, DD, DRR);

        // gated-MLP residual branch
        rms_k<<<M / 4, 256, 0, stream>>>(xbuf, g2, h2);
        dual_k<false><<<dim3(DMM/64, M/128), 256, 0, stream>>>(
            h2, mwgT, mwvT, Th, nullptr, nullptr, M, DMM, DD);
        bgemm<0, true><<<dim3(DD/128, M/128), 256, 0, stream>>>(
            Th, mwoT, nullptr, nullptr, xbuf, xh, nullptr, M, DD, DMM);

        // final attention: fused dual-GEMM -> per-row logit partials
        dual_k<true><<<dim3(DD/64, M/128), 256, 0, stream>>>(
            xh, fwgT, fwvT, nullptr, lpb, wproj, M, DD, DD);
        final_k<<<Bc, 64, 0, stream>>>(xbuf, lpb, fa_bl, out, b0, Bc);
    }
}

// Round 7
// 1659.100 us; speedup vs baseline: 2.6432x; 1.0984x over previous
//
#include <hip/hip_runtime.h>
#include <hip/hip_bf16.h>

// Problem constants (from reference)
#define B_TOT 16384
#define DD    384
#define HH    1024
#define DRR   512
#define DMM   1152
#define SS    6     // 1 + KP + KN
#define KPP   3
#define KNN   2

typedef unsigned short ushort_t;
typedef __bf16 bf16x8 __attribute__((ext_vector_type(8)));
typedef float  f32x4  __attribute__((ext_vector_type(4)));

#define CST 136   // bgemm epilogue LDS stride (bf16)
#define EPW 72    // dual epilogue LDS stride

// ---------------------------------------------------------------- helpers
// hardware transcendentals: v_exp_f32 + v_rcp_f32 (≤2 ULP; ~8 ops per gelu
// vs ~25+ for libm tanhf — at K=384 the gelu epilogue was ~half the kernel)
__device__ __forceinline__ float fexp2(float x) { return __builtin_amdgcn_exp2f(x); }
__device__ __forceinline__ float frcp(float x)  { return __builtin_amdgcn_rcpf(x); }
__device__ __forceinline__ float sigmoid_f(float x) {
    return frcp(1.f + fexp2(-1.4426950408889634f * x));
}
__device__ __forceinline__ float gelu_f(float x) {
    // x * sigmoid(2 * 0.79788456*(x + 0.044715 x^3))  ==  tanh-form gelu
    float z = 0.7978845608028654f * x * (1.f + 0.044715f * x * x);
    return x * frcp(1.f + fexp2(-2.885390081777927f * z));
}
__device__ __forceinline__ float wave_red_sum(float v) {
    #pragma unroll
    for (int off = 32; off; off >>= 1) v += __shfl_xor(v, off);
    return v;
}
__device__ __forceinline__ ushort_t f2bf(float v) {
    __hip_bfloat16 h = __float2bfloat16(v);
    return *reinterpret_cast<ushort_t*>(&h);
}
__device__ __forceinline__ float bf2f(ushort_t u) {
    unsigned int x = ((unsigned int)u) << 16;
    return __uint_as_float(x);
}
// async global->LDS, 16B per lane; LDS dest = wave-uniform base + lane*16
__device__ __forceinline__ void g2l16(const ushort_t* g, ushort_t* l) {
    __builtin_amdgcn_global_load_lds(
        (const __attribute__((address_space(1))) void*)g,
        (__attribute__((address_space(3))) void*)l, 16, 0, 0);
}
// XCD-aware bijective block swizzle
__device__ __forceinline__ void swz_xy(int& bx, int& by) {
    const int nx = gridDim.x;
    const int nwg = nx * gridDim.y;
    const int h = by * nx + bx;
    const int q = nwg >> 3, r = nwg & 7;
    const int xcd = h & 7, lo = h >> 3;
    const int lin = (xcd < r) ? (xcd * (q + 1) + lo)
                              : (r * (q + 1) + (xcd - r) * q + lo);
    bx = lin % nx;
    by = lin / nx;
}

// ---------------------------------------------------------------- MFMA GEMM
// C[M,N] = epi( A[M,K](bf16) @ WT[N,K](bf16)^T + bias )
// EPI: 0 none, 1 relu, 4 v - X2(bf16), 7 split-xy (c<512 -> Ch, else gelu -> Ch2)
// global_load_lds dbuf: A0@0 A1@8192 B0@16384 B1@24576 (ushort units; 64 KiB)
// LDS linear rows of 64 elems, XOR-swizzled chunks: phys_chunk = chunk ^ (row&7)
template<int EPI, bool ACCUM>
__global__ __launch_bounds__(256, 2)
void bgemm(const ushort_t* __restrict__ A, const ushort_t* __restrict__ WT,
           const float* __restrict__ bias, const ushort_t* __restrict__ X2,
           float* __restrict__ C, ushort_t* __restrict__ Ch, ushort_t* __restrict__ Ch2,
           int M, int N, int K)
{
    __shared__ ushort_t sm[32768];

    int bx = blockIdx.x, by = blockIdx.y;
    swz_xy(bx, by);
    const int tid = threadIdx.x;
    const int l = tid & 63, w = tid >> 6;
    const int wr = w >> 1, wc = w & 1;
    const int lr = l & 15, hi = l >> 4;
    const int row0 = by * 128, col0 = bx * 128;

    // staging: wave w, instr i -> rows (w*4+i)*8 + l/8, swizzled source chunk
    const int lrw = l >> 3;
    const int lch = (l & 7) ^ (lrw & 7);
    const ushort_t* As[4]; const ushort_t* Bs[4]; int lo_[4];
    #pragma unroll
    for (int i = 0; i < 4; ++i) {
        const int g = w * 4 + i;
        As[i] = A  + (size_t)(row0 + g*8 + lrw) * K + lch * 8;
        Bs[i] = WT + (size_t)(col0 + g*8 + lrw) * K + lch * 8;
        lo_[i] = g * 512;
    }
    const int ko[2] = {(hi*8) ^ ((lr&7)*8), (32 + hi*8) ^ ((lr&7)*8)};

    f32x4 acc[4][4] = {};
    const int NT = K >> 6;

    #pragma unroll
    for (int i = 0; i < 4; ++i) {
        g2l16(As[i], &sm[lo_[i]]);
        g2l16(Bs[i], &sm[16384 + lo_[i]]);
    }
    __syncthreads();

    int db = 0;
    for (int t = 0; t < NT; ++t) {
        if (t + 1 < NT) {
            const int nb = db ^ 1;
            #pragma unroll
            for (int i = 0; i < 4; ++i) {
                g2l16(As[i] + (size_t)(t+1)*64, &sm[nb*8192 + lo_[i]]);
                g2l16(Bs[i] + (size_t)(t+1)*64, &sm[16384 + nb*8192 + lo_[i]]);
            }
        }
        #pragma unroll
        for (int ks = 0; ks < 2; ++ks) {
            bf16x8 af[4], bfr[4];
            #pragma unroll
            for (int m = 0; m < 4; ++m)
                af[m] = *(const bf16x8*)&sm[db*8192 + (wr*64 + m*16 + lr)*64 + ko[ks]];
            #pragma unroll
            for (int n = 0; n < 4; ++n)
                bfr[n] = *(const bf16x8*)&sm[16384 + db*8192 + (wc*64 + n*16 + lr)*64 + ko[ks]];
            #pragma unroll
            for (int m = 0; m < 4; ++m)
                #pragma unroll
                for (int n = 0; n < 4; ++n)
                    acc[m][n] = __builtin_amdgcn_mfma_f32_16x16x32_bf16(
                        af[m], bfr[n], acc[m][n], 0, 0, 0);
        }
        __syncthreads();
        db ^= 1;
    }

    // epilogue: C/D frag mapping col = l&15, row = (l>>4)*4 + j
    const bool BF = (EPI == 7) || (Ch != nullptr);
    #pragma unroll
    for (int m = 0; m < 4; ++m) {
        #pragma unroll
        for (int n = 0; n < 4; ++n) {
            const int r0 = row0 + wr*64 + m*16 + hi*4;
            const int c  = col0 + wc*64 + n*16 + lr;
            const float bv = bias ? bias[c] : 0.f;
            #pragma unroll
            for (int j = 0; j < 4; ++j) {
                const int r = r0 + j;
                float v = acc[m][n][j] + bv;
                if (EPI == 1) v = fmaxf(v, 0.f);
                if (EPI == 4) v = v - bf2f(X2[(size_t)r * N + c]);
                if (ACCUM)    v += C[(size_t)r * N + c];
                if (C) C[(size_t)r * N + c] = v;
                if (BF) {
                    float ov = (EPI == 7 && c >= 512) ? gelu_f(v) : v;
                    sm[(wr*64 + m*16 + hi*4 + j) * CST + wc*64 + n*16 + lr] = f2bf(ov);
                }
            }
        }
    }
    if (BF) {
        __syncthreads();
        const int er = tid >> 1, ec = (tid & 1) * 64;
        ushort_t* dst; int nn, dc0;
        if (EPI == 7) {
            nn = 512;
            if (col0 < 512) { dst = Ch;  dc0 = col0; }
            else            { dst = Ch2; dc0 = col0 - 512; }
        } else { dst = Ch; nn = N; dc0 = col0; }
        const uint4* sp = (const uint4*)&sm[er * CST + ec];
        uint4* gp = (uint4*)(dst + (size_t)(row0 + er) * nn + dc0 + ec);
        #pragma unroll
        for (int q = 0; q < 8; ++q) gp[q] = sp[q];
    }
}

// ---------------------------------------------------------------- dual-B GEMM
// LOGITS=false: Ch[M,N] = gelu(A@W1T^T) * (A@W2T^T)
// LOGITS=true : LP[r*6+bx] = sum over this block's 64 cols of gelu(G)*V*wproj[c]
// LDS: A0@0 A1@8192 G0@16384 G1@20480 V0@24576 V1@28672 (64 KiB)
template<bool LOGITS>
__global__ __launch_bounds__(256, 2)
void dual_k(const ushort_t* __restrict__ A, const ushort_t* __restrict__ W1T,
            const ushort_t* __restrict__ W2T, ushort_t* __restrict__ Ch,
            float* __restrict__ LP, const float* __restrict__ wproj,
            int M, int N, int K)
{
    __shared__ ushort_t sm[32768];

    int bx = blockIdx.x, by = blockIdx.y;
    swz_xy(bx, by);
    const int tid = threadIdx.x;
    const int l = tid & 63, w = tid >> 6;
    const int wr = w >> 1, wc = w & 1;
    const int lr = l & 15, hi = l >> 4;
    const int row0 = by * 128, col0 = bx * 64;

    const int lrw = l >> 3;
    const int lch = (l & 7) ^ (lrw & 7);
    const ushort_t* As[4]; int loA[4];
    #pragma unroll
    for (int i = 0; i < 4; ++i) {
        const int g = w * 4 + i;
        As[i] = A + (size_t)(row0 + g*8 + lrw) * K + lch * 8;
        loA[i] = g * 512;
    }
    const ushort_t* Gs[2]; const ushort_t* Vs[2]; int loB[2];
    #pragma unroll
    for (int i = 0; i < 2; ++i) {
        const int g = w * 2 + i;
        Gs[i] = W1T + (size_t)(col0 + g*8 + lrw) * K + lch * 8;
        Vs[i] = W2T + (size_t)(col0 + g*8 + lrw) * K + lch * 8;
        loB[i] = g * 512;
    }
    const int ko[2] = {(hi*8) ^ ((lr&7)*8), (32 + hi*8) ^ ((lr&7)*8)};

    f32x4 ag[4][2] = {}, av[4][2] = {};
    const int NT = K >> 6;

    #pragma unroll
    for (int i = 0; i < 4; ++i) g2l16(As[i], &sm[loA[i]]);
    #pragma unroll
    for (int i = 0; i < 2; ++i) {
        g2l16(Gs[i], &sm[16384 + loB[i]]);
        g2l16(Vs[i], &sm[24576 + loB[i]]);
    }
    __syncthreads();

    int db = 0;
    for (int t = 0; t < NT; ++t) {
        if (t + 1 < NT) {
            const int nb = db ^ 1;
            #pragma unroll
            for (int i = 0; i < 4; ++i)
                g2l16(As[i] + (size_t)(t+1)*64, &sm[nb*8192 + loA[i]]);
            #pragma unroll
            for (int i = 0; i < 2; ++i) {
                g2l16(Gs[i] + (size_t)(t+1)*64, &sm[16384 + nb*4096 + loB[i]]);
                g2l16(Vs[i] + (size_t)(t+1)*64, &sm[24576 + nb*4096 + loB[i]]);
            }
        }
        #pragma unroll
        for (int ks = 0; ks < 2; ++ks) {
            bf16x8 af[4], bg[2], bv[2];
            #pragma unroll
            for (int m = 0; m < 4; ++m)
                af[m] = *(const bf16x8*)&sm[db*8192 + (wr*64 + m*16 + lr)*64 + ko[ks]];
            #pragma unroll
            for (int n = 0; n < 2; ++n) {
                bg[n] = *(const bf16x8*)&sm[16384 + db*4096 + (wc*32 + n*16 + lr)*64 + ko[ks]];
                bv[n] = *(const bf16x8*)&sm[24576 + db*4096 + (wc*32 + n*16 + lr)*64 + ko[ks]];
            }
            #pragma unroll
            for (int m = 0; m < 4; ++m)
                #pragma unroll
                for (int n = 0; n < 2; ++n) {
                    ag[m][n] = __builtin_amdgcn_mfma_f32_16x16x32_bf16(af[m], bg[n], ag[m][n], 0, 0, 0);
                    av[m][n] = __builtin_amdgcn_mfma_f32_16x16x32_bf16(af[m], bv[n], av[m][n], 0, 0, 0);
                }
        }
        __syncthreads();
        db ^= 1;
    }

    if (!LOGITS) {
        #pragma unroll
        for (int m = 0; m < 4; ++m)
            #pragma unroll
            for (int n = 0; n < 2; ++n)
                #pragma unroll
                for (int j = 0; j < 4; ++j)
                    sm[(wr*64 + m*16 + hi*4 + j) * EPW + wc*32 + n*16 + lr] =
                        f2bf(gelu_f(ag[m][n][j]) * av[m][n][j]);
        __syncthreads();
        const int er = tid >> 1, ec = (tid & 1) * 32;
        const uint4* sp = (const uint4*)&sm[er * EPW + ec];
        uint4* gp = (uint4*)(Ch + (size_t)(row0 + er) * N + col0 + ec);
        #pragma unroll
        for (int q = 0; q < 4; ++q) gp[q] = sp[q];
    } else {
        float wp[2];
        #pragma unroll
        for (int n = 0; n < 2; ++n) wp[n] = wproj[col0 + wc*32 + n*16 + lr];
        float* red = (float*)sm;   // [128][2]
        #pragma unroll
        for (int m = 0; m < 4; ++m) {
            #pragma unroll
            for (int j = 0; j < 4; ++j) {
                float s = 0.f;
                #pragma unroll
                for (int n = 0; n < 2; ++n)
                    s += gelu_f(ag[m][n][j]) * av[m][n][j] * wp[n];
                s += __shfl_xor(s, 1);
                s += __shfl_xor(s, 2);
                s += __shfl_xor(s, 4);
                s += __shfl_xor(s, 8);
                if (lr == 0) red[(wr*64 + m*16 + hi*4 + j) * 2 + wc] = s;
            }
        }
        __syncthreads();
        if (tid < 128)
            LP[(size_t)(row0 + tid) * 6 + bx] = red[tid*2] + red[tid*2 + 1];
    }
}

// ---------------------------------------------------------------- RG-LRU recurrence
// ri[M][1024] holds r logits (cols 0..511) and i logits (cols 512..1023),
// biases already folded. Thread owns 8 contiguous d's of one b; loops t.
// Writes prod = h*gate IN-PLACE over u (same element, read-before-write).
__global__ __launch_bounds__(256, 8)
void rec_k(ushort_t* __restrict__ u, const ushort_t* __restrict__ gate,
           const ushort_t* __restrict__ ri, const float* __restrict__ a2,
           int Bc)
{
    const int g = blockIdx.x * 256 + threadIdx.x;   // < Bc*64
    const int b = g >> 6, c8 = (g & 63) << 3;
    float a2v[8];
    *(float4*)&a2v[0] = *(const float4*)&a2[c8];
    *(float4*)&a2v[4] = *(const float4*)&a2[c8 + 4];
    float h[8] = {};
    for (int t = 0; t < SS; ++t) {
        const size_t row = (size_t)t * Bc + b;
        uint4 uw = *(const uint4*)&u[row * DRR + c8];
        uint4 rw = *(const uint4*)&ri[row * 1024 + c8];
        uint4 iw = *(const uint4*)&ri[row * 1024 + 512 + c8];
        uint4 gw = *(const uint4*)&gate[row * DRR + c8];
        const ushort_t* up = (const ushort_t*)&uw;
        const ushort_t* rp = (const ushort_t*)&rw;
        const ushort_t* ip = (const ushort_t*)&iw;
        const ushort_t* gp = (const ushort_t*)&gw;
        ushort_t o[8];
        #pragma unroll
        for (int q = 0; q < 8; ++q) {
            const float rv = sigmoid_f(bf2f(rp[q]));
            const float iv = sigmoid_f(bf2f(ip[q]));
            const float e  = fexp2(a2v[q] * rv);
            const float hv = e * h[q]
                           + sqrtf(fmaxf(0.f, 1.f - e * e)) * (iv * bf2f(up[q]));
            h[q] = hv;
            o[q] = f2bf(hv * bf2f(gp[q]));
        }
        *(uint4*)&u[row * DRR + c8] = *(const uint4*)o;
    }
}

// ---------------------------------------------------------------- small kernels

// one-shot tiled transpose+convert of all 12 weights: WT[n*K+k] = bf16(W[k*N+n])
struct TrArgs { const float* W[12]; };
__global__ void tr_all_k(TrArgs a, ushort_t* __restrict__ wt)
{
    constexpr int KT[12]  = {384,1024,384,384,512,512,512,384,384,1152,384,384};
    constexpr int NTb[12] = {1024,384,512,512,512,512,384,1152,1152,384,384,384};
    constexpr int EOFF[12]= {0,393216,786432,983040,1179648,1441792,1703936,
                             1900544,2342912,2785280,3227648,3375104};
    constexpr int TPRE[13]= {0,384,768,960,1152,1408,1664,1856,2288,2720,3152,3296,3440};
    const int tb = blockIdx.x;
    int s = 0;
    #pragma unroll
    for (int i = 0; i < 12; ++i) if (tb >= TPRE[i+1]) s = i + 1;
    const int rel = tb - TPRE[s];
    const int K = KT[s], N = NTb[s];
    const int ntn = N >> 5;
    const int k0 = (rel / ntn) * 32, n0 = (rel % ntn) * 32;

    __shared__ float ts[32][33];
    const int r = threadIdx.x >> 3, c4 = (threadIdx.x & 7) * 4;
    const float4 v = *(const float4*)&a.W[s][(size_t)(k0 + r) * N + n0 + c4];
    ts[r][c4+0] = v.x; ts[r][c4+1] = v.y; ts[r][c4+2] = v.z; ts[r][c4+3] = v.w;
    __syncthreads();
    ushort_t o4[4];
    #pragma unroll
    for (int q = 0; q < 4; ++q) o4[q] = f2bf(ts[c4 + q][r]);
    *(uint2*)&wt[EOFF[s] + (size_t)(n0 + r) * K + k0 + c4] = *(const uint2*)o4;
}

__global__ void prep_k(const float* __restrict__ rg_bx, const float* __restrict__ rg_by,
                       const float* __restrict__ rg_lam,
                       const float* __restrict__ rg_br, const float* __restrict__ rg_bi,
                       float* __restrict__ bias_xy, float* __restrict__ a2,
                       float* __restrict__ bias_ri)
{
    int i = blockIdx.x * 256 + threadIdx.x;
    if (i < 512) {
        bias_xy[i] = rg_bx[i];
        bias_ri[i] = rg_br[i];
        float lam = rg_lam[i];
        float sp = (lam > 20.f) ? lam : log1pf(expf(lam));
        a2[i] = -8.0f * sp * 1.4426950408889634f;
    } else if (i < 1024) {
        bias_xy[i] = rg_by[i - 512];
        bias_ri[i] = rg_bi[i - 512];
    }
}

__global__ void negm_k(const float* __restrict__ head, const float* __restrict__ pred,
                       ushort_t* __restrict__ negm_h, int b0, int Bc)
{
    int idx = blockIdx.x * 256 + threadIdx.x;        // < Bc*2*384
    int d = idx % DD, rr = idx / DD;
    int j = (rr >= Bc) ? 1 : 0;
    int b = rr - j * Bc;
    size_t off = ((size_t)(KPP + j) * B_TOT + (b0 + b)) * DD + d;
    negm_h[idx] = f2bf(head[off] + pred[off]);
}

// grouped softmax attn + assemble x rows (t-major) + rmsnorm(g1) -> hb bf16
__global__ void asmrms_k(const float* __restrict__ init_f,
                         const float* __restrict__ head, const float* __restrict__ pred,
                         const float* __restrict__ w_ap, const float* __restrict__ b_ap,
                         const float* __restrict__ w_an, const float* __restrict__ b_an,
                         const ushort_t* __restrict__ nf, const float* __restrict__ g1,
                         float* __restrict__ x, ushort_t* __restrict__ hb,
                         int b0, int Bc)
{
    const int lb = blockIdx.x, gb = b0 + lb, lane = threadIdx.x;
    float hp[3][6], nv[2][6], iv[6], wap[6], wan[6];
    #pragma unroll
    for (int q = 0; q < 6; ++q) {
        int d = lane + 64 * q;
        wap[q] = w_ap[d]; wan[q] = w_an[d];
        iv[q] = init_f[(size_t)gb * DD + d];
    }
    float lp[3], ln2[2];
    #pragma unroll
    for (int j = 0; j < 3; ++j) {
        float p = 0.f;
        #pragma unroll
        for (int q = 0; q < 6; ++q) {
            int d = lane + 64 * q;
            size_t off = ((size_t)j * B_TOT + gb) * DD + d;
            float v = head[off] + pred[off];
            hp[j][q] = v;
            p += v * wap[q];
        }
        lp[j] = wave_red_sum(p) + b_ap[0];
    }
    #pragma unroll
    for (int j = 0; j < 2; ++j) {
        float p = 0.f;
        #pragma unroll
        for (int q = 0; q < 6; ++q) {
            int d = lane + 64 * q;
            float v = bf2f(nf[((size_t)j * Bc + lb) * DD + d]);
            nv[j][q] = v;
            p += v * wan[q];
        }
        ln2[j] = wave_red_sum(p) + b_an[0];
    }
    float mp = fmaxf(lp[0], fmaxf(lp[1], lp[2]));
    float e0 = expf(lp[0]-mp), e1 = expf(lp[1]-mp), e2 = expf(lp[2]-mp);
    float sp = e0 + e1 + e2;
    float awp[3] = {e0/sp, e1/sp, e2/sp};
    float mn = fmaxf(ln2[0], ln2[1]);
    float f0 = expf(ln2[0]-mn), f1 = expf(ln2[1]-mn);
    float sn = f0 + f1;
    float awn[2] = {f0/sn, f1/sn};

    #pragma unroll
    for (int t = 0; t < SS; ++t) {
        float rowv[6], ss = 0.f;
        #pragma unroll
        for (int q = 0; q < 6; ++q) {
            float v;
            if (t == 0)      v = iv[q];
            else if (t <= 3) v = hp[t-1][q] * awp[t-1];
            else             v = nv[t-4][q] * awn[t-4];
            rowv[q] = v;
            ss += v * v;
        }
        ss = wave_red_sum(ss);
        float sc = rsqrtf(ss / (float)DD + 1e-6f);
        float* xr = x + (size_t)(t * Bc + lb) * DD;
        ushort_t* hr = hb + (size_t)(t * Bc + lb) * DD;
        #pragma unroll
        for (int q = 0; q < 6; ++q) {
            int d = lane + 64 * q;
            xr[d] = rowv[q];
            hr[d] = f2bf(rowv[q] * g1[d] * sc);
        }
    }
}

__global__ void rms_k(const float* __restrict__ x, const float* __restrict__ g,
                      ushort_t* __restrict__ h)
{
    int row  = blockIdx.x * 4 + (threadIdx.x >> 6);
    int lane = threadIdx.x & 63;
    const float* xr = x + (size_t)row * DD;
    float ss = 0.f;
    for (int d = lane; d < DD; d += 64) { float v = xr[d]; ss += v * v; }
    ss = wave_red_sum(ss);
    float sc = rsqrtf(ss / (float)DD + 1e-6f);
    ushort_t* hr = h + (size_t)row * DD;
    for (int d = lane; d < DD; d += 64) hr[d] = f2bf(xr[d] * g[d] * sc);
}

__global__ void wproj_k(const float* __restrict__ fa_wo, const float* __restrict__ fa_wl,
                        float* __restrict__ wproj)
{
    int d = threadIdx.x;  // 384 threads
    float s = 0.f;
    for (int k = 0; k < DD; ++k) s += fa_wo[(size_t)d * DD + k] * fa_wl[k];
    wproj[d] = s;
}

// logits from 6 partials; softmax over S; out = (1/6) sum_t x_t * w_t
__global__ void final_k(const float* __restrict__ x, const float* __restrict__ lp,
                        const float* __restrict__ fa_bl,
                        float* __restrict__ out, int b0, int Bc)
{
    const int lb = blockIdx.x, gb = b0 + lb, lane = threadIdx.x;
    float lg[SS];
    #pragma unroll
    for (int t = 0; t < SS; ++t) {
        const float* pp = lp + (size_t)(t * Bc + lb) * 6;
        lg[t] = pp[0] + pp[1] + pp[2] + pp[3] + pp[4] + pp[5] + fa_bl[0];
    }
    float m = lg[0];
    #pragma unroll
    for (int t = 1; t < SS; ++t) m = fmaxf(m, lg[t]);
    float e[SS], s = 0.f;
    #pragma unroll
    for (int t = 0; t < SS; ++t) { e[t] = expf(lg[t] - m); s += e[t]; }
    float inv = 1.0f / s;
    #pragma unroll
    for (int q = 0; q < 6; ++q) {
        int d = lane + 64 * q;
        float acc = 0.f;
        #pragma unroll
        for (int t = 0; t < SS; ++t)
            acc += x[(size_t)(t * Bc + lb) * DD + d] * (e[t] * inv);
        out[(size_t)gb * DD + d] = acc * (1.0f / 6.0f);
    }
}

// ---------------------------------------------------------------- launch
extern "C" void kernel_launch(void* const* d_in, const int* in_sizes, int n_in,
                              void* d_out, int out_size, void* d_ws, size_t ws_size,
                              hipStream_t stream)
{
    (void)in_sizes; (void)n_in; (void)out_size;
    const float* init_f  = (const float*)d_in[0];
    const float* head    = (const float*)d_in[1];
    const float* pred    = (const float*)d_in[2];
    const float* w_ap    = (const float*)d_in[3];
    const float* b_ap    = (const float*)d_in[4];
    const float* w_an    = (const float*)d_in[5];
    const float* b_an    = (const float*)d_in[6];
    const float* nt_w1   = (const float*)d_in[7];
    const float* nt_b1   = (const float*)d_in[8];
    const float* nt_w2   = (const float*)d_in[9];
    const float* nt_b2   = (const float*)d_in[10];
    const float* g1      = (const float*)d_in[11];
    const float* rg_wx   = (const float*)d_in[12];
    const float* rg_bx   = (const float*)d_in[13];
    const float* rg_wy   = (const float*)d_in[14];
    const float* rg_by   = (const float*)d_in[15];
    const float* rg_wr   = (const float*)d_in[16];
    const float* rg_br   = (const float*)d_in[17];
    const float* rg_wi   = (const float*)d_in[18];
    const float* rg_bi   = (const float*)d_in[19];
    const float* rg_lam  = (const float*)d_in[20];
    const float* rg_wo   = (const float*)d_in[21];
    const float* rg_bo   = (const float*)d_in[22];
    const float* g2      = (const float*)d_in[23];
    const float* mlp_wg  = (const float*)d_in[24];
    const float* mlp_wv  = (const float*)d_in[25];
    const float* mlp_wo  = (const float*)d_in[26];
    const float* fa_wg   = (const float*)d_in[27];
    const float* fa_wv   = (const float*)d_in[28];
    const float* fa_wo   = (const float*)d_in[29];
    const float* fa_wl   = (const float*)d_in[30];
    const float* fa_bl   = (const float*)d_in[31];
    float* out = (float*)d_out;

    float* ws_f    = (float*)d_ws;
    float* wproj   = ws_f;                 // 512 f32
    float* bias_xy = ws_f + 512;           // 1024
    float* a2      = ws_f + 1536;          // 512
    float* bias_ri = ws_f + 2048;          // 1024
    ushort_t* wt   = (ushort_t*)(ws_f + 3072);

    // bf16 transposed weights (bf16-elem offsets; matches tr_all_k EOFF)
    ushort_t* ntw1T = wt + 0;
    ushort_t* ntw2T = wt + 393216;
    ushort_t* wxyT  = wt + 786432;   // wx rows [0,512), wy rows [512,1024)
    ushort_t* wriT  = wt + 1179648;  // wr rows [0,512), wi rows [512,1024) (adjacent)
    ushort_t* woT   = wt + 1703936;
    ushort_t* mwgT  = wt + 1900544;
    ushort_t* mwvT  = wt + 2342912;
    ushort_t* mwoT  = wt + 2785280;
    ushort_t* fwgT  = wt + 3227648;
    ushort_t* fwvT  = wt + 3375104;  // end 3522560 bf16 = 1761280 f32

    TrArgs ta;
    ta.W[0]=nt_w1; ta.W[1]=nt_w2; ta.W[2]=rg_wx; ta.W[3]=rg_wy;
    ta.W[4]=rg_wr; ta.W[5]=rg_wi; ta.W[6]=rg_wo; ta.W[7]=mlp_wg;
    ta.W[8]=mlp_wv; ta.W[9]=mlp_wo; ta.W[10]=fa_wg; ta.W[11]=fa_wv;
    tr_all_k<<<3440, 256, 0, stream>>>(ta, wt);
    prep_k<<<4, 256, 0, stream>>>(rg_bx, rg_by, rg_lam, rg_br, rg_bi,
                                  bias_xy, a2, bias_ri);
    wproj_k<<<1, DD, 0, stream>>>(fa_wo, fa_wl, wproj);

    // per-b arena 8448 f32 with lifetime-overlaid slots
    const size_t fixed_f32 = 3072 + 1761280;
    const size_t per_b_f32 = 8448;
    int Bc = B_TOT;
    while (Bc > 128 && (fixed_f32 + per_b_f32 * (size_t)Bc) * 4 > ws_size) Bc >>= 1;

    float* arena = ws_f + fixed_f32;

    for (int b0 = 0; b0 < B_TOT; b0 += Bc) {
        const int M  = Bc * SS;
        const int M2 = Bc * KNN;
        float*    xbuf = arena;                                    // [0,2304) live always
        ushort_t* negm = (ushort_t*)(arena + (size_t)2304 * Bc);   // [2304,2688)
        ushort_t* hid  = (ushort_t*)(arena + (size_t)2688 * Bc);   // [2688,3712)
        ushort_t* nf   = (ushort_t*)(arena + (size_t)3712 * Bc);   // [3712,4096)
        ushort_t* hb   = (ushort_t*)(arena + (size_t)4096 * Bc);   // [4096,5248)
        ushort_t* uh   = (ushort_t*)(arena + (size_t)5376 * Bc);   // [5376,6912) (u, then prod in-place)
        ushort_t* gth  = (ushort_t*)(arena + (size_t)6912 * Bc);   // [6912,8448)
        ushort_t* ri   = (ushort_t*)(arena + (size_t)2304 * Bc);   // [2304,5376) (after hb dead)
        ushort_t* h2   = (ushort_t*)(arena + (size_t)2304 * Bc);   // [2304,3456)
        ushort_t* Th   = (ushort_t*)(arena + (size_t)3456 * Bc);   // [3456,6912)
        ushort_t* xh   = (ushort_t*)(arena + (size_t)6912 * Bc);   // [6912,8064)
        float*    lpb  = arena + (size_t)2304 * Bc;                // [2304,2340)

        // stage 1: neg messages + MLP residual + attention assembly (+rms g1)
        negm_k<<<Bc * 3, 256, 0, stream>>>(head, pred, negm, b0, Bc);
        bgemm<1, false><<<dim3(HH/128, M2/128), 256, 0, stream>>>(
            negm, ntw1T, nt_b1, nullptr, nullptr, hid, nullptr, M2, HH, DD);
        bgemm<4, false><<<dim3(DD/128, M2/128), 256, 0, stream>>>(
            hid, ntw2T, nt_b2, negm, nullptr, nf, nullptr, M2, DD, HH);
        asmrms_k<<<Bc, 64, 0, stream>>>(init_f, head, pred, w_ap, b_ap, w_an, b_an,
                                        nf, g1, xbuf, hb, b0, Bc);

        // Griffin recurrent branch: u|gate GEMM, r|i logits GEMM, recurrence, wo
        bgemm<7, false><<<dim3(1024/128, M/128), 256, 0, stream>>>(
            hb, wxyT, bias_xy, nullptr, nullptr, uh, gth, M, 1024, DD);
        bgemm<0, false><<<dim3(1024/128, M/128), 256, 0, stream>>>(
            uh, wriT, bias_ri, nullptr, nullptr, ri, nullptr, M, 1024, DRR);
        rec_k<<<Bc / 4, 256, 0, stream>>>(uh, gth, ri, a2, Bc);
        bgemm<0, true><<<dim3(DD/128, M/128), 256, 0, stream>>>(
            uh, woT, rg_bo, nullptr, xbuf, nullptr, nullptr, M, DD, DRR);

        // gated-MLP residual branch
        rms_k<<<M / 4, 256, 0, stream>>>(xbuf, g2, h2);
        dual_k<false><<<dim3(DMM/64, M/128), 256, 0, stream>>>(
            h2, mwgT, mwvT, Th, nullptr, nullptr, M, DMM, DD);
        bgemm<0, true><<<dim3(DD/128, M/128), 256, 0, stream>>>(
            Th, mwoT, nullptr, nullptr, xbuf, xh, nullptr, M, DD, DMM);

        // final attention: fused dual-GEMM -> per-row logit partials
        dual_k<true><<<dim3(DD/64, M/128), 256, 0, stream>>>(
            xh, fwgT, fwvT, nullptr, lpb, wproj, M, DD, DD);
        final_k<<<Bc, 64, 0, stream>>>(xbuf, lpb, fa_bl, out, b0, Bc);
    }
}

// Round 8
// 1611.656 us; speedup vs baseline: 2.7210x; 1.0294x over previous
//
#include <hip/hip_runtime.h>
#include <hip/hip_bf16.h>

// Problem constants (from reference)
#define B_TOT 16384
#define DD    384
#define HH    1024
#define DRR   512
#define DMM   1152
#define SS    6     // 1 + KP + KN
#define KPP   3
#define KNN   2

typedef unsigned short ushort_t;
typedef __bf16 bf16x8 __attribute__((ext_vector_type(8)));
typedef float  f32x4  __attribute__((ext_vector_type(4)));

#define CST 136   // bgemm epilogue LDS stride (bf16)
#define EPW 72    // dual epilogue LDS stride

// ---------------------------------------------------------------- helpers
__device__ __forceinline__ float fexp2(float x) { return __builtin_amdgcn_exp2f(x); }
__device__ __forceinline__ float frcp(float x)  { return __builtin_amdgcn_rcpf(x); }
__device__ __forceinline__ float sigmoid_f(float x) {
    return frcp(1.f + fexp2(-1.4426950408889634f * x));
}
__device__ __forceinline__ float gelu_f(float x) {
    float z = 0.7978845608028654f * x * (1.f + 0.044715f * x * x);
    return x * frcp(1.f + fexp2(-2.885390081777927f * z));
}
__device__ __forceinline__ float wave_red_sum(float v) {
    #pragma unroll
    for (int off = 32; off; off >>= 1) v += __shfl_xor(v, off);
    return v;
}
__device__ __forceinline__ ushort_t f2bf(float v) {
    __hip_bfloat16 h = __float2bfloat16(v);
    return *reinterpret_cast<ushort_t*>(&h);
}
__device__ __forceinline__ float bf2f(ushort_t u) {
    unsigned int x = ((unsigned int)u) << 16;
    return __uint_as_float(x);
}
// async global->LDS, 16B per lane
__device__ __forceinline__ void g2l16(const ushort_t* g, ushort_t* l) {
    __builtin_amdgcn_global_load_lds(
        (const __attribute__((address_space(1))) void*)g,
        (__attribute__((address_space(3))) void*)l, 16, 0, 0);
}
// XCD-aware bijective block swizzle
__device__ __forceinline__ void swz_xy(int& bx, int& by) {
    const int nx = gridDim.x;
    const int nwg = nx * gridDim.y;
    const int h = by * nx + bx;
    const int q = nwg >> 3, r = nwg & 7;
    const int xcd = h & 7, lo = h >> 3;
    const int lin = (xcd < r) ? (xcd * (q + 1) + lo)
                              : (r * (q + 1) + (xcd - r) * q + lo);
    bx = lin % nx;
    by = lin / nx;
}

// ---------------------------------------------------------------- MFMA GEMM
// Counted-vmcnt prefetch-distance-2 pipeline (T3/T4):
//   per tile: ds_read all frags -> lgkmcnt(0) -> barrier -> stage t+2 ->
//   MFMA (regs) -> vmcnt(8) (t+1 landed, t+2 in flight) -> barrier.
// vmcnt never drains to 0 in steady state; loads span barriers.
template<int EPI, bool ACCUM>
__global__ __launch_bounds__(256, 2)
void bgemm(const ushort_t* __restrict__ A, const ushort_t* __restrict__ WT,
           const float* __restrict__ bias, const ushort_t* __restrict__ X2,
           float* __restrict__ C, ushort_t* __restrict__ Ch, ushort_t* __restrict__ Ch2,
           int M, int N, int K)
{
    __shared__ ushort_t sm[32768];

    int bx = blockIdx.x, by = blockIdx.y;
    swz_xy(bx, by);
    const int tid = threadIdx.x;
    const int l = tid & 63, w = tid >> 6;
    const int wr = w >> 1, wc = w & 1;
    const int lr = l & 15, hi = l >> 4;
    const int row0 = by * 128, col0 = bx * 128;

    const int lrw = l >> 3;
    const int lch = (l & 7) ^ (lrw & 7);
    const ushort_t* As[4]; const ushort_t* Bs[4]; int lo_[4];
    #pragma unroll
    for (int i = 0; i < 4; ++i) {
        const int g = w * 4 + i;
        As[i] = A  + (size_t)(row0 + g*8 + lrw) * K + lch * 8;
        Bs[i] = WT + (size_t)(col0 + g*8 + lrw) * K + lch * 8;
        lo_[i] = g * 512;
    }
    const int ko[2] = {(hi*8) ^ ((lr&7)*8), (32 + hi*8) ^ ((lr&7)*8)};

    f32x4 acc[4][4] = {};
    const int NT = K >> 6;   // >= 6 for all our shapes

    // prologue: stage t0 -> buf0, t1 -> buf1; wait t0 only (t1 stays in flight)
    #pragma unroll
    for (int i = 0; i < 4; ++i) {
        g2l16(As[i], &sm[lo_[i]]);
        g2l16(Bs[i], &sm[16384 + lo_[i]]);
    }
    #pragma unroll
    for (int i = 0; i < 4; ++i) {
        g2l16(As[i] + 64, &sm[8192 + lo_[i]]);
        g2l16(Bs[i] + 64, &sm[16384 + 8192 + lo_[i]]);
    }
    asm volatile("s_waitcnt vmcnt(8)" ::: "memory");
    __builtin_amdgcn_s_barrier();

    int db = 0;
    for (int t = 0; t < NT; ++t) {
        bf16x8 af[2][4], bfr[2][4];
        #pragma unroll
        for (int ks = 0; ks < 2; ++ks) {
            #pragma unroll
            for (int m = 0; m < 4; ++m)
                af[ks][m] = *(const bf16x8*)&sm[db*8192 + (wr*64 + m*16 + lr)*64 + ko[ks]];
            #pragma unroll
            for (int n = 0; n < 4; ++n)
                bfr[ks][n] = *(const bf16x8*)&sm[16384 + db*8192 + (wc*64 + n*16 + lr)*64 + ko[ks]];
        }
        asm volatile("s_waitcnt lgkmcnt(0)" ::: "memory");
        __builtin_amdgcn_sched_barrier(0);
        __builtin_amdgcn_s_barrier();                 // all waves done reading buf[db]
        if (t + 2 < NT) {                             // refill buf[db] with tile t+2
            #pragma unroll
            for (int i = 0; i < 4; ++i) {
                g2l16(As[i] + (size_t)(t+2)*64, &sm[db*8192 + lo_[i]]);
                g2l16(Bs[i] + (size_t)(t+2)*64, &sm[16384 + db*8192 + lo_[i]]);
            }
        }
        #pragma unroll
        for (int ks = 0; ks < 2; ++ks)
            #pragma unroll
            for (int m = 0; m < 4; ++m)
                #pragma unroll
                for (int n = 0; n < 4; ++n)
                    acc[m][n] = __builtin_amdgcn_mfma_f32_16x16x32_bf16(
                        af[ks][m], bfr[ks][n], acc[m][n], 0, 0, 0);
        if (t + 1 < NT) {
            if (t + 2 < NT) asm volatile("s_waitcnt vmcnt(8)" ::: "memory");
            else            asm volatile("s_waitcnt vmcnt(0)" ::: "memory");
            __builtin_amdgcn_s_barrier();             // buf[db^1] (tile t+1) ready
        }
        db ^= 1;
    }

    // epilogue: C/D frag mapping col = l&15, row = (l>>4)*4 + j
    const bool BF = (EPI == 7) || (Ch != nullptr);
    #pragma unroll
    for (int m = 0; m < 4; ++m) {
        #pragma unroll
        for (int n = 0; n < 4; ++n) {
            const int r0 = row0 + wr*64 + m*16 + hi*4;
            const int c  = col0 + wc*64 + n*16 + lr;
            const float bv = bias ? bias[c] : 0.f;
            #pragma unroll
            for (int j = 0; j < 4; ++j) {
                const int r = r0 + j;
                float v = acc[m][n][j] + bv;
                if (EPI == 1) v = fmaxf(v, 0.f);
                if (EPI == 4) v = v - bf2f(X2[(size_t)r * N + c]);
                if (ACCUM)    v += C[(size_t)r * N + c];
                if (C) C[(size_t)r * N + c] = v;
                if (BF) {
                    float ov = (EPI == 7 && c >= 512) ? gelu_f(v) : v;
                    sm[(wr*64 + m*16 + hi*4 + j) * CST + wc*64 + n*16 + lr] = f2bf(ov);
                }
            }
        }
    }
    if (BF) {
        __syncthreads();
        const int er = tid >> 1, ec = (tid & 1) * 64;
        ushort_t* dst; int nn, dc0;
        if (EPI == 7) {
            nn = 512;
            if (col0 < 512) { dst = Ch;  dc0 = col0; }
            else            { dst = Ch2; dc0 = col0 - 512; }
        } else { dst = Ch; nn = N; dc0 = col0; }
        const uint4* sp = (const uint4*)&sm[er * CST + ec];
        uint4* gp = (uint4*)(dst + (size_t)(row0 + er) * nn + dc0 + ec);
        #pragma unroll
        for (int q = 0; q < 8; ++q) gp[q] = sp[q];
    }
}

// ---------------------------------------------------------------- dual-B GEMM
// Same counted-vmcnt pipeline; L=8 loads/tile (4A + 2G + 2V).
// LDS: A0@0 A1@8192 G0@16384 G1@20480 V0@24576 V1@28672 (64 KiB)
template<bool LOGITS>
__global__ __launch_bounds__(256, 2)
void dual_k(const ushort_t* __restrict__ A, const ushort_t* __restrict__ W1T,
            const ushort_t* __restrict__ W2T, ushort_t* __restrict__ Ch,
            float* __restrict__ LP, const float* __restrict__ wproj,
            int M, int N, int K)
{
    __shared__ ushort_t sm[32768];

    int bx = blockIdx.x, by = blockIdx.y;
    swz_xy(bx, by);
    const int tid = threadIdx.x;
    const int l = tid & 63, w = tid >> 6;
    const int wr = w >> 1, wc = w & 1;
    const int lr = l & 15, hi = l >> 4;
    const int row0 = by * 128, col0 = bx * 64;

    const int lrw = l >> 3;
    const int lch = (l & 7) ^ (lrw & 7);
    const ushort_t* As[4]; int loA[4];
    #pragma unroll
    for (int i = 0; i < 4; ++i) {
        const int g = w * 4 + i;
        As[i] = A + (size_t)(row0 + g*8 + lrw) * K + lch * 8;
        loA[i] = g * 512;
    }
    const ushort_t* Gs[2]; const ushort_t* Vs[2]; int loB[2];
    #pragma unroll
    for (int i = 0; i < 2; ++i) {
        const int g = w * 2 + i;
        Gs[i] = W1T + (size_t)(col0 + g*8 + lrw) * K + lch * 8;
        Vs[i] = W2T + (size_t)(col0 + g*8 + lrw) * K + lch * 8;
        loB[i] = g * 512;
    }
    const int ko[2] = {(hi*8) ^ ((lr&7)*8), (32 + hi*8) ^ ((lr&7)*8)};

    f32x4 ag[4][2] = {}, av[4][2] = {};
    const int NT = K >> 6;

    // prologue: stage t0, t1
    #pragma unroll
    for (int i = 0; i < 4; ++i) g2l16(As[i], &sm[loA[i]]);
    #pragma unroll
    for (int i = 0; i < 2; ++i) {
        g2l16(Gs[i], &sm[16384 + loB[i]]);
        g2l16(Vs[i], &sm[24576 + loB[i]]);
    }
    #pragma unroll
    for (int i = 0; i < 4; ++i) g2l16(As[i] + 64, &sm[8192 + loA[i]]);
    #pragma unroll
    for (int i = 0; i < 2; ++i) {
        g2l16(Gs[i] + 64, &sm[16384 + 4096 + loB[i]]);
        g2l16(Vs[i] + 64, &sm[24576 + 4096 + loB[i]]);
    }
    asm volatile("s_waitcnt vmcnt(8)" ::: "memory");
    __builtin_amdgcn_s_barrier();

    int db = 0;
    for (int t = 0; t < NT; ++t) {
        bf16x8 af[2][4], bg[2][2], bv[2][2];
        #pragma unroll
        for (int ks = 0; ks < 2; ++ks) {
            #pragma unroll
            for (int m = 0; m < 4; ++m)
                af[ks][m] = *(const bf16x8*)&sm[db*8192 + (wr*64 + m*16 + lr)*64 + ko[ks]];
            #pragma unroll
            for (int n = 0; n < 2; ++n) {
                bg[ks][n] = *(const bf16x8*)&sm[16384 + db*4096 + (wc*32 + n*16 + lr)*64 + ko[ks]];
                bv[ks][n] = *(const bf16x8*)&sm[24576 + db*4096 + (wc*32 + n*16 + lr)*64 + ko[ks]];
            }
        }
        asm volatile("s_waitcnt lgkmcnt(0)" ::: "memory");
        __builtin_amdgcn_sched_barrier(0);
        __builtin_amdgcn_s_barrier();
        if (t + 2 < NT) {
            #pragma unroll
            for (int i = 0; i < 4; ++i)
                g2l16(As[i] + (size_t)(t+2)*64, &sm[db*8192 + loA[i]]);
            #pragma unroll
            for (int i = 0; i < 2; ++i) {
                g2l16(Gs[i] + (size_t)(t+2)*64, &sm[16384 + db*4096 + loB[i]]);
                g2l16(Vs[i] + (size_t)(t+2)*64, &sm[24576 + db*4096 + loB[i]]);
            }
        }
        #pragma unroll
        for (int ks = 0; ks < 2; ++ks)
            #pragma unroll
            for (int m = 0; m < 4; ++m)
                #pragma unroll
                for (int n = 0; n < 2; ++n) {
                    ag[m][n] = __builtin_amdgcn_mfma_f32_16x16x32_bf16(af[ks][m], bg[ks][n], ag[m][n], 0, 0, 0);
                    av[m][n] = __builtin_amdgcn_mfma_f32_16x16x32_bf16(af[ks][m], bv[ks][n], av[m][n], 0, 0, 0);
                }
        if (t + 1 < NT) {
            if (t + 2 < NT) asm volatile("s_waitcnt vmcnt(8)" ::: "memory");
            else            asm volatile("s_waitcnt vmcnt(0)" ::: "memory");
            __builtin_amdgcn_s_barrier();
        }
        db ^= 1;
    }

    if (!LOGITS) {
        #pragma unroll
        for (int m = 0; m < 4; ++m)
            #pragma unroll
            for (int n = 0; n < 2; ++n)
                #pragma unroll
                for (int j = 0; j < 4; ++j)
                    sm[(wr*64 + m*16 + hi*4 + j) * EPW + wc*32 + n*16 + lr] =
                        f2bf(gelu_f(ag[m][n][j]) * av[m][n][j]);
        __syncthreads();
        const int er = tid >> 1, ec = (tid & 1) * 32;
        const uint4* sp = (const uint4*)&sm[er * EPW + ec];
        uint4* gp = (uint4*)(Ch + (size_t)(row0 + er) * N + col0 + ec);
        #pragma unroll
        for (int q = 0; q < 4; ++q) gp[q] = sp[q];
    } else {
        float wp[2];
        #pragma unroll
        for (int n = 0; n < 2; ++n) wp[n] = wproj[col0 + wc*32 + n*16 + lr];
        float* red = (float*)sm;   // [128][2]
        #pragma unroll
        for (int m = 0; m < 4; ++m) {
            #pragma unroll
            for (int j = 0; j < 4; ++j) {
                float s = 0.f;
                #pragma unroll
                for (int n = 0; n < 2; ++n)
                    s += gelu_f(ag[m][n][j]) * av[m][n][j] * wp[n];
                s += __shfl_xor(s, 1);
                s += __shfl_xor(s, 2);
                s += __shfl_xor(s, 4);
                s += __shfl_xor(s, 8);
                if (lr == 0) red[(wr*64 + m*16 + hi*4 + j) * 2 + wc] = s;
            }
        }
        __syncthreads();
        if (tid < 128)
            LP[(size_t)(row0 + tid) * 6 + bx] = red[tid*2] + red[tid*2 + 1];
    }
}

// ---------------------------------------------------------------- RG-LRU recurrence
__global__ __launch_bounds__(256, 8)
void rec_k(ushort_t* __restrict__ u, const ushort_t* __restrict__ gate,
           const ushort_t* __restrict__ ri, const float* __restrict__ a2,
           int Bc)
{
    const int g = blockIdx.x * 256 + threadIdx.x;   // < Bc*64
    const int b = g >> 6, c8 = (g & 63) << 3;
    float a2v[8];
    *(float4*)&a2v[0] = *(const float4*)&a2[c8];
    *(float4*)&a2v[4] = *(const float4*)&a2[c8 + 4];
    float h[8] = {};
    for (int t = 0; t < SS; ++t) {
        const size_t row = (size_t)t * Bc + b;
        uint4 uw = *(const uint4*)&u[row * DRR + c8];
        uint4 rw = *(const uint4*)&ri[row * 1024 + c8];
        uint4 iw = *(const uint4*)&ri[row * 1024 + 512 + c8];
        uint4 gw = *(const uint4*)&gate[row * DRR + c8];
        const ushort_t* up = (const ushort_t*)&uw;
        const ushort_t* rp = (const ushort_t*)&rw;
        const ushort_t* ip = (const ushort_t*)&iw;
        const ushort_t* gp = (const ushort_t*)&gw;
        ushort_t o[8];
        #pragma unroll
        for (int q = 0; q < 8; ++q) {
            const float rv = sigmoid_f(bf2f(rp[q]));
            const float iv = sigmoid_f(bf2f(ip[q]));
            const float e  = fexp2(a2v[q] * rv);
            const float hv = e * h[q]
                           + sqrtf(fmaxf(0.f, 1.f - e * e)) * (iv * bf2f(up[q]));
            h[q] = hv;
            o[q] = f2bf(hv * bf2f(gp[q]));
        }
        *(uint4*)&u[row * DRR + c8] = *(const uint4*)o;
    }
}

// ---------------------------------------------------------------- small kernels

struct TrArgs { const float* W[12]; };
__global__ void tr_all_k(TrArgs a, ushort_t* __restrict__ wt)
{
    constexpr int KT[12]  = {384,1024,384,384,512,512,512,384,384,1152,384,384};
    constexpr int NTb[12] = {1024,384,512,512,512,512,384,1152,1152,384,384,384};
    constexpr int EOFF[12]= {0,393216,786432,983040,1179648,1441792,1703936,
                             1900544,2342912,2785280,3227648,3375104};
    constexpr int TPRE[13]= {0,384,768,960,1152,1408,1664,1856,2288,2720,3152,3296,3440};
    const int tb = blockIdx.x;
    int s = 0;
    #pragma unroll
    for (int i = 0; i < 12; ++i) if (tb >= TPRE[i+1]) s = i + 1;
    const int rel = tb - TPRE[s];
    const int K = KT[s], N = NTb[s];
    const int ntn = N >> 5;
    const int k0 = (rel / ntn) * 32, n0 = (rel % ntn) * 32;

    __shared__ float ts[32][33];
    const int r = threadIdx.x >> 3, c4 = (threadIdx.x & 7) * 4;
    const float4 v = *(const float4*)&a.W[s][(size_t)(k0 + r) * N + n0 + c4];
    ts[r][c4+0] = v.x; ts[r][c4+1] = v.y; ts[r][c4+2] = v.z; ts[r][c4+3] = v.w;
    __syncthreads();
    ushort_t o4[4];
    #pragma unroll
    for (int q = 0; q < 4; ++q) o4[q] = f2bf(ts[c4 + q][r]);
    *(uint2*)&wt[EOFF[s] + (size_t)(n0 + r) * K + k0 + c4] = *(const uint2*)o4;
}

__global__ void prep_k(const float* __restrict__ rg_bx, const float* __restrict__ rg_by,
                       const float* __restrict__ rg_lam,
                       const float* __restrict__ rg_br, const float* __restrict__ rg_bi,
                       float* __restrict__ bias_xy, float* __restrict__ a2,
                       float* __restrict__ bias_ri)
{
    int i = blockIdx.x * 256 + threadIdx.x;
    if (i < 512) {
        bias_xy[i] = rg_bx[i];
        bias_ri[i] = rg_br[i];
        float lam = rg_lam[i];
        float sp = (lam > 20.f) ? lam : log1pf(expf(lam));
        a2[i] = -8.0f * sp * 1.4426950408889634f;
    } else if (i < 1024) {
        bias_xy[i] = rg_by[i - 512];
        bias_ri[i] = rg_bi[i - 512];
    }
}

__global__ void negm_k(const float* __restrict__ head, const float* __restrict__ pred,
                       ushort_t* __restrict__ negm_h, int b0, int Bc)
{
    int idx = blockIdx.x * 256 + threadIdx.x;        // < Bc*2*384
    int d = idx % DD, rr = idx / DD;
    int j = (rr >= Bc) ? 1 : 0;
    int b = rr - j * Bc;
    size_t off = ((size_t)(KPP + j) * B_TOT + (b0 + b)) * DD + d;
    negm_h[idx] = f2bf(head[off] + pred[off]);
}

__global__ void asmrms_k(const float* __restrict__ init_f,
                         const float* __restrict__ head, const float* __restrict__ pred,
                         const float* __restrict__ w_ap, const float* __restrict__ b_ap,
                         const float* __restrict__ w_an, const float* __restrict__ b_an,
                         const ushort_t* __restrict__ nf, const float* __restrict__ g1,
                         float* __restrict__ x, ushort_t* __restrict__ hb,
                         int b0, int Bc)
{
    const int lb = blockIdx.x, gb = b0 + lb, lane = threadIdx.x;
    float hp[3][6], nv[2][6], iv[6], wap[6], wan[6];
    #pragma unroll
    for (int q = 0; q < 6; ++q) {
        int d = lane + 64 * q;
        wap[q] = w_ap[d]; wan[q] = w_an[d];
        iv[q] = init_f[(size_t)gb * DD + d];
    }
    float lp[3], ln2[2];
    #pragma unroll
    for (int j = 0; j < 3; ++j) {
        float p = 0.f;
        #pragma unroll
        for (int q = 0; q < 6; ++q) {
            int d = lane + 64 * q;
            size_t off = ((size_t)j * B_TOT + gb) * DD + d;
            float v = head[off] + pred[off];
            hp[j][q] = v;
            p += v * wap[q];
        }
        lp[j] = wave_red_sum(p) + b_ap[0];
    }
    #pragma unroll
    for (int j = 0; j < 2; ++j) {
        float p = 0.f;
        #pragma unroll
        for (int q = 0; q < 6; ++q) {
            int d = lane + 64 * q;
            float v = bf2f(nf[((size_t)j * Bc + lb) * DD + d]);
            nv[j][q] = v;
            p += v * wan[q];
        }
        ln2[j] = wave_red_sum(p) + b_an[0];
    }
    float mp = fmaxf(lp[0], fmaxf(lp[1], lp[2]));
    float e0 = expf(lp[0]-mp), e1 = expf(lp[1]-mp), e2 = expf(lp[2]-mp);
    float sp = e0 + e1 + e2;
    float awp[3] = {e0/sp, e1/sp, e2/sp};
    float mn = fmaxf(ln2[0], ln2[1]);
    float f0 = expf(ln2[0]-mn), f1 = expf(ln2[1]-mn);
    float sn = f0 + f1;
    float awn[2] = {f0/sn, f1/sn};

    #pragma unroll
    for (int t = 0; t < SS; ++t) {
        float rowv[6], ss = 0.f;
        #pragma unroll
        for (int q = 0; q < 6; ++q) {
            float v;
            if (t == 0)      v = iv[q];
            else if (t <= 3) v = hp[t-1][q] * awp[t-1];
            else             v = nv[t-4][q] * awn[t-4];
            rowv[q] = v;
            ss += v * v;
        }
        ss = wave_red_sum(ss);
        float sc = rsqrtf(ss / (float)DD + 1e-6f);
        float* xr = x + (size_t)(t * Bc + lb) * DD;
        ushort_t* hr = hb + (size_t)(t * Bc + lb) * DD;
        #pragma unroll
        for (int q = 0; q < 6; ++q) {
            int d = lane + 64 * q;
            xr[d] = rowv[q];
            hr[d] = f2bf(rowv[q] * g1[d] * sc);
        }
    }
}

__global__ void rms_k(const float* __restrict__ x, const float* __restrict__ g,
                      ushort_t* __restrict__ h)
{
    int row  = blockIdx.x * 4 + (threadIdx.x >> 6);
    int lane = threadIdx.x & 63;
    const float* xr = x + (size_t)row * DD;
    float ss = 0.f;
    for (int d = lane; d < DD; d += 64) { float v = xr[d]; ss += v * v; }
    ss = wave_red_sum(ss);
    float sc = rsqrtf(ss / (float)DD + 1e-6f);
    ushort_t* hr = h + (size_t)row * DD;
    for (int d = lane; d < DD; d += 64) hr[d] = f2bf(xr[d] * g[d] * sc);
}

__global__ void wproj_k(const float* __restrict__ fa_wo, const float* __restrict__ fa_wl,
                        float* __restrict__ wproj)
{
    int d = threadIdx.x;  // 384 threads
    float s = 0.f;
    for (int k = 0; k < DD; ++k) s += fa_wo[(size_t)d * DD + k] * fa_wl[k];
    wproj[d] = s;
}

__global__ void final_k(const float* __restrict__ x, const float* __restrict__ lp,
                        const float* __restrict__ fa_bl,
                        float* __restrict__ out, int b0, int Bc)
{
    const int lb = blockIdx.x, gb = b0 + lb, lane = threadIdx.x;
    float lg[SS];
    #pragma unroll
    for (int t = 0; t < SS; ++t) {
        const float* pp = lp + (size_t)(t * Bc + lb) * 6;
        lg[t] = pp[0] + pp[1] + pp[2] + pp[3] + pp[4] + pp[5] + fa_bl[0];
    }
    float m = lg[0];
    #pragma unroll
    for (int t = 1; t < SS; ++t) m = fmaxf(m, lg[t]);
    float e[SS], s = 0.f;
    #pragma unroll
    for (int t = 0; t < SS; ++t) { e[t] = expf(lg[t] - m); s += e[t]; }
    float inv = 1.0f / s;
    #pragma unroll
    for (int q = 0; q < 6; ++q) {
        int d = lane + 64 * q;
        float acc = 0.f;
        #pragma unroll
        for (int t = 0; t < SS; ++t)
            acc += x[(size_t)(t * Bc + lb) * DD + d] * (e[t] * inv);
        out[(size_t)gb * DD + d] = acc * (1.0f / 6.0f);
    }
}

// ---------------------------------------------------------------- launch
extern "C" void kernel_launch(void* const* d_in, const int* in_sizes, int n_in,
                              void* d_out, int out_size, void* d_ws, size_t ws_size,
                              hipStream_t stream)
{
    (void)in_sizes; (void)n_in; (void)out_size;
    const float* init_f  = (const float*)d_in[0];
    const float* head    = (const float*)d_in[1];
    const float* pred    = (const float*)d_in[2];
    const float* w_ap    = (const float*)d_in[3];
    const float* b_ap    = (const float*)d_in[4];
    const float* w_an    = (const float*)d_in[5];
    const float* b_an    = (const float*)d_in[6];
    const float* nt_w1   = (const float*)d_in[7];
    const float* nt_b1   = (const float*)d_in[8];
    const float* nt_w2   = (const float*)d_in[9];
    const float* nt_b2   = (const float*)d_in[10];
    const float* g1      = (const float*)d_in[11];
    const float* rg_wx   = (const float*)d_in[12];
    const float* rg_bx   = (const float*)d_in[13];
    const float* rg_wy   = (const float*)d_in[14];
    const float* rg_by   = (const float*)d_in[15];
    const float* rg_wr   = (const float*)d_in[16];
    const float* rg_br   = (const float*)d_in[17];
    const float* rg_wi   = (const float*)d_in[18];
    const float* rg_bi   = (const float*)d_in[19];
    const float* rg_lam  = (const float*)d_in[20];
    const float* rg_wo   = (const float*)d_in[21];
    const float* rg_bo   = (const float*)d_in[22];
    const float* g2      = (const float*)d_in[23];
    const float* mlp_wg  = (const float*)d_in[24];
    const float* mlp_wv  = (const float*)d_in[25];
    const float* mlp_wo  = (const float*)d_in[26];
    const float* fa_wg   = (const float*)d_in[27];
    const float* fa_wv   = (const float*)d_in[28];
    const float* fa_wo   = (const float*)d_in[29];
    const float* fa_wl   = (const float*)d_in[30];
    const float* fa_bl   = (const float*)d_in[31];
    float* out = (float*)d_out;

    float* ws_f    = (float*)d_ws;
    float* wproj   = ws_f;                 // 512 f32
    float* bias_xy = ws_f + 512;           // 1024
    float* a2      = ws_f + 1536;          // 512
    float* bias_ri = ws_f + 2048;          // 1024
    ushort_t* wt   = (ushort_t*)(ws_f + 3072);

    ushort_t* ntw1T = wt + 0;
    ushort_t* ntw2T = wt + 393216;
    ushort_t* wxyT  = wt + 786432;   // wx rows [0,512), wy rows [512,1024)
    ushort_t* wriT  = wt + 1179648;  // wr rows [0,512), wi rows [512,1024)
    ushort_t* woT   = wt + 1703936;
    ushort_t* mwgT  = wt + 1900544;
    ushort_t* mwvT  = wt + 2342912;
    ushort_t* mwoT  = wt + 2785280;
    ushort_t* fwgT  = wt + 3227648;
    ushort_t* fwvT  = wt + 3375104;  // end 3522560 bf16 = 1761280 f32

    TrArgs ta;
    ta.W[0]=nt_w1; ta.W[1]=nt_w2; ta.W[2]=rg_wx; ta.W[3]=rg_wy;
    ta.W[4]=rg_wr; ta.W[5]=rg_wi; ta.W[6]=rg_wo; ta.W[7]=mlp_wg;
    ta.W[8]=mlp_wv; ta.W[9]=mlp_wo; ta.W[10]=fa_wg; ta.W[11]=fa_wv;
    tr_all_k<<<3440, 256, 0, stream>>>(ta, wt);
    prep_k<<<4, 256, 0, stream>>>(rg_bx, rg_by, rg_lam, rg_br, rg_bi,
                                  bias_xy, a2, bias_ri);
    wproj_k<<<1, DD, 0, stream>>>(fa_wo, fa_wl, wproj);

    const size_t fixed_f32 = 3072 + 1761280;
    const size_t per_b_f32 = 8448;
    int Bc = B_TOT;
    while (Bc > 128 && (fixed_f32 + per_b_f32 * (size_t)Bc) * 4 > ws_size) Bc >>= 1;

    float* arena = ws_f + fixed_f32;

    for (int b0 = 0; b0 < B_TOT; b0 += Bc) {
        const int M  = Bc * SS;
        const int M2 = Bc * KNN;
        float*    xbuf = arena;                                    // [0,2304) live always
        ushort_t* negm = (ushort_t*)(arena + (size_t)2304 * Bc);   // [2304,2688)
        ushort_t* hid  = (ushort_t*)(arena + (size_t)2688 * Bc);   // [2688,3712)
        ushort_t* nf   = (ushort_t*)(arena + (size_t)3712 * Bc);   // [3712,4096)
        ushort_t* hb   = (ushort_t*)(arena + (size_t)4096 * Bc);   // [4096,5248)
        ushort_t* uh   = (ushort_t*)(arena + (size_t)5376 * Bc);   // [5376,6912)
        ushort_t* gth  = (ushort_t*)(arena + (size_t)6912 * Bc);   // [6912,8448)
        ushort_t* ri   = (ushort_t*)(arena + (size_t)2304 * Bc);   // [2304,5376)
        ushort_t* h2   = (ushort_t*)(arena + (size_t)2304 * Bc);   // [2304,3456)
        ushort_t* Th   = (ushort_t*)(arena + (size_t)3456 * Bc);   // [3456,6912)
        ushort_t* xh   = (ushort_t*)(arena + (size_t)6912 * Bc);   // [6912,8064)
        float*    lpb  = arena + (size_t)2304 * Bc;                // [2304,2340)

        // stage 1: neg messages + MLP residual + attention assembly (+rms g1)
        negm_k<<<Bc * 3, 256, 0, stream>>>(head, pred, negm, b0, Bc);
        bgemm<1, false><<<dim3(HH/128, M2/128), 256, 0, stream>>>(
            negm, ntw1T, nt_b1, nullptr, nullptr, hid, nullptr, M2, HH, DD);
        bgemm<4, false><<<dim3(DD/128, M2/128), 256, 0, stream>>>(
            hid, ntw2T, nt_b2, negm, nullptr, nf, nullptr, M2, DD, HH);
        asmrms_k<<<Bc, 64, 0, stream>>>(init_f, head, pred, w_ap, b_ap, w_an, b_an,
                                        nf, g1, xbuf, hb, b0, Bc);

        // Griffin recurrent branch
        bgemm<7, false><<<dim3(1024/128, M/128), 256, 0, stream>>>(
            hb, wxyT, bias_xy, nullptr, nullptr, uh, gth, M, 1024, DD);
        bgemm<0, false><<<dim3(1024/128, M/128), 256, 0, stream>>>(
            uh, wriT, bias_ri, nullptr, nullptr, ri, nullptr, M, 1024, DRR);
        rec_k<<<Bc / 4, 256, 0, stream>>>(uh, gth, ri, a2, Bc);
        bgemm<0, true><<<dim3(DD/128, M/128), 256, 0, stream>>>(
            uh, woT, rg_bo, nullptr, xbuf, nullptr, nullptr, M, DD, DRR);

        // gated-MLP residual branch
        rms_k<<<M / 4, 256, 0, stream>>>(xbuf, g2, h2);
        dual_k<false><<<dim3(DMM/64, M/128), 256, 0, stream>>>(
            h2, mwgT, mwvT, Th, nullptr, nullptr, M, DMM, DD);
        bgemm<0, true><<<dim3(DD/128, M/128), 256, 0, stream>>>(
            Th, mwoT, nullptr, nullptr, xbuf, xh, nullptr, M, DD, DMM);

        // final attention: fused dual-GEMM -> per-row logit partials
        dual_k<true><<<dim3(DD/64, M/128), 256, 0, stream>>>(
            xh, fwgT, fwvT, nullptr, lpb, wproj, M, DD, DD);
        final_k<<<Bc, 64, 0, stream>>>(xbuf, lpb, fa_bl, out, b0, Bc);
    }
}

// Round 9
// 1467.814 us; speedup vs baseline: 2.9876x; 1.0980x over previous
//
#include <hip/hip_runtime.h>
#include <hip/hip_bf16.h>

// Problem constants (from reference)
#define B_TOT 16384
#define DD    384
#define HH    1024
#define DRR   512
#define DMM   1152
#define SS    6     // 1 + KP + KN
#define KPP   3
#define KNN   2

typedef unsigned short ushort_t;
typedef __bf16 bf16x8 __attribute__((ext_vector_type(8)));
typedef float  f32x4  __attribute__((ext_vector_type(4)));

// ---------------------------------------------------------------- helpers
__device__ __forceinline__ float fexp2(float x) { return __builtin_amdgcn_exp2f(x); }
__device__ __forceinline__ float frcp(float x)  { return __builtin_amdgcn_rcpf(x); }
__device__ __forceinline__ float sigmoid_f(float x) {
    return frcp(1.f + fexp2(-1.4426950408889634f * x));
}
__device__ __forceinline__ float gelu_f(float x) {
    float z = 0.7978845608028654f * x * (1.f + 0.044715f * x * x);
    return x * frcp(1.f + fexp2(-2.885390081777927f * z));
}
__device__ __forceinline__ float wave_red_sum(float v) {
    #pragma unroll
    for (int off = 32; off; off >>= 1) v += __shfl_xor(v, off);
    return v;
}
__device__ __forceinline__ ushort_t f2bf(float v) {
    __hip_bfloat16 h = __float2bfloat16(v);
    return *reinterpret_cast<ushort_t*>(&h);
}
__device__ __forceinline__ float bf2f(ushort_t u) {
    unsigned int x = ((unsigned int)u) << 16;
    return __uint_as_float(x);
}
// async global->LDS, 16B per lane
__device__ __forceinline__ void g2l16(const ushort_t* g, ushort_t* l) {
    __builtin_amdgcn_global_load_lds(
        (const __attribute__((address_space(1))) void*)g,
        (__attribute__((address_space(3))) void*)l, 16, 0, 0);
}
// XCD-aware bijective block swizzle
__device__ __forceinline__ void swz_xy(int& bx, int& by) {
    const int nx = gridDim.x;
    const int nwg = nx * gridDim.y;
    const int h = by * nx + bx;
    const int q = nwg >> 3, r = nwg & 7;
    const int xcd = h & 7, lo = h >> 3;
    const int lin = (xcd < r) ? (xcd * (q + 1) + lo)
                              : (r * (q + 1) + (xcd - r) * q + lo);
    bx = lin % nx;
    by = lin / nx;
}

// ---------------------------------------------------------------- MFMA GEMM
// m97 single-buffer structure, 32 KiB LDS -> 4-5 blocks/CU; wave-level overlap
// across resident blocks hides staging latency (m114 mechanism).
//   stage(t) -> __syncthreads (drains vmcnt) -> ds_read+MFMA -> __syncthreads
//   -> stage(t+1)
// LDS: A@0 (16KB), B@8192 (16KB). Main-loop both-sides XOR chunk swizzle.
// Epilogue reuses sm with XOR-chunk swizzle (chunk ^ (row&7)) to fit 32 KiB.
template<int EPI, bool ACCUM>
__global__ __launch_bounds__(256, 4)
void bgemm(const ushort_t* __restrict__ A, const ushort_t* __restrict__ WT,
           const float* __restrict__ bias, const ushort_t* __restrict__ X2,
           float* __restrict__ C, ushort_t* __restrict__ Ch, ushort_t* __restrict__ Ch2,
           int M, int N, int K)
{
    __shared__ ushort_t sm[16384];   // 32 KiB

    int bx = blockIdx.x, by = blockIdx.y;
    swz_xy(bx, by);
    const int tid = threadIdx.x;
    const int l = tid & 63, w = tid >> 6;
    const int wr = w >> 1, wc = w & 1;
    const int lr = l & 15, hi = l >> 4;
    const int row0 = by * 128, col0 = bx * 128;

    const int lrw = l >> 3;
    const int lch = (l & 7) ^ (lrw & 7);
    const ushort_t* As[4]; const ushort_t* Bs[4]; int lo_[4];
    #pragma unroll
    for (int i = 0; i < 4; ++i) {
        const int g = w * 4 + i;
        As[i] = A  + (size_t)(row0 + g*8 + lrw) * K + lch * 8;
        Bs[i] = WT + (size_t)(col0 + g*8 + lrw) * K + lch * 8;
        lo_[i] = g * 512;
    }
    const int ko[2] = {(hi*8) ^ ((lr&7)*8), (32 + hi*8) ^ ((lr&7)*8)};

    f32x4 acc[4][4] = {};
    const int NT = K >> 6;

    #pragma unroll
    for (int i = 0; i < 4; ++i) {
        g2l16(As[i], &sm[lo_[i]]);
        g2l16(Bs[i], &sm[8192 + lo_[i]]);
    }
    for (int t = 0; t < NT; ++t) {
        __syncthreads();                       // drains vmcnt: tile t ready
        #pragma unroll
        for (int ks = 0; ks < 2; ++ks) {
            bf16x8 af[4], bfr[4];
            #pragma unroll
            for (int m = 0; m < 4; ++m)
                af[m] = *(const bf16x8*)&sm[(wr*64 + m*16 + lr)*64 + ko[ks]];
            #pragma unroll
            for (int n = 0; n < 4; ++n)
                bfr[n] = *(const bf16x8*)&sm[8192 + (wc*64 + n*16 + lr)*64 + ko[ks]];
            #pragma unroll
            for (int m = 0; m < 4; ++m)
                #pragma unroll
                for (int n = 0; n < 4; ++n)
                    acc[m][n] = __builtin_amdgcn_mfma_f32_16x16x32_bf16(
                        af[m], bfr[n], acc[m][n], 0, 0, 0);
        }
        __syncthreads();                       // all waves done reading LDS
        if (t + 1 < NT) {
            #pragma unroll
            for (int i = 0; i < 4; ++i) {
                g2l16(As[i] + (size_t)(t+1)*64, &sm[lo_[i]]);
                g2l16(Bs[i] + (size_t)(t+1)*64, &sm[8192 + lo_[i]]);
            }
        }
    }

    // epilogue: C/D frag mapping col = l&15, row = (l>>4)*4 + j
    const bool BF = (EPI == 7) || (Ch != nullptr);
    #pragma unroll
    for (int m = 0; m < 4; ++m) {
        #pragma unroll
        for (int n = 0; n < 4; ++n) {
            const int r0 = row0 + wr*64 + m*16 + hi*4;
            const int c  = col0 + wc*64 + n*16 + lr;
            const float bv = bias ? bias[c] : 0.f;
            const int rl0 = wr*64 + m*16 + hi*4;
            const int cl  = wc*64 + n*16 + lr;
            #pragma unroll
            for (int j = 0; j < 4; ++j) {
                const int r = r0 + j;
                float v = acc[m][n][j] + bv;
                if (EPI == 1) v = fmaxf(v, 0.f);
                if (EPI == 4) v = v - bf2f(X2[(size_t)r * N + c]);
                if (ACCUM)    v += C[(size_t)r * N + c];
                if (C) C[(size_t)r * N + c] = v;
                if (BF) {
                    float ov = (EPI == 7 && c >= 512) ? gelu_f(v) : v;
                    const int rl = rl0 + j;
                    sm[rl*128 + ((((cl>>3) ^ (rl & 7))) << 3) + (cl & 7)] = f2bf(ov);
                }
            }
        }
    }
    if (BF) {
        __syncthreads();
        const int er = tid >> 1, ec = (tid & 1) * 64;
        ushort_t* dst; int nn, dc0;
        if (EPI == 7) {
            nn = 512;
            if (col0 < 512) { dst = Ch;  dc0 = col0; }
            else            { dst = Ch2; dc0 = col0 - 512; }
        } else { dst = Ch; nn = N; dc0 = col0; }
        ushort_t* gp = dst + (size_t)(row0 + er) * nn + dc0 + ec;
        #pragma unroll
        for (int qq = 0; qq < 8; ++qq) {
            const int q = (ec >> 3) + qq;
            const uint4 vv = *(const uint4*)&sm[er*128 + ((q ^ (er & 7)) << 3)];
            *(uint4*)(gp + qq*8) = vv;
        }
    }
}

// ---------------------------------------------------------------- dual-B GEMM
// Single-buffer 32 KiB: A@0 (16KB), G@8192 (8KB), V@12288 (8KB).
template<bool LOGITS>
__global__ __launch_bounds__(256, 4)
void dual_k(const ushort_t* __restrict__ A, const ushort_t* __restrict__ W1T,
            const ushort_t* __restrict__ W2T, ushort_t* __restrict__ Ch,
            float* __restrict__ LP, const float* __restrict__ wproj,
            int M, int N, int K)
{
    __shared__ ushort_t sm[16384];

    int bx = blockIdx.x, by = blockIdx.y;
    swz_xy(bx, by);
    const int tid = threadIdx.x;
    const int l = tid & 63, w = tid >> 6;
    const int wr = w >> 1, wc = w & 1;
    const int lr = l & 15, hi = l >> 4;
    const int row0 = by * 128, col0 = bx * 64;

    const int lrw = l >> 3;
    const int lch = (l & 7) ^ (lrw & 7);
    const ushort_t* As[4]; int loA[4];
    #pragma unroll
    for (int i = 0; i < 4; ++i) {
        const int g = w * 4 + i;
        As[i] = A + (size_t)(row0 + g*8 + lrw) * K + lch * 8;
        loA[i] = g * 512;
    }
    const ushort_t* Gs[2]; const ushort_t* Vs[2]; int loB[2];
    #pragma unroll
    for (int i = 0; i < 2; ++i) {
        const int g = w * 2 + i;
        Gs[i] = W1T + (size_t)(col0 + g*8 + lrw) * K + lch * 8;
        Vs[i] = W2T + (size_t)(col0 + g*8 + lrw) * K + lch * 8;
        loB[i] = g * 512;
    }
    const int ko[2] = {(hi*8) ^ ((lr&7)*8), (32 + hi*8) ^ ((lr&7)*8)};

    f32x4 ag[4][2] = {}, av[4][2] = {};
    const int NT = K >> 6;

    #pragma unroll
    for (int i = 0; i < 4; ++i) g2l16(As[i], &sm[loA[i]]);
    #pragma unroll
    for (int i = 0; i < 2; ++i) {
        g2l16(Gs[i], &sm[8192  + loB[i]]);
        g2l16(Vs[i], &sm[12288 + loB[i]]);
    }
    for (int t = 0; t < NT; ++t) {
        __syncthreads();
        #pragma unroll
        for (int ks = 0; ks < 2; ++ks) {
            bf16x8 af[4], bg[2], bv[2];
            #pragma unroll
            for (int m = 0; m < 4; ++m)
                af[m] = *(const bf16x8*)&sm[(wr*64 + m*16 + lr)*64 + ko[ks]];
            #pragma unroll
            for (int n = 0; n < 2; ++n) {
                bg[n] = *(const bf16x8*)&sm[8192  + (wc*32 + n*16 + lr)*64 + ko[ks]];
                bv[n] = *(const bf16x8*)&sm[12288 + (wc*32 + n*16 + lr)*64 + ko[ks]];
            }
            #pragma unroll
            for (int m = 0; m < 4; ++m)
                #pragma unroll
                for (int n = 0; n < 2; ++n) {
                    ag[m][n] = __builtin_amdgcn_mfma_f32_16x16x32_bf16(af[m], bg[n], ag[m][n], 0, 0, 0);
                    av[m][n] = __builtin_amdgcn_mfma_f32_16x16x32_bf16(af[m], bv[n], av[m][n], 0, 0, 0);
                }
        }
        __syncthreads();
        if (t + 1 < NT) {
            #pragma unroll
            for (int i = 0; i < 4; ++i)
                g2l16(As[i] + (size_t)(t+1)*64, &sm[loA[i]]);
            #pragma unroll
            for (int i = 0; i < 2; ++i) {
                g2l16(Gs[i] + (size_t)(t+1)*64, &sm[8192  + loB[i]]);
                g2l16(Vs[i] + (size_t)(t+1)*64, &sm[12288 + loB[i]]);
            }
        }
    }

    if (!LOGITS) {
        #pragma unroll
        for (int m = 0; m < 4; ++m)
            #pragma unroll
            for (int n = 0; n < 2; ++n) {
                const int cl = wc*32 + n*16 + lr;
                #pragma unroll
                for (int j = 0; j < 4; ++j) {
                    const int rl = wr*64 + m*16 + hi*4 + j;
                    sm[rl*64 + (((cl>>3) ^ (rl & 7)) << 3) + (cl & 7)] =
                        f2bf(gelu_f(ag[m][n][j]) * av[m][n][j]);
                }
            }
        __syncthreads();
        const int er = tid >> 1, ec = (tid & 1) * 32;
        ushort_t* gp = Ch + (size_t)(row0 + er) * N + col0 + ec;
        #pragma unroll
        for (int qq = 0; qq < 4; ++qq) {
            const int q = (ec >> 3) + qq;
            const uint4 vv = *(const uint4*)&sm[er*64 + ((q ^ (er & 7)) << 3)];
            *(uint4*)(gp + qq*8) = vv;
        }
    } else {
        float wp[2];
        #pragma unroll
        for (int n = 0; n < 2; ++n) wp[n] = wproj[col0 + wc*32 + n*16 + lr];
        float* red = (float*)sm;   // [128][2]
        #pragma unroll
        for (int m = 0; m < 4; ++m) {
            #pragma unroll
            for (int j = 0; j < 4; ++j) {
                float s = 0.f;
                #pragma unroll
                for (int n = 0; n < 2; ++n)
                    s += gelu_f(ag[m][n][j]) * av[m][n][j] * wp[n];
                s += __shfl_xor(s, 1);
                s += __shfl_xor(s, 2);
                s += __shfl_xor(s, 4);
                s += __shfl_xor(s, 8);
                if (lr == 0) red[(wr*64 + m*16 + hi*4 + j) * 2 + wc] = s;
            }
        }
        __syncthreads();
        if (tid < 128)
            LP[(size_t)(row0 + tid) * 6 + bx] = red[tid*2] + red[tid*2 + 1];
    }
}

// ---------------------------------------------------------------- RG-LRU recurrence
__global__ __launch_bounds__(256, 8)
void rec_k(ushort_t* __restrict__ u, const ushort_t* __restrict__ gate,
           const ushort_t* __restrict__ ri, const float* __restrict__ a2,
           int Bc)
{
    const int g = blockIdx.x * 256 + threadIdx.x;   // < Bc*64
    const int b = g >> 6, c8 = (g & 63) << 3;
    float a2v[8];
    *(float4*)&a2v[0] = *(const float4*)&a2[c8];
    *(float4*)&a2v[4] = *(const float4*)&a2[c8 + 4];
    float h[8] = {};
    for (int t = 0; t < SS; ++t) {
        const size_t row = (size_t)t * Bc + b;
        uint4 uw = *(const uint4*)&u[row * DRR + c8];
        uint4 rw = *(const uint4*)&ri[row * 1024 + c8];
        uint4 iw = *(const uint4*)&ri[row * 1024 + 512 + c8];
        uint4 gw = *(const uint4*)&gate[row * DRR + c8];
        const ushort_t* up = (const ushort_t*)&uw;
        const ushort_t* rp = (const ushort_t*)&rw;
        const ushort_t* ip = (const ushort_t*)&iw;
        const ushort_t* gp = (const ushort_t*)&gw;
        ushort_t o[8];
        #pragma unroll
        for (int q = 0; q < 8; ++q) {
            const float rv = sigmoid_f(bf2f(rp[q]));
            const float iv = sigmoid_f(bf2f(ip[q]));
            const float e  = fexp2(a2v[q] * rv);
            const float hv = e * h[q]
                           + sqrtf(fmaxf(0.f, 1.f - e * e)) * (iv * bf2f(up[q]));
            h[q] = hv;
            o[q] = f2bf(hv * bf2f(gp[q]));
        }
        *(uint4*)&u[row * DRR + c8] = *(const uint4*)o;
    }
}

// ---------------------------------------------------------------- small kernels

struct TrArgs { const float* W[12]; };
__global__ void tr_all_k(TrArgs a, ushort_t* __restrict__ wt)
{
    constexpr int KT[12]  = {384,1024,384,384,512,512,512,384,384,1152,384,384};
    constexpr int NTb[12] = {1024,384,512,512,512,512,384,1152,1152,384,384,384};
    constexpr int EOFF[12]= {0,393216,786432,983040,1179648,1441792,1703936,
                             1900544,2342912,2785280,3227648,3375104};
    constexpr int TPRE[13]= {0,384,768,960,1152,1408,1664,1856,2288,2720,3152,3296,3440};
    const int tb = blockIdx.x;
    int s = 0;
    #pragma unroll
    for (int i = 0; i < 12; ++i) if (tb >= TPRE[i+1]) s = i + 1;
    const int rel = tb - TPRE[s];
    const int K = KT[s], N = NTb[s];
    const int ntn = N >> 5;
    const int k0 = (rel / ntn) * 32, n0 = (rel % ntn) * 32;

    __shared__ float ts[32][33];
    const int r = threadIdx.x >> 3, c4 = (threadIdx.x & 7) * 4;
    const float4 v = *(const float4*)&a.W[s][(size_t)(k0 + r) * N + n0 + c4];
    ts[r][c4+0] = v.x; ts[r][c4+1] = v.y; ts[r][c4+2] = v.z; ts[r][c4+3] = v.w;
    __syncthreads();
    ushort_t o4[4];
    #pragma unroll
    for (int q = 0; q < 4; ++q) o4[q] = f2bf(ts[c4 + q][r]);
    *(uint2*)&wt[EOFF[s] + (size_t)(n0 + r) * K + k0 + c4] = *(const uint2*)o4;
}

__global__ void prep_k(const float* __restrict__ rg_bx, const float* __restrict__ rg_by,
                       const float* __restrict__ rg_lam,
                       const float* __restrict__ rg_br, const float* __restrict__ rg_bi,
                       float* __restrict__ bias_xy, float* __restrict__ a2,
                       float* __restrict__ bias_ri)
{
    int i = blockIdx.x * 256 + threadIdx.x;
    if (i < 512) {
        bias_xy[i] = rg_bx[i];
        bias_ri[i] = rg_br[i];
        float lam = rg_lam[i];
        float sp = (lam > 20.f) ? lam : log1pf(expf(lam));
        a2[i] = -8.0f * sp * 1.4426950408889634f;
    } else if (i < 1024) {
        bias_xy[i] = rg_by[i - 512];
        bias_ri[i] = rg_bi[i - 512];
    }
}

__global__ void negm_k(const float* __restrict__ head, const float* __restrict__ pred,
                       ushort_t* __restrict__ negm_h, int b0, int Bc)
{
    int idx = blockIdx.x * 256 + threadIdx.x;        // < Bc*2*384
    int d = idx % DD, rr = idx / DD;
    int j = (rr >= Bc) ? 1 : 0;
    int b = rr - j * Bc;
    size_t off = ((size_t)(KPP + j) * B_TOT + (b0 + b)) * DD + d;
    negm_h[idx] = f2bf(head[off] + pred[off]);
}

__global__ void asmrms_k(const float* __restrict__ init_f,
                         const float* __restrict__ head, const float* __restrict__ pred,
                         const float* __restrict__ w_ap, const float* __restrict__ b_ap,
                         const float* __restrict__ w_an, const float* __restrict__ b_an,
                         const ushort_t* __restrict__ nf, const float* __restrict__ g1,
                         float* __restrict__ x, ushort_t* __restrict__ hb,
                         int b0, int Bc)
{
    const int lb = blockIdx.x, gb = b0 + lb, lane = threadIdx.x;
    float hp[3][6], nv[2][6], iv[6], wap[6], wan[6];
    #pragma unroll
    for (int q = 0; q < 6; ++q) {
        int d = lane + 64 * q;
        wap[q] = w_ap[d]; wan[q] = w_an[d];
        iv[q] = init_f[(size_t)gb * DD + d];
    }
    float lp[3], ln2[2];
    #pragma unroll
    for (int j = 0; j < 3; ++j) {
        float p = 0.f;
        #pragma unroll
        for (int q = 0; q < 6; ++q) {
            int d = lane + 64 * q;
            size_t off = ((size_t)j * B_TOT + gb) * DD + d;
            float v = head[off] + pred[off];
            hp[j][q] = v;
            p += v * wap[q];
        }
        lp[j] = wave_red_sum(p) + b_ap[0];
    }
    #pragma unroll
    for (int j = 0; j < 2; ++j) {
        float p = 0.f;
        #pragma unroll
        for (int q = 0; q < 6; ++q) {
            int d = lane + 64 * q;
            float v = bf2f(nf[((size_t)j * Bc + lb) * DD + d]);
            nv[j][q] = v;
            p += v * wan[q];
        }
        ln2[j] = wave_red_sum(p) + b_an[0];
    }
    float mp = fmaxf(lp[0], fmaxf(lp[1], lp[2]));
    float e0 = expf(lp[0]-mp), e1 = expf(lp[1]-mp), e2 = expf(lp[2]-mp);
    float sp = e0 + e1 + e2;
    float awp[3] = {e0/sp, e1/sp, e2/sp};
    float mn = fmaxf(ln2[0], ln2[1]);
    float f0 = expf(ln2[0]-mn), f1 = expf(ln2[1]-mn);
    float sn = f0 + f1;
    float awn[2] = {f0/sn, f1/sn};

    #pragma unroll
    for (int t = 0; t < SS; ++t) {
        float rowv[6], ss = 0.f;
        #pragma unroll
        for (int q = 0; q < 6; ++q) {
            float v;
            if (t == 0)      v = iv[q];
            else if (t <= 3) v = hp[t-1][q] * awp[t-1];
            else             v = nv[t-4][q] * awn[t-4];
            rowv[q] = v;
            ss += v * v;
        }
        ss = wave_red_sum(ss);
        float sc = rsqrtf(ss / (float)DD + 1e-6f);
        float* xr = x + (size_t)(t * Bc + lb) * DD;
        ushort_t* hr = hb + (size_t)(t * Bc + lb) * DD;
        #pragma unroll
        for (int q = 0; q < 6; ++q) {
            int d = lane + 64 * q;
            xr[d] = rowv[q];
            hr[d] = f2bf(rowv[q] * g1[d] * sc);
        }
    }
}

__global__ void rms_k(const float* __restrict__ x, const float* __restrict__ g,
                      ushort_t* __restrict__ h)
{
    int row  = blockIdx.x * 4 + (threadIdx.x >> 6);
    int lane = threadIdx.x & 63;
    const float* xr = x + (size_t)row * DD;
    float ss = 0.f;
    for (int d = lane; d < DD; d += 64) { float v = xr[d]; ss += v * v; }
    ss = wave_red_sum(ss);
    float sc = rsqrtf(ss / (float)DD + 1e-6f);
    ushort_t* hr = h + (size_t)row * DD;
    for (int d = lane; d < DD; d += 64) hr[d] = f2bf(xr[d] * g[d] * sc);
}

__global__ void wproj_k(const float* __restrict__ fa_wo, const float* __restrict__ fa_wl,
                        float* __restrict__ wproj)
{
    int d = threadIdx.x;  // 384 threads
    float s = 0.f;
    for (int k = 0; k < DD; ++k) s += fa_wo[(size_t)d * DD + k] * fa_wl[k];
    wproj[d] = s;
}

__global__ void final_k(const float* __restrict__ x, const float* __restrict__ lp,
                        const float* __restrict__ fa_bl,
                        float* __restrict__ out, int b0, int Bc)
{
    const int lb = blockIdx.x, gb = b0 + lb, lane = threadIdx.x;
    float lg[SS];
    #pragma unroll
    for (int t = 0; t < SS; ++t) {
        const float* pp = lp + (size_t)(t * Bc + lb) * 6;
        lg[t] = pp[0] + pp[1] + pp[2] + pp[3] + pp[4] + pp[5] + fa_bl[0];
    }
    float m = lg[0];
    #pragma unroll
    for (int t = 1; t < SS; ++t) m = fmaxf(m, lg[t]);
    float e[SS], s = 0.f;
    #pragma unroll
    for (int t = 0; t < SS; ++t) { e[t] = expf(lg[t] - m); s += e[t]; }
    float inv = 1.0f / s;
    #pragma unroll
    for (int q = 0; q < 6; ++q) {
        int d = lane + 64 * q;
        float acc = 0.f;
        #pragma unroll
        for (int t = 0; t < SS; ++t)
            acc += x[(size_t)(t * Bc + lb) * DD + d] * (e[t] * inv);
        out[(size_t)gb * DD + d] = acc * (1.0f / 6.0f);
    }
}

// ---------------------------------------------------------------- launch
extern "C" void kernel_launch(void* const* d_in, const int* in_sizes, int n_in,
                              void* d_out, int out_size, void* d_ws, size_t ws_size,
                              hipStream_t stream)
{
    (void)in_sizes; (void)n_in; (void)out_size;
    const float* init_f  = (const float*)d_in[0];
    const float* head    = (const float*)d_in[1];
    const float* pred    = (const float*)d_in[2];
    const float* w_ap    = (const float*)d_in[3];
    const float* b_ap    = (const float*)d_in[4];
    const float* w_an    = (const float*)d_in[5];
    const float* b_an    = (const float*)d_in[6];
    const float* nt_w1   = (const float*)d_in[7];
    const float* nt_b1   = (const float*)d_in[8];
    const float* nt_w2   = (const float*)d_in[9];
    const float* nt_b2   = (const float*)d_in[10];
    const float* g1      = (const float*)d_in[11];
    const float* rg_wx   = (const float*)d_in[12];
    const float* rg_bx   = (const float*)d_in[13];
    const float* rg_wy   = (const float*)d_in[14];
    const float* rg_by   = (const float*)d_in[15];
    const float* rg_wr   = (const float*)d_in[16];
    const float* rg_br   = (const float*)d_in[17];
    const float* rg_wi   = (const float*)d_in[18];
    const float* rg_bi   = (const float*)d_in[19];
    const float* rg_lam  = (const float*)d_in[20];
    const float* rg_wo   = (const float*)d_in[21];
    const float* rg_bo   = (const float*)d_in[22];
    const float* g2      = (const float*)d_in[23];
    const float* mlp_wg  = (const float*)d_in[24];
    const float* mlp_wv  = (const float*)d_in[25];
    const float* mlp_wo  = (const float*)d_in[26];
    const float* fa_wg   = (const float*)d_in[27];
    const float* fa_wv   = (const float*)d_in[28];
    const float* fa_wo   = (const float*)d_in[29];
    const float* fa_wl   = (const float*)d_in[30];
    const float* fa_bl   = (const float*)d_in[31];
    float* out = (float*)d_out;

    float* ws_f    = (float*)d_ws;
    float* wproj   = ws_f;                 // 512 f32
    float* bias_xy = ws_f + 512;           // 1024
    float* a2      = ws_f + 1536;          // 512
    float* bias_ri = ws_f + 2048;          // 1024
    ushort_t* wt   = (ushort_t*)(ws_f + 3072);

    ushort_t* ntw1T = wt + 0;
    ushort_t* ntw2T = wt + 393216;
    ushort_t* wxyT  = wt + 786432;   // wx rows [0,512), wy rows [512,1024)
    ushort_t* wriT  = wt + 1179648;  // wr rows [0,512), wi rows [512,1024)
    ushort_t* woT   = wt + 1703936;
    ushort_t* mwgT  = wt + 1900544;
    ushort_t* mwvT  = wt + 2342912;
    ushort_t* mwoT  = wt + 2785280;
    ushort_t* fwgT  = wt + 3227648;
    ushort_t* fwvT  = wt + 3375104;  // end 3522560 bf16 = 1761280 f32

    TrArgs ta;
    ta.W[0]=nt_w1; ta.W[1]=nt_w2; ta.W[2]=rg_wx; ta.W[3]=rg_wy;
    ta.W[4]=rg_wr; ta.W[5]=rg_wi; ta.W[6]=rg_wo; ta.W[7]=mlp_wg;
    ta.W[8]=mlp_wv; ta.W[9]=mlp_wo; ta.W[10]=fa_wg; ta.W[11]=fa_wv;
    tr_all_k<<<3440, 256, 0, stream>>>(ta, wt);
    prep_k<<<4, 256, 0, stream>>>(rg_bx, rg_by, rg_lam, rg_br, rg_bi,
                                  bias_xy, a2, bias_ri);
    wproj_k<<<1, DD, 0, stream>>>(fa_wo, fa_wl, wproj);

    const size_t fixed_f32 = 3072 + 1761280;
    const size_t per_b_f32 = 8448;
    int Bc = B_TOT;
    while (Bc > 128 && (fixed_f32 + per_b_f32 * (size_t)Bc) * 4 > ws_size) Bc >>= 1;

    float* arena = ws_f + fixed_f32;

    for (int b0 = 0; b0 < B_TOT; b0 += Bc) {
        const int M  = Bc * SS;
        const int M2 = Bc * KNN;
        float*    xbuf = arena;                                    // [0,2304) live always
        ushort_t* negm = (ushort_t*)(arena + (size_t)2304 * Bc);   // [2304,2688)
        ushort_t* hid  = (ushort_t*)(arena + (size_t)2688 * Bc);   // [2688,3712)
        ushort_t* nf   = (ushort_t*)(arena + (size_t)3712 * Bc);   // [3712,4096)
        ushort_t* hb   = (ushort_t*)(arena + (size_t)4096 * Bc);   // [4096,5248)
        ushort_t* uh   = (ushort_t*)(arena + (size_t)5376 * Bc);   // [5376,6912)
        ushort_t* gth  = (ushort_t*)(arena + (size_t)6912 * Bc);   // [6912,8448)
        ushort_t* ri   = (ushort_t*)(arena + (size_t)2304 * Bc);   // [2304,5376)
        ushort_t* h2   = (ushort_t*)(arena + (size_t)2304 * Bc);   // [2304,3456)
        ushort_t* Th   = (ushort_t*)(arena + (size_t)3456 * Bc);   // [3456,6912)
        ushort_t* xh   = (ushort_t*)(arena + (size_t)6912 * Bc);   // [6912,8064)
        float*    lpb  = arena + (size_t)2304 * Bc;                // [2304,2340)

        // stage 1: neg messages + MLP residual + attention assembly (+rms g1)
        negm_k<<<Bc * 3, 256, 0, stream>>>(head, pred, negm, b0, Bc);
        bgemm<1, false><<<dim3(HH/128, M2/128), 256, 0, stream>>>(
            negm, ntw1T, nt_b1, nullptr, nullptr, hid, nullptr, M2, HH, DD);
        bgemm<4, false><<<dim3(DD/128, M2/128), 256, 0, stream>>>(
            hid, ntw2T, nt_b2, negm, nullptr, nf, nullptr, M2, DD, HH);
        asmrms_k<<<Bc, 64, 0, stream>>>(init_f, head, pred, w_ap, b_ap, w_an, b_an,
                                        nf, g1, xbuf, hb, b0, Bc);

        // Griffin recurrent branch
        bgemm<7, false><<<dim3(1024/128, M/128), 256, 0, stream>>>(
            hb, wxyT, bias_xy, nullptr, nullptr, uh, gth, M, 1024, DD);
        bgemm<0, false><<<dim3(1024/128, M/128), 256, 0, stream>>>(
            uh, wriT, bias_ri, nullptr, nullptr, ri, nullptr, M, 1024, DRR);
        rec_k<<<Bc / 4, 256, 0, stream>>>(uh, gth, ri, a2, Bc);
        bgemm<0, true><<<dim3(DD/128, M/128), 256, 0, stream>>>(
            uh, woT, rg_bo, nullptr, xbuf, nullptr, nullptr, M, DD, DRR);

        // gated-MLP residual branch
        rms_k<<<M / 4, 256, 0, stream>>>(xbuf, g2, h2);
        dual_k<false><<<dim3(DMM/64, M/128), 256, 0, stream>>>(
            h2, mwgT, mwvT, Th, nullptr, nullptr, M, DMM, DD);
        bgemm<0, true><<<dim3(DD/128, M/128), 256, 0, stream>>>(
            Th, mwoT, nullptr, nullptr, xbuf, xh, nullptr, M, DD, DMM);

        // final attention: fused dual-GEMM -> per-row logit partials
        dual_k<true><<<dim3(DD/64, M/128), 256, 0, stream>>>(
            xh, fwgT, fwvT, nullptr, lpb, wproj, M, DD, DD);
        final_k<<<Bc, 64, 0, stream>>>(xbuf, lpb, fa_bl, out, b0, Bc);
    }
}